// Round 8
// baseline (753.522 us; speedup 1.0000x reference)
//
#include <hip/hip_runtime.h>
#include <hip/hip_bf16.h>
#include <math.h>

// MPv2_3d_arch: B=8, n=64*64=4096, c=180, heads=6 (hd=30), dict M=64, rd=10,
// dtd=64, mlp_hid=360, cat C=424, window 16x16, groups of 128.
// R19: R18 (passing, 709us) + two byte/issue-count fixes:
// (a) qkv stored bf16 in padded [ROWS][576] layout (3 sec x 6 heads x 32;
//     pads zeroed; Q pre-scaled by scq in gemm epilogue) — numerics-identical
//     to the old fp32-store+f2b-at-load path; halves qkv HBM traffic and
//     vectorizes win/acmsa staging (v8s loads, no f2b loops).
// (b) conv weights moved from LDS to L2-resident global wT[25][448] fp32:
//     LDS issues 204->104 b128/thread, LDS 45.5->39.2KB (4 blocks/CU).
// SESSION RULE: input dtype VARIES per run (bf16 or fp32) — every d_in
// access must go through *flag (by value). Raw-bit reads = NaN.
#define BB      8
#define NTOK    4096
#define CDIM    180
#define C3      540
#define NHEADS  6
#define HD      30
#define MDICT   64
#define RD      10
#define DTD     64
#define MHID    360
#define CCAT    424
#define WS      16
#define WIN_N   256
#define GS      128
#define NG      32
#define ROWS    (BB*NTOK)   // 32768
#define KP1     192         // Kpad for K=180
#define KP2     448         // Kpad for K=424
#define QKVP    576         // padded qkv row: 3 sec * 6 heads * 32

typedef __hip_bfloat16 bf16;
typedef short v8s __attribute__((ext_vector_type(8)));
typedef float f32x4 __attribute__((ext_vector_type(4)));
typedef unsigned int u32x4 __attribute__((ext_vector_type(4)));

__device__ __forceinline__ float gelu_exact(float x) {
    return 0.5f * x * (1.0f + erff(x * 0.70710678118654752f));
}
__device__ __forceinline__ float wave_sum(float v) {
    #pragma unroll
    for (int off = 32; off > 0; off >>= 1) v += __shfl_xor(v, off, 64);
    return v;
}
// fp32 <-> bf16 bits without type-punning (RNE)
__device__ __forceinline__ unsigned short f2b(float v) {
    unsigned u = __float_as_uint(v);
    return (unsigned short)((u + 0x7FFFu + ((u >> 16) & 1u)) >> 16);
}
__device__ __forceinline__ float b2f(unsigned short h) {
    return __uint_as_float(((unsigned)h) << 16);
}
__device__ __forceinline__ unsigned packbf(float lo, float hi) {
    return (unsigned)f2b(lo) | ((unsigned)f2b(hi) << 16);
}
// async global->LDS 16B (gfx950); size must be literal; lds addr = per-lane
// slot in lane-order-contiguous slab (wave-uniform base + lane*16).
__device__ __forceinline__ void gload16(const void* g, void* l) {
    __builtin_amdgcn_global_load_lds(
        (const __attribute__((address_space(1))) void*)g,
        (__attribute__((address_space(3))) void*)l, 16, 0, 0);
}

// ---------------- dtype detector: flag=1 if inputs are fp32, 0 if bf16 -----
__global__ __launch_bounds__(256) void detect_kernel(const void* __restrict__ x,
                                                     int* __restrict__ flag,
                                                     int* __restrict__ diag)
{
    __shared__ int cnt;
    if (threadIdx.x == 0) { cnt = 0; *diag = 0; }
    __syncthreads();
    const unsigned short* u = (const unsigned short*)x;
    int c = 0;
    for (int i = threadIdx.x; i < 2048; i += 256) {
        unsigned short e = u[2 * i] & 0x7F80;
        if (e >= 0x4300) c++;
    }
    atomicAdd(&cnt, c);
    __syncthreads();
    if (threadIdx.x == 0) *flag = (cnt > 16) ? 1 : 0;
}

// ---------------- batched dtype-flexible input -> fp32 conversion ----------
#define NCVT 23
struct CvtArgs {
    const void* src[NCVT];
    float* dst[NCVT];
    int cum[NCVT + 1];
};
__global__ __launch_bounds__(256) void convert_all_kernel(CvtArgs a, int total,
        const int* __restrict__ flag)
{
    int i = blockIdx.x * 256 + threadIdx.x;
    if (i >= total) return;
    int s = 0;
    while (i >= a.cum[s + 1]) s++;   // x is segment 0 -> most threads exit fast
    int off = i - a.cum[s];
    if (*flag) a.dst[s][off] = ((const float*)a.src[s])[off];
    else       a.dst[s][off] = __bfloat162float(((const bf16*)a.src[s])[off]);
}

// ---------------- NaN/Inf check -> diag bit --------------------------------
__global__ __launch_bounds__(256) void check_f32_kernel(const float* __restrict__ buf,
        int n, int bit, int* __restrict__ diag)
{
    int i = blockIdx.x * 256 + threadIdx.x;
    if (i >= n) return;
    unsigned u = __float_as_uint(buf[i]);
    if ((u & 0x7F800000u) == 0x7F800000u) atomicOr(diag, bit);
}

// ---------------- output emit: fp32 src -> d_out in detected dtype ---------
__global__ __launch_bounds__(256) void emit_kernel(const float* __restrict__ src,
        void* __restrict__ out, const int* __restrict__ flag,
        const int* __restrict__ diag, int n)
{
    int i = blockIdx.x * 256 + threadIdx.x;
    if (i >= n) return;
    float v = src[i];
    int d = *diag;
    if (d) v = 100.f + 32.f * (float)d;   // NaN stage code -> absmax bin
    if (*flag) ((float*)out)[i] = v;
    else       ((bf16*)out)[i]  = __float2bfloat16(v);
}

// ---------------- zero cols 180..191 of a [ROWS,KP1] bf16 buffer -----------
__global__ __launch_bounds__(256) void zero_tail_kernel(bf16* __restrict__ buf)
{
    int idx = blockIdx.x * 256 + threadIdx.x;   // ROWS*12
    int row = idx / 12, c = idx % 12;
    buf[(size_t)row * KP1 + CDIM + c] = __float2bfloat16(0.f);
}

// ---------------- zero pad slots (d=30,31 per head/sec) of qkvb ------------
__global__ __launch_bounds__(256) void zero_qkvpad_kernel(bf16* __restrict__ qb)
{
    int idx = blockIdx.x * 256 + threadIdx.x;   // ROWS*36
    int row = idx / 36, r = idx % 36;
    int sec = r / 12, rr = r % 12, hh = rr >> 1, d = 30 + (rr & 1);
    qb[(size_t)row * QKVP + sec * 192 + hh * 32 + d] = __float2bfloat16(0.f);
}

// ---------------- adaptive weight repack: W[K,N] -> Wt[Npad,Kpad] bf16 -----
__global__ __launch_bounds__(256) void packW_kernel(const void* __restrict__ W,
        bf16* __restrict__ Wt, int K, int N, int Kpad, int total,
        const int* __restrict__ flag)
{
    int idx = blockIdx.x * 256 + threadIdx.x;
    if (idx >= total) return;
    int n = idx / Kpad, k = idx % Kpad;
    float v = 0.f;
    if (k < K && n < N) {
        size_t src = (size_t)k * N + n;
        v = (*flag) ? ((const float*)W)[src]
                    : __bfloat162float(((const bf16*)W)[src]);
    }
    Wt[idx] = __float2bfloat16(v);
}

// ---------------- conv weight transpose: w[C][25] -> wT[25][448] fp32 ------
__global__ __launch_bounds__(256) void packWT_kernel(const float* __restrict__ w,
        float* __restrict__ wT)
{
    int idx = blockIdx.x * 256 + threadIdx.x;   // 25*448
    if (idx >= 25 * KP2) return;
    int kk = idx / KP2, ch = idx % KP2;
    wT[idx] = (ch < CCAT) ? w[ch * 25 + kk] : 0.f;
}

// ---------------- window-attention bias table: [6][256][256] ---------------
__global__ __launch_bounds__(256) void bias_pre_kernel(const int* __restrict__ rpi,
        const float* __restrict__ rpb, float* __restrict__ bias_t)
{
    int idx = blockIdx.x * 256 + threadIdx.x;   // 6*65536
    int h = idx >> 16, ij = idx & 65535;
    bias_t[idx] = rpb[rpi[ij] * NHEADS + h];
}

// ---------------- MFMA GEMM: out = act(A@W [+bias]) [+ res] ----------------
// R18 structure: 128(M)x64(N) tile, 256 threads, global_load_lds staging,
// 8 MFMA/k-step/wave. R19: OM=1 variant writes bf16 to padded qkv layout
// (slot = sec*192 + hh*32 + d), with Q section (sec==0) pre-scaled by scq.
// Numerics identical to fp32-store + f2b-at-load (same rounding, same order).
template<bool GELU_, bool ADDRES, bool BIAS_, int OM>
__global__ __launch_bounds__(256) void mgemm_kernel(
        const bf16* __restrict__ A, int lda,
        const bf16* __restrict__ Wt, int ldw,
        const float* __restrict__ bias,
        const float* __restrict__ res, int ldr,
        float* __restrict__ outF, int ldo, int N, int K)
{
    __shared__ __align__(16) unsigned short As[128][32];   // 8 KB
    __shared__ __align__(16) unsigned short Bs[64][32];    // 4 KB
    int tid = threadIdx.x;
    int wave = tid >> 6, lane = tid & 63;
    int quad = lane >> 4, mr = lane & 15;
    int row0 = blockIdx.y * 128, col0 = blockIdx.x * 64;
    int ar = tid >> 2, ac = (tid & 3) * 8;   // LDS slot byte off = tid*16
    f32x4 z = {0.f, 0.f, 0.f, 0.f};
    f32x4 acc[2][4] = {{z, z, z, z}, {z, z, z, z}};
    const unsigned short* Au = (const unsigned short*)A;
    const unsigned short* Wu = (const unsigned short*)Wt;
    for (int k0 = 0; k0 < K; k0 += 32) {
        gload16(&Au[(size_t)(row0 + ar) * lda + k0 + ac],      &As[ar][ac]);
        gload16(&Au[(size_t)(row0 + 64 + ar) * lda + k0 + ac], &As[64 + ar][ac]);
        gload16(&Wu[(size_t)(col0 + ar) * ldw + k0 + ac],      &Bs[ar][ac]);
        __syncthreads();   // compiler emits vmcnt(0) drain before barrier
        v8s bfr[4];
        #pragma unroll
        for (int ni = 0; ni < 4; ni++)
            bfr[ni] = *(const v8s*)&Bs[ni * 16 + mr][quad * 8];
        #pragma unroll
        for (int s = 0; s < 2; s++) {
            v8s a = *(const v8s*)&As[wave * 32 + s * 16 + mr][quad * 8];
            #pragma unroll
            for (int ni = 0; ni < 4; ni++)
                acc[s][ni] = __builtin_amdgcn_mfma_f32_16x16x32_bf16(
                    a, bfr[ni], acc[s][ni], 0, 0, 0);
        }
        __syncthreads();
    }
    if (OM == 1) {
        bf16* outb = (bf16*)outF;
        #pragma unroll
        for (int ni = 0; ni < 4; ni++) {
            int gc = col0 + ni * 16 + mr;
            if (gc >= N) continue;
            float bv = bias[gc];
            int sec = gc / 180, rem = gc - sec * 180;
            int hh = rem / 30, d = rem - hh * 30;
            int slot = sec * 192 + hh * 32 + d;
            float sc = (sec == 0) ? 0.18257418583505536f : 1.f;
            #pragma unroll
            for (int s = 0; s < 2; s++) {
                #pragma unroll
                for (int r = 0; r < 4; r++) {
                    int gr = row0 + wave * 32 + s * 16 + quad * 4 + r;
                    outb[(size_t)gr * QKVP + slot] =
                        __float2bfloat16((acc[s][ni][r] + bv) * sc);
                }
            }
        }
        return;
    }
    #pragma unroll
    for (int ni = 0; ni < 4; ni++) {
        int gc = col0 + ni * 16 + mr;
        if (gc >= N) continue;
        float bv = BIAS_ ? bias[gc] : 0.f;
        #pragma unroll
        for (int s = 0; s < 2; s++) {
            #pragma unroll
            for (int r = 0; r < 4; r++) {
                int gr = row0 + wave * 32 + s * 16 + quad * 4 + r;
                float v = acc[s][ni][r] + bv;
                if (GELU_) v = gelu_exact(v);
                if (ADDRES) v += res[(size_t)gr * ldr + gc];
                outF[(size_t)gr * ldo + gc] = v;
            }
        }
    }
}

// ---------------- batched AV GEMM: acc[b] = P[b]@vvT[b] + x[b] -------------
// grid (3, 64, 8). P bf16 [b][4096][64]; vvT bf16 [b][192][64]; K=64.
__global__ __launch_bounds__(256) void av_mgemm_kernel(
        const bf16* __restrict__ P, const bf16* __restrict__ vvT,
        const float* __restrict__ xres, float* __restrict__ accout)
{
    __shared__ unsigned short As[64][32];
    __shared__ unsigned short Bs[64][32];
    int tid = threadIdx.x;
    int wave = tid >> 6, lane = tid & 63;
    int quad = lane >> 4, mr = lane & 15;
    int row0 = blockIdx.y * 64, col0 = blockIdx.x * 64;
    int bz = blockIdx.z;
    const unsigned short* Au = (const unsigned short*)P + (size_t)bz * NTOK * MDICT;
    const unsigned short* Wu = (const unsigned short*)vvT + (size_t)bz * 192 * MDICT;
    const float* res = xres + (size_t)bz * NTOK * CDIM;
    float* outF = accout + (size_t)bz * NTOK * CDIM;
    f32x4 z = {0.f, 0.f, 0.f, 0.f};
    f32x4 acc[4] = {z, z, z, z};
    for (int k0 = 0; k0 < MDICT; k0 += 32) {
        #pragma unroll
        for (int e = 0; e < 8; e++) {
            int idx = tid * 8 + e;
            int r = idx >> 5, c = idx & 31;
            As[r][c] = Au[(size_t)(row0 + r) * MDICT + k0 + c];
            Bs[r][c] = Wu[(size_t)(col0 + r) * MDICT + k0 + c];
        }
        __syncthreads();
        v8s a;
        #pragma unroll
        for (int j = 0; j < 8; j++) a[j] = (short)As[wave * 16 + mr][quad * 8 + j];
        #pragma unroll
        for (int ni = 0; ni < 4; ni++) {
            v8s b;
            #pragma unroll
            for (int j = 0; j < 8; j++) b[j] = (short)Bs[ni * 16 + mr][quad * 8 + j];
            acc[ni] = __builtin_amdgcn_mfma_f32_16x16x32_bf16(a, b, acc[ni], 0, 0, 0);
        }
        __syncthreads();
    }
    #pragma unroll
    for (int ni = 0; ni < 4; ni++) {
        int gc = col0 + ni * 16 + mr;
        if (gc >= CDIM) continue;
        #pragma unroll
        for (int r = 0; r < 4; r++) {
            int gr = row0 + wave * 16 + quad * 4 + r;
            float v = acc[ni][r] + res[(size_t)gr * CDIM + gc];
            outF[(size_t)gr * CDIM + gc] = v;
        }
    }
}

// ---------------- Window attention, MFMA flash (bf16 KP1 out) --------------
// R12 structure + R19 bf16-qkv input: Q/K/V loaded as aligned v8s from the
// padded [ROWS][576] layout (Q pre-scaled, pads zero) — no f2b at load.
__global__ __launch_bounds__(256, 4) void win_mfma_kernel(const bf16* __restrict__ qkvb,
        const float* __restrict__ bias_t, bf16* __restrict__ outb)
{
    int b = blockIdx.y;
    int widx = blockIdx.x / NHEADS;
    int hh = blockIdx.x % NHEADS;
    int wy = widx >> 2, wx = widx & 3;
    int tid = threadIdx.x;
    int wave = tid >> 6, lane = tid & 63, quad = lane >> 4, mr = lane & 15;
    __shared__ __align__(16) unsigned short Ks[64][40];
    __shared__ __align__(16) unsigned short Vt[32][80];

    size_t brow = (size_t)b * NTOK;
    const unsigned short* qu = (const unsigned short*)qkvb;

    v8s aq[4];
    #pragma unroll
    for (int tt = 0; tt < 4; tt++) {
        int m = (wave * 4 + tt) * 16 + mr;
        int nt_ = (wy * WS + (m >> 4)) * 64 + wx * WS + (m & 15);
        aq[tt] = *(const v8s*)&qu[(brow + nt_) * QKVP + hh * 32 + quad * 8];
    }
    f32x4 z = {0.f, 0.f, 0.f, 0.f};
    f32x4 oacc[4][2] = {{z, z}, {z, z}, {z, z}, {z, z}};
    float m_r[4], l_r[4];
    #pragma unroll
    for (int tt = 0; tt < 4; tt++) { m_r[tt] = -3.0e38f; l_r[tt] = 0.f; }
    const float* btab = bias_t + (size_t)hh * WIN_N * WIN_N;

    for (int kc = 0; kc < WIN_N; kc += 64) {
        {
            int j = tid >> 2, dg = (tid & 3) * 8;
            int tok = kc + j;
            int nt_ = (wy * WS + (tok >> 4)) * 64 + wx * WS + (tok & 15);
            const unsigned short* base = qu + (brow + nt_) * QKVP + hh * 32;
            v8s kv = *(const v8s*)&base[192 + dg];
            v8s vv = *(const v8s*)&base[384 + dg];
            *(v8s*)&Ks[j][dg] = kv;
            #pragma unroll
            for (int jj = 0; jj < 8; jj++)
                Vt[dg + jj][j] = (unsigned short)vv[jj];
        }
        __syncthreads();
        #pragma unroll
        for (int tt = 0; tt < 4; tt++) {
            // --- QK^T swapped: s[nt][r] = S[key=kc+nt*16+quad*4+r][query] ---
            f32x4 s[4];
            #pragma unroll
            for (int nt = 0; nt < 4; nt++) {
                v8s bk = *(const v8s*)&Ks[nt * 16 + mr][quad * 8];
                s[nt] = __builtin_amdgcn_mfma_f32_16x16x32_bf16(bk, aq[tt], z, 0, 0, 0);
            }
            int qg = (wave * 4 + tt) * 16 + mr;
            const float* bi = btab + (size_t)qg * WIN_N + kc;
            float mc = -3.0e38f;
            #pragma unroll
            for (int nt = 0; nt < 4; nt++) {
                f32x4 b4 = *(const f32x4*)(bi + nt * 16 + quad * 4);
                s[nt][0] += b4[0]; s[nt][1] += b4[1];
                s[nt][2] += b4[2]; s[nt][3] += b4[3];
                mc = fmaxf(mc, fmaxf(fmaxf(s[nt][0], s[nt][1]),
                                     fmaxf(s[nt][2], s[nt][3])));
            }
            mc = fmaxf(mc, __shfl_xor(mc, 16, 64));
            mc = fmaxf(mc, __shfl_xor(mc, 32, 64));
            float mn = fmaxf(m_r[tt], mc);
            float alpha = __expf(m_r[tt] - mn);
            m_r[tt] = mn;
            float ls = 0.f;
            #pragma unroll
            for (int nt = 0; nt < 4; nt++) {
                #pragma unroll
                for (int r = 0; r < 4; r++) {
                    float pp = __expf(s[nt][r] - mn);
                    ls += pp;
                    s[nt][r] = pp;
                }
            }
            ls += __shfl_xor(ls, 16, 64);
            ls += __shfl_xor(ls, 32, 64);
            l_r[tt] = l_r[tt] * alpha + ls;
            // --- pack P (bf16 pairs): dpk[nt][s] = keys nt*16+quad*4+{2s,2s+1}
            unsigned dpk[4][2];
            #pragma unroll
            for (int nt = 0; nt < 4; nt++) {
                dpk[nt][0] = packbf(s[nt][0], s[nt][1]);
                dpk[nt][1] = packbf(s[nt][2], s[nt][3]);
            }
            // --- rescale oacc rows (query = quad*4+r) by alpha ---
            #pragma unroll
            for (int r = 0; r < 4; r++) {
                float av = __shfl(alpha, quad * 4 + r, 64);
                oacc[tt][0][r] *= av;
                oacc[tt][1][r] *= av;
            }
            // --- PV: build A-frags via cross-lane shuffle, 2 chunks of K=32 --
            #pragma unroll
            for (int c = 0; c < 2; c++) {
                union { u32x4 u; v8s s8; } afu;
                #pragma unroll
                for (int t = 0; t < 4; t++) {
                    int srcl = (((quad * 2 + (t >> 1)) & 3) << 4) | mr;
                    unsigned r0 = (unsigned)__shfl((int)dpk[2 * c][t & 1], srcl, 64);
                    unsigned r1 = (unsigned)__shfl((int)dpk[2 * c + 1][t & 1], srcl, 64);
                    afu.u[t] = (quad & 2) ? r1 : r0;
                }
                #pragma unroll
                for (int dt = 0; dt < 2; dt++) {
                    v8s bv = *(const v8s*)&Vt[dt * 16 + mr][c * 32 + quad * 8];
                    oacc[tt][dt] = __builtin_amdgcn_mfma_f32_16x16x32_bf16(
                        afu.s8, bv, oacc[tt][dt], 0, 0, 0);
                }
            }
        }
        __syncthreads();
    }
    #pragma unroll
    for (int tt = 0; tt < 4; tt++) {
        float il = 1.f / l_r[tt];
        #pragma unroll
        for (int r = 0; r < 4; r++) {
            float ilr = __shfl(il, quad * 4 + r, 64);
            int m = (wave * 4 + tt) * 16 + quad * 4 + r;
            int nt_ = (wy * WS + (m >> 4)) * 64 + wx * WS + (m & 15);
            #pragma unroll
            for (int dt = 0; dt < 2; dt++) {
                int d = dt * 16 + mr;
                if (d >= HD) continue;
                outb[(brow + nt_) * KP1 + hh * HD + d] =
                    __float2bfloat16(oacc[tt][dt][r] * ilr);
            }
        }
    }
}

// ---------------- AC_MSA, MFMA flash, swapped QK^T -------------------------
// R17 structure + R19 bf16-qkv input (v8s loads, toks[] indirection).
__global__ __launch_bounds__(256, 4) void acmsa_mfma_kernel(const bf16* __restrict__ qkvb,
        const int* __restrict__ sidx, bf16* __restrict__ outb)
{
    int b = blockIdx.y;
    int g = blockIdx.x / NHEADS;
    int hh = blockIdx.x % NHEADS;
    int tid = threadIdx.x;
    int wave = tid >> 6, lane = tid & 63, quad = lane >> 4, mr = lane & 15;
    __shared__ int toks[GS];
    __shared__ __align__(16) unsigned short Ks[64][40];
    __shared__ __align__(16) unsigned short Vt[32][80];

    size_t brow = (size_t)b * NTOK;
    if (tid < GS) toks[tid] = sidx[brow + (size_t)g * GS + tid];
    __syncthreads();
    const unsigned short* qu = (const unsigned short*)qkvb;

    v8s aq[2];
    #pragma unroll
    for (int tt = 0; tt < 2; tt++) {
        int m = (wave * 2 + tt) * 16 + mr;
        aq[tt] = *(const v8s*)&qu[(brow + toks[m]) * QKVP + hh * 32 + quad * 8];
    }
    f32x4 z = {0.f, 0.f, 0.f, 0.f};
    f32x4 oacc[2][2] = {{z, z}, {z, z}};
    float m_r[2], l_r[2];
    #pragma unroll
    for (int tt = 0; tt < 2; tt++) { m_r[tt] = -3.0e38f; l_r[tt] = 0.f; }

    for (int kc = 0; kc < GS; kc += 64) {
        {
            int j = tid >> 2, dg = (tid & 3) * 8;
            int tok = toks[kc + j];
            const unsigned short* base = qu + (brow + tok) * QKVP + hh * 32;
            v8s kv = *(const v8s*)&base[192 + dg];
            v8s vv = *(const v8s*)&base[384 + dg];
            *(v8s*)&Ks[j][dg] = kv;
            #pragma unroll
            for (int jj = 0; jj < 8; jj++)
                Vt[dg + jj][j] = (unsigned short)vv[jj];
        }
        __syncthreads();
        #pragma unroll
        for (int tt = 0; tt < 2; tt++) {
            // --- QK^T swapped: s[nt][r] = S[key=kc+nt*16+quad*4+r][query=mr]
            f32x4 s[4];
            #pragma unroll
            for (int nt = 0; nt < 4; nt++) {
                v8s bk = *(const v8s*)&Ks[nt * 16 + mr][quad * 8];
                s[nt] = __builtin_amdgcn_mfma_f32_16x16x32_bf16(bk, aq[tt], z, 0, 0, 0);
            }
            float mc = -3.0e38f;
            #pragma unroll
            for (int nt = 0; nt < 4; nt++)
                mc = fmaxf(mc, fmaxf(fmaxf(s[nt][0], s[nt][1]),
                                     fmaxf(s[nt][2], s[nt][3])));
            mc = fmaxf(mc, __shfl_xor(mc, 16, 64));
            mc = fmaxf(mc, __shfl_xor(mc, 32, 64));
            float mn = fmaxf(m_r[tt], mc);
            float alpha = __expf(m_r[tt] - mn);
            m_r[tt] = mn;
            float ls = 0.f;
            #pragma unroll
            for (int nt = 0; nt < 4; nt++) {
                #pragma unroll
                for (int r = 0; r < 4; r++) {
                    float pp = __expf(s[nt][r] - mn);
                    ls += pp;
                    s[nt][r] = pp;
                }
            }
            ls += __shfl_xor(ls, 16, 64);
            ls += __shfl_xor(ls, 32, 64);
            l_r[tt] = l_r[tt] * alpha + ls;
            unsigned dpk[4][2];
            #pragma unroll
            for (int nt = 0; nt < 4; nt++) {
                dpk[nt][0] = packbf(s[nt][0], s[nt][1]);
                dpk[nt][1] = packbf(s[nt][2], s[nt][3]);
            }
            #pragma unroll
            for (int r = 0; r < 4; r++) {
                float av = __shfl(alpha, quad * 4 + r, 64);
                oacc[tt][0][r] *= av;
                oacc[tt][1][r] *= av;
            }
            #pragma unroll
            for (int c = 0; c < 2; c++) {
                union { u32x4 u; v8s s8; } afu;
                #pragma unroll
                for (int t = 0; t < 4; t++) {
                    int srcl = (((quad * 2 + (t >> 1)) & 3) << 4) | mr;
                    unsigned r0 = (unsigned)__shfl((int)dpk[2 * c][t & 1], srcl, 64);
                    unsigned r1 = (unsigned)__shfl((int)dpk[2 * c + 1][t & 1], srcl, 64);
                    afu.u[t] = (quad & 2) ? r1 : r0;
                }
                #pragma unroll
                for (int dt = 0; dt < 2; dt++) {
                    v8s bv = *(const v8s*)&Vt[dt * 16 + mr][c * 32 + quad * 8];
                    oacc[tt][dt] = __builtin_amdgcn_mfma_f32_16x16x32_bf16(
                        afu.s8, bv, oacc[tt][dt], 0, 0, 0);
                }
            }
        }
        __syncthreads();
    }
    #pragma unroll
    for (int tt = 0; tt < 2; tt++) {
        float il = 1.f / l_r[tt];
        #pragma unroll
        for (int r = 0; r < 4; r++) {
            float ilr = __shfl(il, quad * 4 + r, 64);
            int m = (wave * 2 + tt) * 16 + quad * 4 + r;
            int tok = toks[m];
            #pragma unroll
            for (int dt = 0; dt < 2; dt++) {
                int d = dt * 16 + mr;
                if (d >= HD) continue;
                outb[(brow + tok) * KP1 + hh * HD + d] =
                    __float2bfloat16(oacc[tt][dt][r] * ilr);
            }
        }
    }
}

// ---------------- LayerNorm: fp32 out + fused bf16 KP1-padded out ----------
__global__ __launch_bounds__(64) void ln_kernel(const float* __restrict__ x,
        const float* __restrict__ g, const float* __restrict__ be,
        float* __restrict__ out, bf16* __restrict__ outb)
{
    int row = blockIdx.x; int t = threadIdx.x;
    const float* xr = x + (size_t)row * CDIM;
    float v0 = xr[t];
    float v1 = xr[t + 64];
    float v2 = (t < CDIM - 128) ? xr[t + 128] : 0.f;
    float s1 = wave_sum(v0 + v1 + v2);
    float s2 = wave_sum(v0*v0 + v1*v1 + v2*v2);
    float mu = s1 / (float)CDIM;
    float var = s2 / (float)CDIM - mu * mu;
    float rs = rsqrtf(var + 1e-5f);
    float o0 = (v0 - mu) * rs * g[t]      + be[t];
    float o1 = (v1 - mu) * rs * g[t + 64] + be[t + 64];
    float o2 = (t < CDIM - 128) ? ((v2 - mu) * rs * g[t + 128] + be[t + 128]) : 0.f;
    float* o = out + (size_t)row * CDIM;
    o[t] = o0; o[t + 64] = o1;
    if (t < CDIM - 128) o[t + 128] = o2;
    bf16* ob = outb + (size_t)row * KP1;
    ob[t]       = __float2bfloat16(o0);
    ob[t + 64]  = __float2bfloat16(o1);
    ob[t + 128] = __float2bfloat16(o2);   // cols 180..191 get 0 (t>=52 -> o2=0)
}

// ---------------- Dictionary precompute: kkn (l2), vvT bf16, td_proj -------
__global__ __launch_bounds__(64) void td_pre_kernel(const float* __restrict__ td,
        const float* __restrict__ wk, const float* __restrict__ wkb,
        const float* __restrict__ wv, const float* __restrict__ wvb,
        const float* __restrict__ wtd, const float* __restrict__ wtdb,
        float* __restrict__ kkn, bf16* __restrict__ vvT, float* __restrict__ tdp)
{
    int blk = blockIdx.x;   // b*64 + m
    int b = blk >> 6, m = blk & 63;
    int t = threadIdx.x;
    __shared__ float tr[CDIM];
    __shared__ float sk[RD];
    __shared__ float snorm;
    const float* tdr = td + (size_t)blk * CDIM;
    tr[t] = tdr[t]; tr[t + 64] = tdr[t + 64];
    if (t < CDIM - 128) tr[t + 128] = tdr[t + 128];
    __syncthreads();
    if (t < RD) {
        float s = wkb[t];
        for (int k = 0; k < CDIM; k++) s += tr[k] * wk[k * RD + t];
        sk[t] = s;
    }
    __syncthreads();
    if (t == 0) {
        float s = 0.f;
        #pragma unroll
        for (int j = 0; j < RD; j++) s += sk[j] * sk[j];
        snorm = fmaxf(sqrtf(s), 1e-12f);
    }
    __syncthreads();
    if (t < RD) kkn[(size_t)blk * RD + t] = sk[t] / snorm;
    // vvT[b][c][m] bf16, c padded to 192 (tail rows zero)
    for (int c = t; c < 192; c += 64) {
        float s = 0.f;
        if (c < CDIM) {
            s = wvb[c];
            for (int k = 0; k < CDIM; k++) s += tr[k] * wv[k * CDIM + c];
        }
        vvT[((size_t)(b * 192 + c)) * MDICT + m] = __float2bfloat16(s);
    }
    {
        float s = wtdb[t];
        for (int k = 0; k < CDIM; k++) s += tr[k] * wtd[k * DTD + t];
        tdp[(size_t)blk * DTD + t] = s;
    }
}

// ---------------- ATD softmax/argmax (fp32 exact logits, P bf16 out) -------
__global__ __launch_bounds__(64) void atd_soft_kernel(const float* __restrict__ xn,
        const float* __restrict__ wq, const float* __restrict__ wqb,
        const float* __restrict__ scale_p, const float* __restrict__ kkn,
        bf16* __restrict__ Pout, int* __restrict__ tk_id)
{
    int row = blockIdx.x;
    int b = row >> 12;
    int t = threadIdx.x;
    const float* xrow = xn + (size_t)row * CDIM;
    float v0 = xrow[t];
    float v1 = xrow[t + 64];
    float v2 = (t < CDIM - 128) ? xrow[t + 128] : 0.f;
    // q-proj: all 64 lanes contribute; wave_sum broadcasts result to all lanes
    float sq[RD];
    #pragma unroll
    for (int j = 0; j < RD; j++) {
        float part = v0 * wq[t * RD + j] + v1 * wq[(t + 64) * RD + j];
        if (t < CDIM - 128) part += v2 * wq[(t + 128) * RD + j];
        sq[j] = wave_sum(part) + wqb[j];
    }
    float qn = 0.f;
    #pragma unroll
    for (int j = 0; j < RD; j++) qn += sq[j] * sq[j];
    qn = fmaxf(sqrtf(qn), 1e-12f);
    float ls = 1.0f + fminf(fmaxf(scale_p[0], 0.f), 3.f) * 4.158883083359672f;
    const float* kr = kkn + ((size_t)b * MDICT + t) * RD;
    float s = 0.f;
    #pragma unroll
    for (int j = 0; j < RD; j++) s += sq[j] * kr[j];
    s = s / qn * ls;
    // 64-lane softmax + first-index argmax (fp32 exact)
    float mv = s; int mi = t;
    #pragma unroll
    for (int off = 32; off > 0; off >>= 1) {
        float ov = __shfl_xor(mv, off, 64);
        int   oi = __shfl_xor(mi, off, 64);
        if (ov > mv || (ov == mv && oi < mi)) { mv = ov; mi = oi; }
    }
    float e = __expf(s - mv);
    float denom = wave_sum(e);
    Pout[(size_t)row * MDICT + t] = __float2bfloat16(e / denom);
    if (t == 0) tk_id[row] = mi;
}

// ---------------- Stable counting sort of tk_id ----------------------------
__global__ __launch_bounds__(256) void sort_kernel(const int* __restrict__ tk_id,
                                                   int* __restrict__ sidx)
{
    int b = blockIdx.x; int tid = threadIdx.x;
    __shared__ int keys[NTOK];
    __shared__ int cnt[256];
    __shared__ int off[256];
    const int* kb = tk_id + (size_t)b * NTOK;
    for (int i = tid; i < NTOK; i += 256) keys[i] = kb[i];
    __syncthreads();
    int v = tid >> 2, seg = tid & 3;
    int lo = seg * 1024, hi = lo + 1024;
    int c = 0;
    for (int i = lo; i < hi; i++) c += (keys[i] == v);
    cnt[tid] = c;
    __syncthreads();
    if (tid == 0) {
        int run = 0;
        for (int l = 0; l < 256; l++) { off[l] = run; run += cnt[l]; }
    }
    __syncthreads();
    int o = off[tid];
    int* sb = sidx + (size_t)b * NTOK;
    for (int i = lo; i < hi; i++) if (keys[i] == v) sb[o++] = i;
}

// ---------------- Gather dictionary features into hc[:, 360:424] -----------
__global__ __launch_bounds__(256) void gather_td_kernel(const int* __restrict__ tk_id,
        const float* __restrict__ tdp, float* __restrict__ hc)
{
    int idx = blockIdx.x * 256 + threadIdx.x;
    int row = idx >> 6, j = idx & 63;
    int b = row >> 12;
    int tk = tk_id[row];
    hc[(size_t)row * CCAT + MHID + j] = tdp[((size_t)b * MDICT + tk) * DTD + j];
}

// ---------------- Depthwise 5x5 conv: CHK=64, 8x8 tile, bf16 KP2 out -------
// R15 base (proven: conflicts 0, VGPR 68, writes ideal) + R19: weights read
// from L2-resident global wT[25][448] fp32 (4-lane broadcast f32x4) instead
// of LDS -> LDS issues 204->104 b128/thread; LDS 45.5->39.2KB (4 blocks/CU).
#define CHK3 64
#define CTW  8
#define CTH  8
#define CHW  12     // halo width/height = tile + 4
#define CHP  144    // 12*12 halo pixels
#define CSPX 68     // floats per pixel row (64 + 4 pad) = 272B, 16B-aligned
__global__ __launch_bounds__(256) void conv_kernel(const float* __restrict__ hc,
        const float* __restrict__ wT, const float* __restrict__ wb,
        bf16* __restrict__ outb)
{
    int ch0 = blockIdx.x * CHK3;        // 0,64,...,384 (7 blocks; 424..447 zeroed)
    int tile = blockIdx.y;              // 64 tiles of 8x8
    int b = blockIdx.z;
    int ty0 = (tile >> 3) * CTH, tx0 = (tile & 7) * CTW;
    __shared__ __align__(16) float sh[CHP][CSPX];   // 39168 B
    int tid = threadIdx.x;
    // stage input: lanes cover 64 contiguous channels of one pixel (256B)
    for (int idx = tid; idx < CHP * CHK3; idx += 256) {
        int pix = idx >> 6, ch = idx & 63;
        int gy = ty0 + pix / CHW - 2, gx = tx0 + pix % CHW - 2;
        int chg = ch0 + ch;
        float v = 0.f;
        if (gy >= 0 && gy < 64 && gx >= 0 && gx < 64 && chg < CCAT)
            v = hc[((size_t)b * NTOK + gy * 64 + gx) * CCAT + chg];
        sh[pix][ch] = v;
    }
    __syncthreads();
    int q = tid & 3, p = tid >> 2;      // p: pixel 0..63; q: 16-ch subgroup
    int px = p & 7, py = p >> 3;
    int cb = q * 16;
    int pc = py * CHW + px;             // top-left of 5x5 window
    v8s pk0, pk1;
    #pragma unroll
    for (int sub = 0; sub < 4; sub++) {
        int cs = cb + sub * 4;
        const float* wtc = wT + ch0 + cs;   // column base in wT[25][448]
        f32x4 acc = {0.f, 0.f, 0.f, 0.f};
        #pragma unroll
        for (int dy = 0; dy < 5; dy++) {
            #pragma unroll
            for (int dx = 0; dx < 5; dx++) {
                f32x4 sv = *(const f32x4*)&sh[pc + dy * CHW + dx][cs];
                f32x4 wv = *(const f32x4*)&wtc[(dy * 5 + dx) * KP2];
                acc += sv * wv;
            }
            __builtin_amdgcn_sched_barrier(0);   // cap hoisting at one row
        }
        f32x4 ctr = *(const f32x4*)&sh[pc + 2 * CHW + 2][cs];
        #pragma unroll
        for (int c = 0; c < 4; c++) {
            int chg = ch0 + cs + c;
            float v = 0.f;
            if (chg < CCAT) {
                float gv = gelu_exact(acc[c] + wb[chg]);
                v = ctr[c] + gv;
            }
            int lc = sub * 4 + c;
            if (lc < 8) pk0[lc] = (short)f2b(v);
            else        pk1[lc - 8] = (short)f2b(v);
        }
        __builtin_amdgcn_sched_barrier(0);
    }
    size_t obase = ((size_t)b * NTOK + (ty0 + py) * 64 + tx0 + px) * KP2 + ch0 + cb;
    unsigned short* ob = (unsigned short*)outb + obase;   // 32B-aligned
    *(v8s*)ob = pk0;
    *(v8s*)(ob + 8) = pk1;
}

// ---------------------------------------------------------------------------
extern "C" void kernel_launch(void* const* d_in, const int* in_sizes, int n_in,
                              void* d_out, int out_size, void* d_ws, size_t ws_size,
                              hipStream_t stream)
{
    (void)n_in; (void)ws_size; (void)out_size;
    const int* rpi = (const int*)d_in[28];

    // ---- workspace carve-up ----
    float* p = (float*)d_ws;
    float* xn    = p; p += (size_t)ROWS * CDIM;
    float* acc   = p; p += (size_t)ROWS * CDIM;
    float* tmp1  = p; p += (size_t)ROWS * CDIM;    // alias: P bf16 (head), fc2 out
    float* qkv   = p; p += (size_t)ROWS * C3;      // alias: qkvb bf16; hc fp32 post-win
    float* hcnew = p; p += (size_t)ROWS * CCAT;    // alias: xnb/tmp1b; then conv bf16 out
    float* kkn   = p; p += (size_t)BB * MDICT * RD;
    bf16*  vvT   = (bf16*)p; p += (size_t)BB * 192 * MDICT / 2;   // bf16 [8][192][64]
    float* tdp   = p; p += (size_t)BB * MDICT * DTD;
    int*   tk_id = (int*)p; p += ROWS;
    int*   sidx  = (int*)p; p += ROWS;
    int*   flag  = (int*)p; p += 64;
    int*   diag  = (int*)p; p += 64;
    bf16* wtqkv = (bf16*)p; p += 576 * KP1 / 2;
    bf16* wtaca = (bf16*)p; p += 192 * KP1 / 2;
    bf16* wtwin = (bf16*)p; p += 192 * KP1 / 2;
    bf16* wtfc1 = (bf16*)p; p += 384 * KP1 / 2;
    bf16* wtfc2 = (bf16*)p; p += 192 * KP2 / 2;
    float* cin[28];
    for (int i = 0; i < 28; i++) { cin[i] = p; p += in_sizes[i]; }
    float* bias_t = p; p += (size_t)NHEADS * WIN_N * WIN_N;   // 1.5 MB
    float* wT     = p; p += 25 * KP2;                         // conv weights [25][448]

    float* hc      = qkv;                // fp32 [ROWS,CCAT]; born after win (qkv dead)
    bf16*  qkvb    = (bf16*)qkv;         // bf16 [ROWS,576] padded; dies at win
    bf16*  xnb     = (bf16*)hcnew;                            // [ROWS,KP1]; dies at fc1
    bf16*  tmp1b   = (bf16*)(hcnew + (size_t)ROWS * KP1 / 2); // [ROWS,KP1]; dies at winp
    bf16*  hcnewb2 = (bf16*)hcnew;       // [ROWS,KP2] bf16; born at conv
    bf16*  Pbuf    = (bf16*)tmp1;        // [ROWS,64] bf16 = 4MB; dies after av_mgemm
                                         // (tmp1 fp32 reborn at fc2 much later)

    // ---- dtype detect (+diag=0) + batched input normalize to fp32 ----
    detect_kernel<<<1, 256, 0, stream>>>(d_in[0], flag, diag);
    {
        CvtArgs ca;
        int total = 0, s = 0;
        for (int i = 0; i < 28; i++) {
            if (i == 4 || i == 13 || i == 16 || i == 20 || i == 24) continue;
            ca.src[s] = d_in[i];
            ca.dst[s] = cin[i];
            ca.cum[s] = total;
            total += in_sizes[i];
            s++;
        }
        ca.cum[s] = total;
        convert_all_kernel<<<(total + 255) / 256, 256, 0, stream>>>(ca, total, flag);
    }
    const float *x = cin[0], *td = cin[1], *n1g = cin[2], *n1b = cin[3],
        *wqkv_b = cin[5], *wq_w = cin[6], *wq_b = cin[7],
        *wk_w = cin[8], *wk_b = cin[9], *wv_w = cin[10], *wv_b = cin[11],
        *atd_scale = cin[12], *aca_b = cin[14], *win_rpb = cin[15],
        *winp_b = cin[17], *fctd_w = cin[18], *fctd_b = cin[19],
        *fc1_b = cin[21], *dw_w = cin[22], *dw_b = cin[23], *fc2_b = cin[25],
        *n2g = cin[26], *n2b = cin[27];

    // ---- adaptive weight repacks (by value) + bias table ----
    packW_kernel<<<576 * KP1 / 256, 256, 0, stream>>>(d_in[4],  wtqkv, CDIM, C3,   KP1, 576 * KP1, flag);
    packW_kernel<<<192 * KP1 / 256, 256, 0, stream>>>(d_in[13], wtaca, CDIM, CDIM, KP1, 192 * KP1, flag);
    packW_kernel<<<192 * KP1 / 256, 256, 0, stream>>>(d_in[16], wtwin, CDIM, CDIM, KP1, 192 * KP1, flag);
    packW_kernel<<<384 * KP1 / 256, 256, 0, stream>>>(d_in[20], wtfc1, CDIM, MHID, KP1, 384 * KP1, flag);
    packW_kernel<<<192 * KP2 / 256, 256, 0, stream>>>(d_in[24], wtfc2, CCAT, CDIM, KP2, 192 * KP2, flag);
    bias_pre_kernel<<<NHEADS * WIN_N * WIN_N / 256, 256, 0, stream>>>(rpi, win_rpb, bias_t);
    packWT_kernel<<<(25 * KP2 + 255) / 256, 256, 0, stream>>>(dw_w, wT);

    td_pre_kernel<<<BB * MDICT, 64, 0, stream>>>(td, wk_w, wk_b, wv_w, wv_b,
                                                 fctd_w, fctd_b, kkn, vvT, tdp);
    // LN1 with fused bf16-KP1 output
    ln_kernel<<<ROWS, 64, 0, stream>>>(x, n1g, n1b, xn, xnb);
    // qkv gemm: bf16 padded output (Q pre-scaled), then zero pad slots
    mgemm_kernel<false, false, true, 1><<<dim3(9, ROWS / 128), 256, 0, stream>>>(
        xnb, KP1, wtqkv, KP1, wqkv_b, nullptr, 0, (float*)qkvb, QKVP, C3, KP1);
    zero_qkvpad_kernel<<<ROWS * 36 / 256, 256, 0, stream>>>(qkvb);
    // ATD: fp32 softmax/argmax -> P bf16 + tk_id; then batched MFMA AV
    atd_soft_kernel<<<ROWS, 64, 0, stream>>>(xn, wq_w, wq_b, atd_scale, kkn, Pbuf, tk_id);
    av_mgemm_kernel<<<dim3(3, NTOK / 64, BB), 256, 0, stream>>>(Pbuf, vvT, x, acc);
    sort_kernel<<<BB, 256, 0, stream>>>(tk_id, sidx);
    // zero K-tail of tmp1b once; both attentions leave cols 180..191 untouched
    zero_tail_kernel<<<ROWS * 12 / 256, 256, 0, stream>>>(tmp1b);
    // MFMA flash AC_MSA -> tmp1b (bf16 direct)
    acmsa_mfma_kernel<<<dim3(NG * NHEADS, BB), 256, 0, stream>>>(qkvb, sidx, tmp1b);
    mgemm_kernel<false, true, true, 0><<<dim3(3, ROWS / 128), 256, 0, stream>>>(
        tmp1b, KP1, wtaca, KP1, aca_b, acc, CDIM, acc, CDIM, CDIM, KP1);
    // MFMA flash window attention -> tmp1b (bf16 direct)
    win_mfma_kernel<<<dim3(16 * NHEADS, BB), 256, 0, stream>>>(qkvb, bias_t, tmp1b);
    mgemm_kernel<false, true, true, 0><<<dim3(3, ROWS / 128), 256, 0, stream>>>(
        tmp1b, KP1, wtwin, KP1, winp_b, acc, CDIM, acc, CDIM, CDIM, KP1);
    // FFN: LN2 fused bf16 out -> fc1 -> gather -> conv (bf16 KP2 direct) -> fc2
    ln_kernel<<<ROWS, 64, 0, stream>>>(acc, n2g, n2b, xn, xnb);
    mgemm_kernel<true, false, true, 0><<<dim3(6, ROWS / 128), 256, 0, stream>>>(
        xnb, KP1, wtfc1, KP1, fc1_b, nullptr, 0, hc, CCAT, MHID, KP1);
    gather_td_kernel<<<ROWS * 64 / 256, 256, 0, stream>>>(tk_id, tdp, hc);
    conv_kernel<<<dim3(7, 64, BB), 256, 0, stream>>>(hc, wT, dw_b, hcnewb2);
    mgemm_kernel<false, true, true, 0><<<dim3(3, ROWS / 128), 256, 0, stream>>>(
        hcnewb2, KP2, wtfc2, KP2, fc2_b, acc, CDIM, tmp1, CDIM, CDIM, KP2);
    check_f32_kernel<<<(ROWS * CDIM + 255) / 256, 256, 0, stream>>>(tmp1, ROWS * CDIM, 8, diag);
    emit_kernel<<<(ROWS * CDIM + 255) / 256, 256, 0, stream>>>(
        tmp1, d_out, flag, diag, ROWS * CDIM);
}

// Round 9
// 721.120 us; speedup vs baseline: 1.0449x; 1.0449x over previous
//
#include <hip/hip_runtime.h>
#include <hip/hip_bf16.h>
#include <math.h>

// MPv2_3d_arch: B=8, n=64*64=4096, c=180, heads=6 (hd=30), dict M=64, rd=10,
// dtd=64, mlp_hid=360, cat C=424, window 16x16, groups of 128.
// R20: R19 (passing, 753us) post-mortem: conv wt-from-L2 exposed VMEM latency
// (143us) -> reverted to LDS weights. qkv-bf16 kept (neutral, fewer bytes).
// NEW conv compute shape: thread = 4 x-adjacent pixels x 4 ch (16 outputs,
// unchanged) with row-register sharing: per dy load 8 row positions + 5 taps,
// feed 4 accs -> LDS reads/thread 204 -> 69 b128. No cross-dy liveness (the
// R16 spill trap); sched_barrier(0) per dy. Staging vectorized f32x4.
// SESSION RULE: input dtype VARIES per run (bf16 or fp32) — every d_in
// access must go through *flag (by value). Raw-bit reads = NaN.
#define BB      8
#define NTOK    4096
#define CDIM    180
#define C3      540
#define NHEADS  6
#define HD      30
#define MDICT   64
#define RD      10
#define DTD     64
#define MHID    360
#define CCAT    424
#define WS      16
#define WIN_N   256
#define GS      128
#define NG      32
#define ROWS    (BB*NTOK)   // 32768
#define KP1     192         // Kpad for K=180
#define KP2     448         // Kpad for K=424
#define QKVP    576         // padded qkv row: 3 sec * 6 heads * 32

typedef __hip_bfloat16 bf16;
typedef short v8s __attribute__((ext_vector_type(8)));
typedef short v4s __attribute__((ext_vector_type(4)));
typedef float f32x4 __attribute__((ext_vector_type(4)));
typedef unsigned int u32x4 __attribute__((ext_vector_type(4)));

__device__ __forceinline__ float gelu_exact(float x) {
    return 0.5f * x * (1.0f + erff(x * 0.70710678118654752f));
}
__device__ __forceinline__ float wave_sum(float v) {
    #pragma unroll
    for (int off = 32; off > 0; off >>= 1) v += __shfl_xor(v, off, 64);
    return v;
}
// fp32 <-> bf16 bits without type-punning (RNE)
__device__ __forceinline__ unsigned short f2b(float v) {
    unsigned u = __float_as_uint(v);
    return (unsigned short)((u + 0x7FFFu + ((u >> 16) & 1u)) >> 16);
}
__device__ __forceinline__ float b2f(unsigned short h) {
    return __uint_as_float(((unsigned)h) << 16);
}
__device__ __forceinline__ unsigned packbf(float lo, float hi) {
    return (unsigned)f2b(lo) | ((unsigned)f2b(hi) << 16);
}
// async global->LDS 16B (gfx950); size must be literal; lds addr = per-lane
// slot in lane-order-contiguous slab (wave-uniform base + lane*16).
__device__ __forceinline__ void gload16(const void* g, void* l) {
    __builtin_amdgcn_global_load_lds(
        (const __attribute__((address_space(1))) void*)g,
        (__attribute__((address_space(3))) void*)l, 16, 0, 0);
}

// ---------------- dtype detector: flag=1 if inputs are fp32, 0 if bf16 -----
__global__ __launch_bounds__(256) void detect_kernel(const void* __restrict__ x,
                                                     int* __restrict__ flag,
                                                     int* __restrict__ diag)
{
    __shared__ int cnt;
    if (threadIdx.x == 0) { cnt = 0; *diag = 0; }
    __syncthreads();
    const unsigned short* u = (const unsigned short*)x;
    int c = 0;
    for (int i = threadIdx.x; i < 2048; i += 256) {
        unsigned short e = u[2 * i] & 0x7F80;
        if (e >= 0x4300) c++;
    }
    atomicAdd(&cnt, c);
    __syncthreads();
    if (threadIdx.x == 0) *flag = (cnt > 16) ? 1 : 0;
}

// ---------------- batched dtype-flexible input -> fp32 conversion ----------
#define NCVT 23
struct CvtArgs {
    const void* src[NCVT];
    float* dst[NCVT];
    int cum[NCVT + 1];
};
__global__ __launch_bounds__(256) void convert_all_kernel(CvtArgs a, int total,
        const int* __restrict__ flag)
{
    int i = blockIdx.x * 256 + threadIdx.x;
    if (i >= total) return;
    int s = 0;
    while (i >= a.cum[s + 1]) s++;   // x is segment 0 -> most threads exit fast
    int off = i - a.cum[s];
    if (*flag) a.dst[s][off] = ((const float*)a.src[s])[off];
    else       a.dst[s][off] = __bfloat162float(((const bf16*)a.src[s])[off]);
}

// ---------------- NaN/Inf check -> diag bit --------------------------------
__global__ __launch_bounds__(256) void check_f32_kernel(const float* __restrict__ buf,
        int n, int bit, int* __restrict__ diag)
{
    int i = blockIdx.x * 256 + threadIdx.x;
    if (i >= n) return;
    unsigned u = __float_as_uint(buf[i]);
    if ((u & 0x7F800000u) == 0x7F800000u) atomicOr(diag, bit);
}

// ---------------- output emit: fp32 src -> d_out in detected dtype ---------
__global__ __launch_bounds__(256) void emit_kernel(const float* __restrict__ src,
        void* __restrict__ out, const int* __restrict__ flag,
        const int* __restrict__ diag, int n)
{
    int i = blockIdx.x * 256 + threadIdx.x;
    if (i >= n) return;
    float v = src[i];
    int d = *diag;
    if (d) v = 100.f + 32.f * (float)d;   // NaN stage code -> absmax bin
    if (*flag) ((float*)out)[i] = v;
    else       ((bf16*)out)[i]  = __float2bfloat16(v);
}

// ---------------- zero cols 180..191 of a [ROWS,KP1] bf16 buffer -----------
__global__ __launch_bounds__(256) void zero_tail_kernel(bf16* __restrict__ buf)
{
    int idx = blockIdx.x * 256 + threadIdx.x;   // ROWS*12
    int row = idx / 12, c = idx % 12;
    buf[(size_t)row * KP1 + CDIM + c] = __float2bfloat16(0.f);
}

// ---------------- zero pad slots (d=30,31 per head/sec) of qkvb ------------
__global__ __launch_bounds__(256) void zero_qkvpad_kernel(bf16* __restrict__ qb)
{
    int idx = blockIdx.x * 256 + threadIdx.x;   // ROWS*36
    int row = idx / 36, r = idx % 36;
    int sec = r / 12, rr = r % 12, hh = rr >> 1, d = 30 + (rr & 1);
    qb[(size_t)row * QKVP + sec * 192 + hh * 32 + d] = __float2bfloat16(0.f);
}

// ---------------- adaptive weight repack: W[K,N] -> Wt[Npad,Kpad] bf16 -----
__global__ __launch_bounds__(256) void packW_kernel(const void* __restrict__ W,
        bf16* __restrict__ Wt, int K, int N, int Kpad, int total,
        const int* __restrict__ flag)
{
    int idx = blockIdx.x * 256 + threadIdx.x;
    if (idx >= total) return;
    int n = idx / Kpad, k = idx % Kpad;
    float v = 0.f;
    if (k < K && n < N) {
        size_t src = (size_t)k * N + n;
        v = (*flag) ? ((const float*)W)[src]
                    : __bfloat162float(((const bf16*)W)[src]);
    }
    Wt[idx] = __float2bfloat16(v);
}

// ---------------- window-attention bias table: [6][256][256] ---------------
__global__ __launch_bounds__(256) void bias_pre_kernel(const int* __restrict__ rpi,
        const float* __restrict__ rpb, float* __restrict__ bias_t)
{
    int idx = blockIdx.x * 256 + threadIdx.x;   // 6*65536
    int h = idx >> 16, ij = idx & 65535;
    bias_t[idx] = rpb[rpi[ij] * NHEADS + h];
}

// ---------------- MFMA GEMM: out = act(A@W [+bias]) [+ res] ----------------
// R18 structure: 128(M)x64(N) tile, 256 threads, global_load_lds staging,
// 8 MFMA/k-step/wave. OM=1 variant writes bf16 to padded qkv layout
// (slot = sec*192 + hh*32 + d), with Q section (sec==0) pre-scaled by scq.
template<bool GELU_, bool ADDRES, bool BIAS_, int OM>
__global__ __launch_bounds__(256) void mgemm_kernel(
        const bf16* __restrict__ A, int lda,
        const bf16* __restrict__ Wt, int ldw,
        const float* __restrict__ bias,
        const float* __restrict__ res, int ldr,
        float* __restrict__ outF, int ldo, int N, int K)
{
    __shared__ __align__(16) unsigned short As[128][32];   // 8 KB
    __shared__ __align__(16) unsigned short Bs[64][32];    // 4 KB
    int tid = threadIdx.x;
    int wave = tid >> 6, lane = tid & 63;
    int quad = lane >> 4, mr = lane & 15;
    int row0 = blockIdx.y * 128, col0 = blockIdx.x * 64;
    int ar = tid >> 2, ac = (tid & 3) * 8;   // LDS slot byte off = tid*16
    f32x4 z = {0.f, 0.f, 0.f, 0.f};
    f32x4 acc[2][4] = {{z, z, z, z}, {z, z, z, z}};
    const unsigned short* Au = (const unsigned short*)A;
    const unsigned short* Wu = (const unsigned short*)Wt;
    for (int k0 = 0; k0 < K; k0 += 32) {
        gload16(&Au[(size_t)(row0 + ar) * lda + k0 + ac],      &As[ar][ac]);
        gload16(&Au[(size_t)(row0 + 64 + ar) * lda + k0 + ac], &As[64 + ar][ac]);
        gload16(&Wu[(size_t)(col0 + ar) * ldw + k0 + ac],      &Bs[ar][ac]);
        __syncthreads();   // compiler emits vmcnt(0) drain before barrier
        v8s bfr[4];
        #pragma unroll
        for (int ni = 0; ni < 4; ni++)
            bfr[ni] = *(const v8s*)&Bs[ni * 16 + mr][quad * 8];
        #pragma unroll
        for (int s = 0; s < 2; s++) {
            v8s a = *(const v8s*)&As[wave * 32 + s * 16 + mr][quad * 8];
            #pragma unroll
            for (int ni = 0; ni < 4; ni++)
                acc[s][ni] = __builtin_amdgcn_mfma_f32_16x16x32_bf16(
                    a, bfr[ni], acc[s][ni], 0, 0, 0);
        }
        __syncthreads();
    }
    if (OM == 1) {
        bf16* outb = (bf16*)outF;
        #pragma unroll
        for (int ni = 0; ni < 4; ni++) {
            int gc = col0 + ni * 16 + mr;
            if (gc >= N) continue;
            float bv = bias[gc];
            int sec = gc / 180, rem = gc - sec * 180;
            int hh = rem / 30, d = rem - hh * 30;
            int slot = sec * 192 + hh * 32 + d;
            float sc = (sec == 0) ? 0.18257418583505536f : 1.f;
            #pragma unroll
            for (int s = 0; s < 2; s++) {
                #pragma unroll
                for (int r = 0; r < 4; r++) {
                    int gr = row0 + wave * 32 + s * 16 + quad * 4 + r;
                    outb[(size_t)gr * QKVP + slot] =
                        __float2bfloat16((acc[s][ni][r] + bv) * sc);
                }
            }
        }
        return;
    }
    #pragma unroll
    for (int ni = 0; ni < 4; ni++) {
        int gc = col0 + ni * 16 + mr;
        if (gc >= N) continue;
        float bv = BIAS_ ? bias[gc] : 0.f;
        #pragma unroll
        for (int s = 0; s < 2; s++) {
            #pragma unroll
            for (int r = 0; r < 4; r++) {
                int gr = row0 + wave * 32 + s * 16 + quad * 4 + r;
                float v = acc[s][ni][r] + bv;
                if (GELU_) v = gelu_exact(v);
                if (ADDRES) v += res[(size_t)gr * ldr + gc];
                outF[(size_t)gr * ldo + gc] = v;
            }
        }
    }
}

// ---------------- batched AV GEMM: acc[b] = P[b]@vvT[b] + x[b] -------------
// grid (3, 64, 8). P bf16 [b][4096][64]; vvT bf16 [b][192][64]; K=64.
__global__ __launch_bounds__(256) void av_mgemm_kernel(
        const bf16* __restrict__ P, const bf16* __restrict__ vvT,
        const float* __restrict__ xres, float* __restrict__ accout)
{
    __shared__ unsigned short As[64][32];
    __shared__ unsigned short Bs[64][32];
    int tid = threadIdx.x;
    int wave = tid >> 6, lane = tid & 63;
    int quad = lane >> 4, mr = lane & 15;
    int row0 = blockIdx.y * 64, col0 = blockIdx.x * 64;
    int bz = blockIdx.z;
    const unsigned short* Au = (const unsigned short*)P + (size_t)bz * NTOK * MDICT;
    const unsigned short* Wu = (const unsigned short*)vvT + (size_t)bz * 192 * MDICT;
    const float* res = xres + (size_t)bz * NTOK * CDIM;
    float* outF = accout + (size_t)bz * NTOK * CDIM;
    f32x4 z = {0.f, 0.f, 0.f, 0.f};
    f32x4 acc[4] = {z, z, z, z};
    for (int k0 = 0; k0 < MDICT; k0 += 32) {
        #pragma unroll
        for (int e = 0; e < 8; e++) {
            int idx = tid * 8 + e;
            int r = idx >> 5, c = idx & 31;
            As[r][c] = Au[(size_t)(row0 + r) * MDICT + k0 + c];
            Bs[r][c] = Wu[(size_t)(col0 + r) * MDICT + k0 + c];
        }
        __syncthreads();
        v8s a;
        #pragma unroll
        for (int j = 0; j < 8; j++) a[j] = (short)As[wave * 16 + mr][quad * 8 + j];
        #pragma unroll
        for (int ni = 0; ni < 4; ni++) {
            v8s b;
            #pragma unroll
            for (int j = 0; j < 8; j++) b[j] = (short)Bs[ni * 16 + mr][quad * 8 + j];
            acc[ni] = __builtin_amdgcn_mfma_f32_16x16x32_bf16(a, b, acc[ni], 0, 0, 0);
        }
        __syncthreads();
    }
    #pragma unroll
    for (int ni = 0; ni < 4; ni++) {
        int gc = col0 + ni * 16 + mr;
        if (gc >= CDIM) continue;
        #pragma unroll
        for (int r = 0; r < 4; r++) {
            int gr = row0 + wave * 16 + quad * 4 + r;
            float v = acc[ni][r] + res[(size_t)gr * CDIM + gc];
            outF[(size_t)gr * CDIM + gc] = v;
        }
    }
}

// ---------------- Window attention, MFMA flash (bf16 KP1 out) --------------
// R12 structure + R19 bf16-qkv input: Q/K/V loaded as aligned v8s from the
// padded [ROWS][576] layout (Q pre-scaled, pads zero) — no f2b at load.
__global__ __launch_bounds__(256, 4) void win_mfma_kernel(const bf16* __restrict__ qkvb,
        const float* __restrict__ bias_t, bf16* __restrict__ outb)
{
    int b = blockIdx.y;
    int widx = blockIdx.x / NHEADS;
    int hh = blockIdx.x % NHEADS;
    int wy = widx >> 2, wx = widx & 3;
    int tid = threadIdx.x;
    int wave = tid >> 6, lane = tid & 63, quad = lane >> 4, mr = lane & 15;
    __shared__ __align__(16) unsigned short Ks[64][40];
    __shared__ __align__(16) unsigned short Vt[32][80];

    size_t brow = (size_t)b * NTOK;
    const unsigned short* qu = (const unsigned short*)qkvb;

    v8s aq[4];
    #pragma unroll
    for (int tt = 0; tt < 4; tt++) {
        int m = (wave * 4 + tt) * 16 + mr;
        int nt_ = (wy * WS + (m >> 4)) * 64 + wx * WS + (m & 15);
        aq[tt] = *(const v8s*)&qu[(brow + nt_) * QKVP + hh * 32 + quad * 8];
    }
    f32x4 z = {0.f, 0.f, 0.f, 0.f};
    f32x4 oacc[4][2] = {{z, z}, {z, z}, {z, z}, {z, z}};
    float m_r[4], l_r[4];
    #pragma unroll
    for (int tt = 0; tt < 4; tt++) { m_r[tt] = -3.0e38f; l_r[tt] = 0.f; }
    const float* btab = bias_t + (size_t)hh * WIN_N * WIN_N;

    for (int kc = 0; kc < WIN_N; kc += 64) {
        {
            int j = tid >> 2, dg = (tid & 3) * 8;
            int tok = kc + j;
            int nt_ = (wy * WS + (tok >> 4)) * 64 + wx * WS + (tok & 15);
            const unsigned short* base = qu + (brow + nt_) * QKVP + hh * 32;
            v8s kv = *(const v8s*)&base[192 + dg];
            v8s vv = *(const v8s*)&base[384 + dg];
            *(v8s*)&Ks[j][dg] = kv;
            #pragma unroll
            for (int jj = 0; jj < 8; jj++)
                Vt[dg + jj][j] = (unsigned short)vv[jj];
        }
        __syncthreads();
        #pragma unroll
        for (int tt = 0; tt < 4; tt++) {
            // --- QK^T swapped: s[nt][r] = S[key=kc+nt*16+quad*4+r][query] ---
            f32x4 s[4];
            #pragma unroll
            for (int nt = 0; nt < 4; nt++) {
                v8s bk = *(const v8s*)&Ks[nt * 16 + mr][quad * 8];
                s[nt] = __builtin_amdgcn_mfma_f32_16x16x32_bf16(bk, aq[tt], z, 0, 0, 0);
            }
            int qg = (wave * 4 + tt) * 16 + mr;
            const float* bi = btab + (size_t)qg * WIN_N + kc;
            float mc = -3.0e38f;
            #pragma unroll
            for (int nt = 0; nt < 4; nt++) {
                f32x4 b4 = *(const f32x4*)(bi + nt * 16 + quad * 4);
                s[nt][0] += b4[0]; s[nt][1] += b4[1];
                s[nt][2] += b4[2]; s[nt][3] += b4[3];
                mc = fmaxf(mc, fmaxf(fmaxf(s[nt][0], s[nt][1]),
                                     fmaxf(s[nt][2], s[nt][3])));
            }
            mc = fmaxf(mc, __shfl_xor(mc, 16, 64));
            mc = fmaxf(mc, __shfl_xor(mc, 32, 64));
            float mn = fmaxf(m_r[tt], mc);
            float alpha = __expf(m_r[tt] - mn);
            m_r[tt] = mn;
            float ls = 0.f;
            #pragma unroll
            for (int nt = 0; nt < 4; nt++) {
                #pragma unroll
                for (int r = 0; r < 4; r++) {
                    float pp = __expf(s[nt][r] - mn);
                    ls += pp;
                    s[nt][r] = pp;
                }
            }
            ls += __shfl_xor(ls, 16, 64);
            ls += __shfl_xor(ls, 32, 64);
            l_r[tt] = l_r[tt] * alpha + ls;
            // --- pack P (bf16 pairs): dpk[nt][s] = keys nt*16+quad*4+{2s,2s+1}
            unsigned dpk[4][2];
            #pragma unroll
            for (int nt = 0; nt < 4; nt++) {
                dpk[nt][0] = packbf(s[nt][0], s[nt][1]);
                dpk[nt][1] = packbf(s[nt][2], s[nt][3]);
            }
            // --- rescale oacc rows (query = quad*4+r) by alpha ---
            #pragma unroll
            for (int r = 0; r < 4; r++) {
                float av = __shfl(alpha, quad * 4 + r, 64);
                oacc[tt][0][r] *= av;
                oacc[tt][1][r] *= av;
            }
            // --- PV: build A-frags via cross-lane shuffle, 2 chunks of K=32 --
            #pragma unroll
            for (int c = 0; c < 2; c++) {
                union { u32x4 u; v8s s8; } afu;
                #pragma unroll
                for (int t = 0; t < 4; t++) {
                    int srcl = (((quad * 2 + (t >> 1)) & 3) << 4) | mr;
                    unsigned r0 = (unsigned)__shfl((int)dpk[2 * c][t & 1], srcl, 64);
                    unsigned r1 = (unsigned)__shfl((int)dpk[2 * c + 1][t & 1], srcl, 64);
                    afu.u[t] = (quad & 2) ? r1 : r0;
                }
                #pragma unroll
                for (int dt = 0; dt < 2; dt++) {
                    v8s bv = *(const v8s*)&Vt[dt * 16 + mr][c * 32 + quad * 8];
                    oacc[tt][dt] = __builtin_amdgcn_mfma_f32_16x16x32_bf16(
                        afu.s8, bv, oacc[tt][dt], 0, 0, 0);
                }
            }
        }
        __syncthreads();
    }
    #pragma unroll
    for (int tt = 0; tt < 4; tt++) {
        float il = 1.f / l_r[tt];
        #pragma unroll
        for (int r = 0; r < 4; r++) {
            float ilr = __shfl(il, quad * 4 + r, 64);
            int m = (wave * 4 + tt) * 16 + quad * 4 + r;
            int nt_ = (wy * WS + (m >> 4)) * 64 + wx * WS + (m & 15);
            #pragma unroll
            for (int dt = 0; dt < 2; dt++) {
                int d = dt * 16 + mr;
                if (d >= HD) continue;
                outb[(brow + nt_) * KP1 + hh * HD + d] =
                    __float2bfloat16(oacc[tt][dt][r] * ilr);
            }
        }
    }
}

// ---------------- AC_MSA, MFMA flash, swapped QK^T -------------------------
// R17 structure + R19 bf16-qkv input (v8s loads, toks[] indirection).
__global__ __launch_bounds__(256, 4) void acmsa_mfma_kernel(const bf16* __restrict__ qkvb,
        const int* __restrict__ sidx, bf16* __restrict__ outb)
{
    int b = blockIdx.y;
    int g = blockIdx.x / NHEADS;
    int hh = blockIdx.x % NHEADS;
    int tid = threadIdx.x;
    int wave = tid >> 6, lane = tid & 63, quad = lane >> 4, mr = lane & 15;
    __shared__ int toks[GS];
    __shared__ __align__(16) unsigned short Ks[64][40];
    __shared__ __align__(16) unsigned short Vt[32][80];

    size_t brow = (size_t)b * NTOK;
    if (tid < GS) toks[tid] = sidx[brow + (size_t)g * GS + tid];
    __syncthreads();
    const unsigned short* qu = (const unsigned short*)qkvb;

    v8s aq[2];
    #pragma unroll
    for (int tt = 0; tt < 2; tt++) {
        int m = (wave * 2 + tt) * 16 + mr;
        aq[tt] = *(const v8s*)&qu[(brow + toks[m]) * QKVP + hh * 32 + quad * 8];
    }
    f32x4 z = {0.f, 0.f, 0.f, 0.f};
    f32x4 oacc[2][2] = {{z, z}, {z, z}};
    float m_r[2], l_r[2];
    #pragma unroll
    for (int tt = 0; tt < 2; tt++) { m_r[tt] = -3.0e38f; l_r[tt] = 0.f; }

    for (int kc = 0; kc < GS; kc += 64) {
        {
            int j = tid >> 2, dg = (tid & 3) * 8;
            int tok = toks[kc + j];
            const unsigned short* base = qu + (brow + tok) * QKVP + hh * 32;
            v8s kv = *(const v8s*)&base[192 + dg];
            v8s vv = *(const v8s*)&base[384 + dg];
            *(v8s*)&Ks[j][dg] = kv;
            #pragma unroll
            for (int jj = 0; jj < 8; jj++)
                Vt[dg + jj][j] = (unsigned short)vv[jj];
        }
        __syncthreads();
        #pragma unroll
        for (int tt = 0; tt < 2; tt++) {
            // --- QK^T swapped: s[nt][r] = S[key=kc+nt*16+quad*4+r][query=mr]
            f32x4 s[4];
            #pragma unroll
            for (int nt = 0; nt < 4; nt++) {
                v8s bk = *(const v8s*)&Ks[nt * 16 + mr][quad * 8];
                s[nt] = __builtin_amdgcn_mfma_f32_16x16x32_bf16(bk, aq[tt], z, 0, 0, 0);
            }
            float mc = -3.0e38f;
            #pragma unroll
            for (int nt = 0; nt < 4; nt++)
                mc = fmaxf(mc, fmaxf(fmaxf(s[nt][0], s[nt][1]),
                                     fmaxf(s[nt][2], s[nt][3])));
            mc = fmaxf(mc, __shfl_xor(mc, 16, 64));
            mc = fmaxf(mc, __shfl_xor(mc, 32, 64));
            float mn = fmaxf(m_r[tt], mc);
            float alpha = __expf(m_r[tt] - mn);
            m_r[tt] = mn;
            float ls = 0.f;
            #pragma unroll
            for (int nt = 0; nt < 4; nt++) {
                #pragma unroll
                for (int r = 0; r < 4; r++) {
                    float pp = __expf(s[nt][r] - mn);
                    ls += pp;
                    s[nt][r] = pp;
                }
            }
            ls += __shfl_xor(ls, 16, 64);
            ls += __shfl_xor(ls, 32, 64);
            l_r[tt] = l_r[tt] * alpha + ls;
            unsigned dpk[4][2];
            #pragma unroll
            for (int nt = 0; nt < 4; nt++) {
                dpk[nt][0] = packbf(s[nt][0], s[nt][1]);
                dpk[nt][1] = packbf(s[nt][2], s[nt][3]);
            }
            #pragma unroll
            for (int r = 0; r < 4; r++) {
                float av = __shfl(alpha, quad * 4 + r, 64);
                oacc[tt][0][r] *= av;
                oacc[tt][1][r] *= av;
            }
            #pragma unroll
            for (int c = 0; c < 2; c++) {
                union { u32x4 u; v8s s8; } afu;
                #pragma unroll
                for (int t = 0; t < 4; t++) {
                    int srcl = (((quad * 2 + (t >> 1)) & 3) << 4) | mr;
                    unsigned r0 = (unsigned)__shfl((int)dpk[2 * c][t & 1], srcl, 64);
                    unsigned r1 = (unsigned)__shfl((int)dpk[2 * c + 1][t & 1], srcl, 64);
                    afu.u[t] = (quad & 2) ? r1 : r0;
                }
                #pragma unroll
                for (int dt = 0; dt < 2; dt++) {
                    v8s bv = *(const v8s*)&Vt[dt * 16 + mr][c * 32 + quad * 8];
                    oacc[tt][dt] = __builtin_amdgcn_mfma_f32_16x16x32_bf16(
                        afu.s8, bv, oacc[tt][dt], 0, 0, 0);
                }
            }
        }
        __syncthreads();
    }
    #pragma unroll
    for (int tt = 0; tt < 2; tt++) {
        float il = 1.f / l_r[tt];
        #pragma unroll
        for (int r = 0; r < 4; r++) {
            float ilr = __shfl(il, quad * 4 + r, 64);
            int m = (wave * 2 + tt) * 16 + quad * 4 + r;
            int tok = toks[m];
            #pragma unroll
            for (int dt = 0; dt < 2; dt++) {
                int d = dt * 16 + mr;
                if (d >= HD) continue;
                outb[(brow + tok) * KP1 + hh * HD + d] =
                    __float2bfloat16(oacc[tt][dt][r] * ilr);
            }
        }
    }
}

// ---------------- LayerNorm: fp32 out + fused bf16 KP1-padded out ----------
__global__ __launch_bounds__(64) void ln_kernel(const float* __restrict__ x,
        const float* __restrict__ g, const float* __restrict__ be,
        float* __restrict__ out, bf16* __restrict__ outb)
{
    int row = blockIdx.x; int t = threadIdx.x;
    const float* xr = x + (size_t)row * CDIM;
    float v0 = xr[t];
    float v1 = xr[t + 64];
    float v2 = (t < CDIM - 128) ? xr[t + 128] : 0.f;
    float s1 = wave_sum(v0 + v1 + v2);
    float s2 = wave_sum(v0*v0 + v1*v1 + v2*v2);
    float mu = s1 / (float)CDIM;
    float var = s2 / (float)CDIM - mu * mu;
    float rs = rsqrtf(var + 1e-5f);
    float o0 = (v0 - mu) * rs * g[t]      + be[t];
    float o1 = (v1 - mu) * rs * g[t + 64] + be[t + 64];
    float o2 = (t < CDIM - 128) ? ((v2 - mu) * rs * g[t + 128] + be[t + 128]) : 0.f;
    float* o = out + (size_t)row * CDIM;
    o[t] = o0; o[t + 64] = o1;
    if (t < CDIM - 128) o[t + 128] = o2;
    bf16* ob = outb + (size_t)row * KP1;
    ob[t]       = __float2bfloat16(o0);
    ob[t + 64]  = __float2bfloat16(o1);
    ob[t + 128] = __float2bfloat16(o2);   // cols 180..191 get 0 (t>=52 -> o2=0)
}

// ---------------- Dictionary precompute: kkn (l2), vvT bf16, td_proj -------
__global__ __launch_bounds__(64) void td_pre_kernel(const float* __restrict__ td,
        const float* __restrict__ wk, const float* __restrict__ wkb,
        const float* __restrict__ wv, const float* __restrict__ wvb,
        const float* __restrict__ wtd, const float* __restrict__ wtdb,
        float* __restrict__ kkn, bf16* __restrict__ vvT, float* __restrict__ tdp)
{
    int blk = blockIdx.x;   // b*64 + m
    int b = blk >> 6, m = blk & 63;
    int t = threadIdx.x;
    __shared__ float tr[CDIM];
    __shared__ float sk[RD];
    __shared__ float snorm;
    const float* tdr = td + (size_t)blk * CDIM;
    tr[t] = tdr[t]; tr[t + 64] = tdr[t + 64];
    if (t < CDIM - 128) tr[t + 128] = tdr[t + 128];
    __syncthreads();
    if (t < RD) {
        float s = wkb[t];
        for (int k = 0; k < CDIM; k++) s += tr[k] * wk[k * RD + t];
        sk[t] = s;
    }
    __syncthreads();
    if (t == 0) {
        float s = 0.f;
        #pragma unroll
        for (int j = 0; j < RD; j++) s += sk[j] * sk[j];
        snorm = fmaxf(sqrtf(s), 1e-12f);
    }
    __syncthreads();
    if (t < RD) kkn[(size_t)blk * RD + t] = sk[t] / snorm;
    // vvT[b][c][m] bf16, c padded to 192 (tail rows zero)
    for (int c = t; c < 192; c += 64) {
        float s = 0.f;
        if (c < CDIM) {
            s = wvb[c];
            for (int k = 0; k < CDIM; k++) s += tr[k] * wv[k * CDIM + c];
        }
        vvT[((size_t)(b * 192 + c)) * MDICT + m] = __float2bfloat16(s);
    }
    {
        float s = wtdb[t];
        for (int k = 0; k < CDIM; k++) s += tr[k] * wtd[k * DTD + t];
        tdp[(size_t)blk * DTD + t] = s;
    }
}

// ---------------- ATD softmax/argmax (fp32 exact logits, P bf16 out) -------
__global__ __launch_bounds__(64) void atd_soft_kernel(const float* __restrict__ xn,
        const float* __restrict__ wq, const float* __restrict__ wqb,
        const float* __restrict__ scale_p, const float* __restrict__ kkn,
        bf16* __restrict__ Pout, int* __restrict__ tk_id)
{
    int row = blockIdx.x;
    int b = row >> 12;
    int t = threadIdx.x;
    const float* xrow = xn + (size_t)row * CDIM;
    float v0 = xrow[t];
    float v1 = xrow[t + 64];
    float v2 = (t < CDIM - 128) ? xrow[t + 128] : 0.f;
    // q-proj: all 64 lanes contribute; wave_sum broadcasts result to all lanes
    float sq[RD];
    #pragma unroll
    for (int j = 0; j < RD; j++) {
        float part = v0 * wq[t * RD + j] + v1 * wq[(t + 64) * RD + j];
        if (t < CDIM - 128) part += v2 * wq[(t + 128) * RD + j];
        sq[j] = wave_sum(part) + wqb[j];
    }
    float qn = 0.f;
    #pragma unroll
    for (int j = 0; j < RD; j++) qn += sq[j] * sq[j];
    qn = fmaxf(sqrtf(qn), 1e-12f);
    float ls = 1.0f + fminf(fmaxf(scale_p[0], 0.f), 3.f) * 4.158883083359672f;
    const float* kr = kkn + ((size_t)b * MDICT + t) * RD;
    float s = 0.f;
    #pragma unroll
    for (int j = 0; j < RD; j++) s += sq[j] * kr[j];
    s = s / qn * ls;
    // 64-lane softmax + first-index argmax (fp32 exact)
    float mv = s; int mi = t;
    #pragma unroll
    for (int off = 32; off > 0; off >>= 1) {
        float ov = __shfl_xor(mv, off, 64);
        int   oi = __shfl_xor(mi, off, 64);
        if (ov > mv || (ov == mv && oi < mi)) { mv = ov; mi = oi; }
    }
    float e = __expf(s - mv);
    float denom = wave_sum(e);
    Pout[(size_t)row * MDICT + t] = __float2bfloat16(e / denom);
    if (t == 0) tk_id[row] = mi;
}

// ---------------- Stable counting sort of tk_id ----------------------------
__global__ __launch_bounds__(256) void sort_kernel(const int* __restrict__ tk_id,
                                                   int* __restrict__ sidx)
{
    int b = blockIdx.x; int tid = threadIdx.x;
    __shared__ int keys[NTOK];
    __shared__ int cnt[256];
    __shared__ int off[256];
    const int* kb = tk_id + (size_t)b * NTOK;
    for (int i = tid; i < NTOK; i += 256) keys[i] = kb[i];
    __syncthreads();
    int v = tid >> 2, seg = tid & 3;
    int lo = seg * 1024, hi = lo + 1024;
    int c = 0;
    for (int i = lo; i < hi; i++) c += (keys[i] == v);
    cnt[tid] = c;
    __syncthreads();
    if (tid == 0) {
        int run = 0;
        for (int l = 0; l < 256; l++) { off[l] = run; run += cnt[l]; }
    }
    __syncthreads();
    int o = off[tid];
    int* sb = sidx + (size_t)b * NTOK;
    for (int i = lo; i < hi; i++) if (keys[i] == v) sb[o++] = i;
}

// ---------------- Gather dictionary features into hc[:, 360:424] -----------
__global__ __launch_bounds__(256) void gather_td_kernel(const int* __restrict__ tk_id,
        const float* __restrict__ tdp, float* __restrict__ hc)
{
    int idx = blockIdx.x * 256 + threadIdx.x;
    int row = idx >> 6, j = idx & 63;
    int b = row >> 12;
    int tk = tk_id[row];
    hc[(size_t)row * CCAT + MHID + j] = tdp[((size_t)b * MDICT + tk) * DTD + j];
}

// ---------------- Depthwise 5x5 conv: CHK=64, 8x8 tile, bf16 KP2 out -------
// R20: thread = 4 x-adjacent pixels x 4 channels (16 outputs, same as R15).
// Per dy: 8 row-position reads + 5 tap reads feed 4 accumulators -> LDS
// reads/thread 204 -> 69 b128. All row registers die at end of dy
// (sched_barrier(0) per dy = R16-spill guard: no cross-dy liveness).
// Staging vectorized f32x4. Write-ownership kept (block owns 128B lines;
// 16 q-lanes x 8B per pixel = one full line).
#define CHK3 64
#define CTW  8
#define CTH  8
#define CHW  12     // halo width/height = tile + 4
#define CHP  144    // 12*12 halo pixels
#define CSPX 68     // floats per pixel row (64 + 4 pad) = 272B, 16B-aligned
__global__ __launch_bounds__(256) void conv_kernel(const float* __restrict__ hc,
        const float* __restrict__ w, const float* __restrict__ wb,
        bf16* __restrict__ outb)
{
    int ch0 = blockIdx.x * CHK3;        // 0,64,...,384 (7 blocks; 424..447 zeroed)
    int tile = blockIdx.y;              // 64 tiles of 8x8
    int b = blockIdx.z;
    int ty0 = (tile >> 3) * CTH, tx0 = (tile & 7) * CTW;
    __shared__ __align__(16) float sh[CHP][CSPX];   // 39168 B
    __shared__ __align__(16) float wt[25][CHK3];    // 6400 B
    int tid = threadIdx.x;
    // stage input: f32x4 per (pixel, ch-quad); 16 lanes = 256B coalesced
    for (int idx = tid; idx < CHP * 16; idx += 256) {
        int pix = idx >> 4, cq = idx & 15;
        int gy = ty0 + pix / CHW - 2, gx = tx0 + pix % CHW - 2;
        int chg = ch0 + cq * 4;
        f32x4 v = {0.f, 0.f, 0.f, 0.f};
        if (gy >= 0 && gy < 64 && gx >= 0 && gx < 64 && chg < CCAT)
            v = *(const f32x4*)&hc[((size_t)b * NTOK + gy * 64 + gx) * CCAT + chg];
        *(f32x4*)&sh[pix][cq * 4] = v;
    }
    for (int idx = tid; idx < 25 * CHK3; idx += 256) {
        int kk = idx >> 6, ch = idx & 63;
        int chg = ch0 + ch;
        wt[kk][ch] = (chg < CCAT) ? w[chg * 25 + kk] : 0.f;
    }
    __syncthreads();
    int q = tid & 15, pg = tid >> 4;    // q: ch-quad 0..15; pg: pixel group
    int py = pg >> 1, px0 = (pg & 1) * 4;   // 8 rows x 2 groups of 4 pixels
    int cs = q * 4;
    f32x4 z4 = {0.f, 0.f, 0.f, 0.f};
    f32x4 acc[4] = {z4, z4, z4, z4};
    #pragma unroll
    for (int dy = 0; dy < 5; dy++) {
        const float* srow = &sh[(py + dy) * CHW + px0][cs];
        f32x4 r[8];
        #pragma unroll
        for (int j = 0; j < 8; j++)
            r[j] = *(const f32x4*)(srow + j * CSPX);
        #pragma unroll
        for (int kx = 0; kx < 5; kx++) {
            f32x4 wv = *(const f32x4*)&wt[dy * 5 + kx][cs];
            acc[0] += r[kx] * wv;
            acc[1] += r[kx + 1] * wv;
            acc[2] += r[kx + 2] * wv;
            acc[3] += r[kx + 3] * wv;
        }
        __builtin_amdgcn_sched_barrier(0);   // row registers die here
    }
    #pragma unroll
    for (int px = 0; px < 4; px++) {
        f32x4 ctr = *(const f32x4*)&sh[(py + 2) * CHW + px0 + px + 2][cs];
        v4s pk;
        #pragma unroll
        for (int c = 0; c < 4; c++) {
            int chg = ch0 + cs + c;
            float v = 0.f;
            if (chg < CCAT) {
                float gv = gelu_exact(acc[px][c] + wb[chg]);
                v = ctr[c] + gv;
            }
            pk[c] = (short)f2b(v);
        }
        size_t obase = ((size_t)b * NTOK + (ty0 + py) * 64 + tx0 + px0 + px) * KP2
                       + ch0 + cs;
        *(v4s*)((unsigned short*)outb + obase) = pk;   // 8B aligned
    }
}

// ---------------------------------------------------------------------------
extern "C" void kernel_launch(void* const* d_in, const int* in_sizes, int n_in,
                              void* d_out, int out_size, void* d_ws, size_t ws_size,
                              hipStream_t stream)
{
    (void)n_in; (void)ws_size; (void)out_size;
    const int* rpi = (const int*)d_in[28];

    // ---- workspace carve-up ----
    float* p = (float*)d_ws;
    float* xn    = p; p += (size_t)ROWS * CDIM;
    float* acc   = p; p += (size_t)ROWS * CDIM;
    float* tmp1  = p; p += (size_t)ROWS * CDIM;    // alias: P bf16 (head), fc2 out
    float* qkv   = p; p += (size_t)ROWS * C3;      // alias: qkvb bf16; hc fp32 post-win
    float* hcnew = p; p += (size_t)ROWS * CCAT;    // alias: xnb/tmp1b; then conv bf16 out
    float* kkn   = p; p += (size_t)BB * MDICT * RD;
    bf16*  vvT   = (bf16*)p; p += (size_t)BB * 192 * MDICT / 2;   // bf16 [8][192][64]
    float* tdp   = p; p += (size_t)BB * MDICT * DTD;
    int*   tk_id = (int*)p; p += ROWS;
    int*   sidx  = (int*)p; p += ROWS;
    int*   flag  = (int*)p; p += 64;
    int*   diag  = (int*)p; p += 64;
    bf16* wtqkv = (bf16*)p; p += 576 * KP1 / 2;
    bf16* wtaca = (bf16*)p; p += 192 * KP1 / 2;
    bf16* wtwin = (bf16*)p; p += 192 * KP1 / 2;
    bf16* wtfc1 = (bf16*)p; p += 384 * KP1 / 2;
    bf16* wtfc2 = (bf16*)p; p += 192 * KP2 / 2;
    float* cin[28];
    for (int i = 0; i < 28; i++) { cin[i] = p; p += in_sizes[i]; }
    float* bias_t = p; p += (size_t)NHEADS * WIN_N * WIN_N;   // 1.5 MB

    float* hc      = qkv;                // fp32 [ROWS,CCAT]; born after win (qkv dead)
    bf16*  qkvb    = (bf16*)qkv;         // bf16 [ROWS,576] padded; dies at win
    bf16*  xnb     = (bf16*)hcnew;                            // [ROWS,KP1]; dies at fc1
    bf16*  tmp1b   = (bf16*)(hcnew + (size_t)ROWS * KP1 / 2); // [ROWS,KP1]; dies at winp
    bf16*  hcnewb2 = (bf16*)hcnew;       // [ROWS,KP2] bf16; born at conv
    bf16*  Pbuf    = (bf16*)tmp1;        // [ROWS,64] bf16 = 4MB; dies after av_mgemm
                                         // (tmp1 fp32 reborn at fc2 much later)

    // ---- dtype detect (+diag=0) + batched input normalize to fp32 ----
    detect_kernel<<<1, 256, 0, stream>>>(d_in[0], flag, diag);
    {
        CvtArgs ca;
        int total = 0, s = 0;
        for (int i = 0; i < 28; i++) {
            if (i == 4 || i == 13 || i == 16 || i == 20 || i == 24) continue;
            ca.src[s] = d_in[i];
            ca.dst[s] = cin[i];
            ca.cum[s] = total;
            total += in_sizes[i];
            s++;
        }
        ca.cum[s] = total;
        convert_all_kernel<<<(total + 255) / 256, 256, 0, stream>>>(ca, total, flag);
    }
    const float *x = cin[0], *td = cin[1], *n1g = cin[2], *n1b = cin[3],
        *wqkv_b = cin[5], *wq_w = cin[6], *wq_b = cin[7],
        *wk_w = cin[8], *wk_b = cin[9], *wv_w = cin[10], *wv_b = cin[11],
        *atd_scale = cin[12], *aca_b = cin[14], *win_rpb = cin[15],
        *winp_b = cin[17], *fctd_w = cin[18], *fctd_b = cin[19],
        *fc1_b = cin[21], *dw_w = cin[22], *dw_b = cin[23], *fc2_b = cin[25],
        *n2g = cin[26], *n2b = cin[27];

    // ---- adaptive weight repacks (by value) + bias table ----
    packW_kernel<<<576 * KP1 / 256, 256, 0, stream>>>(d_in[4],  wtqkv, CDIM, C3,   KP1, 576 * KP1, flag);
    packW_kernel<<<192 * KP1 / 256, 256, 0, stream>>>(d_in[13], wtaca, CDIM, CDIM, KP1, 192 * KP1, flag);
    packW_kernel<<<192 * KP1 / 256, 256, 0, stream>>>(d_in[16], wtwin, CDIM, CDIM, KP1, 192 * KP1, flag);
    packW_kernel<<<384 * KP1 / 256, 256, 0, stream>>>(d_in[20], wtfc1, CDIM, MHID, KP1, 384 * KP1, flag);
    packW_kernel<<<192 * KP2 / 256, 256, 0, stream>>>(d_in[24], wtfc2, CCAT, CDIM, KP2, 192 * KP2, flag);
    bias_pre_kernel<<<NHEADS * WIN_N * WIN_N / 256, 256, 0, stream>>>(rpi, win_rpb, bias_t);

    td_pre_kernel<<<BB * MDICT, 64, 0, stream>>>(td, wk_w, wk_b, wv_w, wv_b,
                                                 fctd_w, fctd_b, kkn, vvT, tdp);
    // LN1 with fused bf16-KP1 output
    ln_kernel<<<ROWS, 64, 0, stream>>>(x, n1g, n1b, xn, xnb);
    // qkv gemm: bf16 padded output (Q pre-scaled), then zero pad slots
    mgemm_kernel<false, false, true, 1><<<dim3(9, ROWS / 128), 256, 0, stream>>>(
        xnb, KP1, wtqkv, KP1, wqkv_b, nullptr, 0, (float*)qkvb, QKVP, C3, KP1);
    zero_qkvpad_kernel<<<ROWS * 36 / 256, 256, 0, stream>>>(qkvb);
    // ATD: fp32 softmax/argmax -> P bf16 + tk_id; then batched MFMA AV
    atd_soft_kernel<<<ROWS, 64, 0, stream>>>(xn, wq_w, wq_b, atd_scale, kkn, Pbuf, tk_id);
    av_mgemm_kernel<<<dim3(3, NTOK / 64, BB), 256, 0, stream>>>(Pbuf, vvT, x, acc);
    sort_kernel<<<BB, 256, 0, stream>>>(tk_id, sidx);
    // zero K-tail of tmp1b once; both attentions leave cols 180..191 untouched
    zero_tail_kernel<<<ROWS * 12 / 256, 256, 0, stream>>>(tmp1b);
    // MFMA flash AC_MSA -> tmp1b (bf16 direct)
    acmsa_mfma_kernel<<<dim3(NG * NHEADS, BB), 256, 0, stream>>>(qkvb, sidx, tmp1b);
    mgemm_kernel<false, true, true, 0><<<dim3(3, ROWS / 128), 256, 0, stream>>>(
        tmp1b, KP1, wtaca, KP1, aca_b, acc, CDIM, acc, CDIM, CDIM, KP1);
    // MFMA flash window attention -> tmp1b (bf16 direct)
    win_mfma_kernel<<<dim3(16 * NHEADS, BB), 256, 0, stream>>>(qkvb, bias_t, tmp1b);
    mgemm_kernel<false, true, true, 0><<<dim3(3, ROWS / 128), 256, 0, stream>>>(
        tmp1b, KP1, wtwin, KP1, winp_b, acc, CDIM, acc, CDIM, CDIM, KP1);
    // FFN: LN2 fused bf16 out -> fc1 -> gather -> conv (bf16 KP2 direct) -> fc2
    ln_kernel<<<ROWS, 64, 0, stream>>>(acc, n2g, n2b, xn, xnb);
    mgemm_kernel<true, false, true, 0><<<dim3(6, ROWS / 128), 256, 0, stream>>>(
        xnb, KP1, wtfc1, KP1, fc1_b, nullptr, 0, hc, CCAT, MHID, KP1);
    gather_td_kernel<<<ROWS * 64 / 256, 256, 0, stream>>>(tk_id, tdp, hc);
    conv_kernel<<<dim3(7, 64, BB), 256, 0, stream>>>(hc, dw_w, dw_b, hcnewb2);
    mgemm_kernel<false, true, true, 0><<<dim3(3, ROWS / 128), 256, 0, stream>>>(
        hcnewb2, KP2, wtfc2, KP2, fc2_b, acc, CDIM, tmp1, CDIM, CDIM, KP2);
    check_f32_kernel<<<(ROWS * CDIM + 255) / 256, 256, 0, stream>>>(tmp1, ROWS * CDIM, 8, diag);
    emit_kernel<<<(ROWS * CDIM + 255) / 256, 256, 0, stream>>>(
        tmp1, d_out, flag, diag, ROWS * CDIM);
}

// Round 10
// 701.990 us; speedup vs baseline: 1.0734x; 1.0273x over previous
//
#include <hip/hip_runtime.h>
#include <hip/hip_bf16.h>
#include <math.h>

// MPv2_3d_arch: B=8, n=64*64=4096, c=180, heads=6 (hd=30), dict M=64, rd=10,
// dtd=64, mlp_hid=360, cat C=424, window 16x16, groups of 128.
// R21: R20 (passing, 721us) post-mortem: 4-pixel register blocking repeated
// the R16 trap (VGPR 132, occ 10.8%, conv 116.7us). Conv reverted VERBATIM
// to R15 shape (proven 98.5us: VGPR 68, conflicts 0, writes ideal) — two
// failures confirm 68-VGPR/sequential-quads is this structure's optimum.
// NEW: ln + atd_soft repacked 4 rows per 256-thread block (wave-local math
// unchanged, bit-identical) — kills 3x 32768x64-thread launch inefficiency.
// SESSION RULE: input dtype VARIES per run (bf16 or fp32) — every d_in
// access must go through *flag (by value). Raw-bit reads = NaN.
#define BB      8
#define NTOK    4096
#define CDIM    180
#define C3      540
#define NHEADS  6
#define HD      30
#define MDICT   64
#define RD      10
#define DTD     64
#define MHID    360
#define CCAT    424
#define WS      16
#define WIN_N   256
#define GS      128
#define NG      32
#define ROWS    (BB*NTOK)   // 32768
#define KP1     192         // Kpad for K=180
#define KP2     448         // Kpad for K=424
#define QKVP    576         // padded qkv row: 3 sec * 6 heads * 32

typedef __hip_bfloat16 bf16;
typedef short v8s __attribute__((ext_vector_type(8)));
typedef float f32x4 __attribute__((ext_vector_type(4)));
typedef unsigned int u32x4 __attribute__((ext_vector_type(4)));

__device__ __forceinline__ float gelu_exact(float x) {
    return 0.5f * x * (1.0f + erff(x * 0.70710678118654752f));
}
__device__ __forceinline__ float wave_sum(float v) {
    #pragma unroll
    for (int off = 32; off > 0; off >>= 1) v += __shfl_xor(v, off, 64);
    return v;
}
// fp32 <-> bf16 bits without type-punning (RNE)
__device__ __forceinline__ unsigned short f2b(float v) {
    unsigned u = __float_as_uint(v);
    return (unsigned short)((u + 0x7FFFu + ((u >> 16) & 1u)) >> 16);
}
__device__ __forceinline__ float b2f(unsigned short h) {
    return __uint_as_float(((unsigned)h) << 16);
}
__device__ __forceinline__ unsigned packbf(float lo, float hi) {
    return (unsigned)f2b(lo) | ((unsigned)f2b(hi) << 16);
}
// async global->LDS 16B (gfx950); size must be literal; lds addr = per-lane
// slot in lane-order-contiguous slab (wave-uniform base + lane*16).
__device__ __forceinline__ void gload16(const void* g, void* l) {
    __builtin_amdgcn_global_load_lds(
        (const __attribute__((address_space(1))) void*)g,
        (__attribute__((address_space(3))) void*)l, 16, 0, 0);
}

// ---------------- dtype detector: flag=1 if inputs are fp32, 0 if bf16 -----
__global__ __launch_bounds__(256) void detect_kernel(const void* __restrict__ x,
                                                     int* __restrict__ flag,
                                                     int* __restrict__ diag)
{
    __shared__ int cnt;
    if (threadIdx.x == 0) { cnt = 0; *diag = 0; }
    __syncthreads();
    const unsigned short* u = (const unsigned short*)x;
    int c = 0;
    for (int i = threadIdx.x; i < 2048; i += 256) {
        unsigned short e = u[2 * i] & 0x7F80;
        if (e >= 0x4300) c++;
    }
    atomicAdd(&cnt, c);
    __syncthreads();
    if (threadIdx.x == 0) *flag = (cnt > 16) ? 1 : 0;
}

// ---------------- batched dtype-flexible input -> fp32 conversion ----------
#define NCVT 23
struct CvtArgs {
    const void* src[NCVT];
    float* dst[NCVT];
    int cum[NCVT + 1];
};
__global__ __launch_bounds__(256) void convert_all_kernel(CvtArgs a, int total,
        const int* __restrict__ flag)
{
    int i = blockIdx.x * 256 + threadIdx.x;
    if (i >= total) return;
    int s = 0;
    while (i >= a.cum[s + 1]) s++;   // x is segment 0 -> most threads exit fast
    int off = i - a.cum[s];
    if (*flag) a.dst[s][off] = ((const float*)a.src[s])[off];
    else       a.dst[s][off] = __bfloat162float(((const bf16*)a.src[s])[off]);
}

// ---------------- NaN/Inf check -> diag bit --------------------------------
__global__ __launch_bounds__(256) void check_f32_kernel(const float* __restrict__ buf,
        int n, int bit, int* __restrict__ diag)
{
    int i = blockIdx.x * 256 + threadIdx.x;
    if (i >= n) return;
    unsigned u = __float_as_uint(buf[i]);
    if ((u & 0x7F800000u) == 0x7F800000u) atomicOr(diag, bit);
}

// ---------------- output emit: fp32 src -> d_out in detected dtype ---------
__global__ __launch_bounds__(256) void emit_kernel(const float* __restrict__ src,
        void* __restrict__ out, const int* __restrict__ flag,
        const int* __restrict__ diag, int n)
{
    int i = blockIdx.x * 256 + threadIdx.x;
    if (i >= n) return;
    float v = src[i];
    int d = *diag;
    if (d) v = 100.f + 32.f * (float)d;   // NaN stage code -> absmax bin
    if (*flag) ((float*)out)[i] = v;
    else       ((bf16*)out)[i]  = __float2bfloat16(v);
}

// ---------------- zero cols 180..191 of a [ROWS,KP1] bf16 buffer -----------
__global__ __launch_bounds__(256) void zero_tail_kernel(bf16* __restrict__ buf)
{
    int idx = blockIdx.x * 256 + threadIdx.x;   // ROWS*12
    int row = idx / 12, c = idx % 12;
    buf[(size_t)row * KP1 + CDIM + c] = __float2bfloat16(0.f);
}

// ---------------- zero pad slots (d=30,31 per head/sec) of qkvb ------------
__global__ __launch_bounds__(256) void zero_qkvpad_kernel(bf16* __restrict__ qb)
{
    int idx = blockIdx.x * 256 + threadIdx.x;   // ROWS*36
    int row = idx / 36, r = idx % 36;
    int sec = r / 12, rr = r % 12, hh = rr >> 1, d = 30 + (rr & 1);
    qb[(size_t)row * QKVP + sec * 192 + hh * 32 + d] = __float2bfloat16(0.f);
}

// ---------------- adaptive weight repack: W[K,N] -> Wt[Npad,Kpad] bf16 -----
__global__ __launch_bounds__(256) void packW_kernel(const void* __restrict__ W,
        bf16* __restrict__ Wt, int K, int N, int Kpad, int total,
        const int* __restrict__ flag)
{
    int idx = blockIdx.x * 256 + threadIdx.x;
    if (idx >= total) return;
    int n = idx / Kpad, k = idx % Kpad;
    float v = 0.f;
    if (k < K && n < N) {
        size_t src = (size_t)k * N + n;
        v = (*flag) ? ((const float*)W)[src]
                    : __bfloat162float(((const bf16*)W)[src]);
    }
    Wt[idx] = __float2bfloat16(v);
}

// ---------------- window-attention bias table: [6][256][256] ---------------
__global__ __launch_bounds__(256) void bias_pre_kernel(const int* __restrict__ rpi,
        const float* __restrict__ rpb, float* __restrict__ bias_t)
{
    int idx = blockIdx.x * 256 + threadIdx.x;   // 6*65536
    int h = idx >> 16, ij = idx & 65535;
    bias_t[idx] = rpb[rpi[ij] * NHEADS + h];
}

// ---------------- MFMA GEMM: out = act(A@W [+bias]) [+ res] ----------------
// R18 structure: 128(M)x64(N) tile, 256 threads, global_load_lds staging,
// 8 MFMA/k-step/wave. OM=1 variant writes bf16 to padded qkv layout
// (slot = sec*192 + hh*32 + d), with Q section (sec==0) pre-scaled by scq.
template<bool GELU_, bool ADDRES, bool BIAS_, int OM>
__global__ __launch_bounds__(256) void mgemm_kernel(
        const bf16* __restrict__ A, int lda,
        const bf16* __restrict__ Wt, int ldw,
        const float* __restrict__ bias,
        const float* __restrict__ res, int ldr,
        float* __restrict__ outF, int ldo, int N, int K)
{
    __shared__ __align__(16) unsigned short As[128][32];   // 8 KB
    __shared__ __align__(16) unsigned short Bs[64][32];    // 4 KB
    int tid = threadIdx.x;
    int wave = tid >> 6, lane = tid & 63;
    int quad = lane >> 4, mr = lane & 15;
    int row0 = blockIdx.y * 128, col0 = blockIdx.x * 64;
    int ar = tid >> 2, ac = (tid & 3) * 8;   // LDS slot byte off = tid*16
    f32x4 z = {0.f, 0.f, 0.f, 0.f};
    f32x4 acc[2][4] = {{z, z, z, z}, {z, z, z, z}};
    const unsigned short* Au = (const unsigned short*)A;
    const unsigned short* Wu = (const unsigned short*)Wt;
    for (int k0 = 0; k0 < K; k0 += 32) {
        gload16(&Au[(size_t)(row0 + ar) * lda + k0 + ac],      &As[ar][ac]);
        gload16(&Au[(size_t)(row0 + 64 + ar) * lda + k0 + ac], &As[64 + ar][ac]);
        gload16(&Wu[(size_t)(col0 + ar) * ldw + k0 + ac],      &Bs[ar][ac]);
        __syncthreads();   // compiler emits vmcnt(0) drain before barrier
        v8s bfr[4];
        #pragma unroll
        for (int ni = 0; ni < 4; ni++)
            bfr[ni] = *(const v8s*)&Bs[ni * 16 + mr][quad * 8];
        #pragma unroll
        for (int s = 0; s < 2; s++) {
            v8s a = *(const v8s*)&As[wave * 32 + s * 16 + mr][quad * 8];
            #pragma unroll
            for (int ni = 0; ni < 4; ni++)
                acc[s][ni] = __builtin_amdgcn_mfma_f32_16x16x32_bf16(
                    a, bfr[ni], acc[s][ni], 0, 0, 0);
        }
        __syncthreads();
    }
    if (OM == 1) {
        bf16* outb = (bf16*)outF;
        #pragma unroll
        for (int ni = 0; ni < 4; ni++) {
            int gc = col0 + ni * 16 + mr;
            if (gc >= N) continue;
            float bv = bias[gc];
            int sec = gc / 180, rem = gc - sec * 180;
            int hh = rem / 30, d = rem - hh * 30;
            int slot = sec * 192 + hh * 32 + d;
            float sc = (sec == 0) ? 0.18257418583505536f : 1.f;
            #pragma unroll
            for (int s = 0; s < 2; s++) {
                #pragma unroll
                for (int r = 0; r < 4; r++) {
                    int gr = row0 + wave * 32 + s * 16 + quad * 4 + r;
                    outb[(size_t)gr * QKVP + slot] =
                        __float2bfloat16((acc[s][ni][r] + bv) * sc);
                }
            }
        }
        return;
    }
    #pragma unroll
    for (int ni = 0; ni < 4; ni++) {
        int gc = col0 + ni * 16 + mr;
        if (gc >= N) continue;
        float bv = BIAS_ ? bias[gc] : 0.f;
        #pragma unroll
        for (int s = 0; s < 2; s++) {
            #pragma unroll
            for (int r = 0; r < 4; r++) {
                int gr = row0 + wave * 32 + s * 16 + quad * 4 + r;
                float v = acc[s][ni][r] + bv;
                if (GELU_) v = gelu_exact(v);
                if (ADDRES) v += res[(size_t)gr * ldr + gc];
                outF[(size_t)gr * ldo + gc] = v;
            }
        }
    }
}

// ---------------- batched AV GEMM: acc[b] = P[b]@vvT[b] + x[b] -------------
// grid (3, 64, 8). P bf16 [b][4096][64]; vvT bf16 [b][192][64]; K=64.
__global__ __launch_bounds__(256) void av_mgemm_kernel(
        const bf16* __restrict__ P, const bf16* __restrict__ vvT,
        const float* __restrict__ xres, float* __restrict__ accout)
{
    __shared__ unsigned short As[64][32];
    __shared__ unsigned short Bs[64][32];
    int tid = threadIdx.x;
    int wave = tid >> 6, lane = tid & 63;
    int quad = lane >> 4, mr = lane & 15;
    int row0 = blockIdx.y * 64, col0 = blockIdx.x * 64;
    int bz = blockIdx.z;
    const unsigned short* Au = (const unsigned short*)P + (size_t)bz * NTOK * MDICT;
    const unsigned short* Wu = (const unsigned short*)vvT + (size_t)bz * 192 * MDICT;
    const float* res = xres + (size_t)bz * NTOK * CDIM;
    float* outF = accout + (size_t)bz * NTOK * CDIM;
    f32x4 z = {0.f, 0.f, 0.f, 0.f};
    f32x4 acc[4] = {z, z, z, z};
    for (int k0 = 0; k0 < MDICT; k0 += 32) {
        #pragma unroll
        for (int e = 0; e < 8; e++) {
            int idx = tid * 8 + e;
            int r = idx >> 5, c = idx & 31;
            As[r][c] = Au[(size_t)(row0 + r) * MDICT + k0 + c];
            Bs[r][c] = Wu[(size_t)(col0 + r) * MDICT + k0 + c];
        }
        __syncthreads();
        v8s a;
        #pragma unroll
        for (int j = 0; j < 8; j++) a[j] = (short)As[wave * 16 + mr][quad * 8 + j];
        #pragma unroll
        for (int ni = 0; ni < 4; ni++) {
            v8s b;
            #pragma unroll
            for (int j = 0; j < 8; j++) b[j] = (short)Bs[ni * 16 + mr][quad * 8 + j];
            acc[ni] = __builtin_amdgcn_mfma_f32_16x16x32_bf16(a, b, acc[ni], 0, 0, 0);
        }
        __syncthreads();
    }
    #pragma unroll
    for (int ni = 0; ni < 4; ni++) {
        int gc = col0 + ni * 16 + mr;
        if (gc >= CDIM) continue;
        #pragma unroll
        for (int r = 0; r < 4; r++) {
            int gr = row0 + wave * 16 + quad * 4 + r;
            float v = acc[ni][r] + res[(size_t)gr * CDIM + gc];
            outF[(size_t)gr * CDIM + gc] = v;
        }
    }
}

// ---------------- Window attention, MFMA flash (bf16 KP1 out) --------------
// R12 structure + R19 bf16-qkv input: Q/K/V loaded as aligned v8s from the
// padded [ROWS][576] layout (Q pre-scaled, pads zero) — no f2b at load.
__global__ __launch_bounds__(256, 4) void win_mfma_kernel(const bf16* __restrict__ qkvb,
        const float* __restrict__ bias_t, bf16* __restrict__ outb)
{
    int b = blockIdx.y;
    int widx = blockIdx.x / NHEADS;
    int hh = blockIdx.x % NHEADS;
    int wy = widx >> 2, wx = widx & 3;
    int tid = threadIdx.x;
    int wave = tid >> 6, lane = tid & 63, quad = lane >> 4, mr = lane & 15;
    __shared__ __align__(16) unsigned short Ks[64][40];
    __shared__ __align__(16) unsigned short Vt[32][80];

    size_t brow = (size_t)b * NTOK;
    const unsigned short* qu = (const unsigned short*)qkvb;

    v8s aq[4];
    #pragma unroll
    for (int tt = 0; tt < 4; tt++) {
        int m = (wave * 4 + tt) * 16 + mr;
        int nt_ = (wy * WS + (m >> 4)) * 64 + wx * WS + (m & 15);
        aq[tt] = *(const v8s*)&qu[(brow + nt_) * QKVP + hh * 32 + quad * 8];
    }
    f32x4 z = {0.f, 0.f, 0.f, 0.f};
    f32x4 oacc[4][2] = {{z, z}, {z, z}, {z, z}, {z, z}};
    float m_r[4], l_r[4];
    #pragma unroll
    for (int tt = 0; tt < 4; tt++) { m_r[tt] = -3.0e38f; l_r[tt] = 0.f; }
    const float* btab = bias_t + (size_t)hh * WIN_N * WIN_N;

    for (int kc = 0; kc < WIN_N; kc += 64) {
        {
            int j = tid >> 2, dg = (tid & 3) * 8;
            int tok = kc + j;
            int nt_ = (wy * WS + (tok >> 4)) * 64 + wx * WS + (tok & 15);
            const unsigned short* base = qu + (brow + nt_) * QKVP + hh * 32;
            v8s kv = *(const v8s*)&base[192 + dg];
            v8s vv = *(const v8s*)&base[384 + dg];
            *(v8s*)&Ks[j][dg] = kv;
            #pragma unroll
            for (int jj = 0; jj < 8; jj++)
                Vt[dg + jj][j] = (unsigned short)vv[jj];
        }
        __syncthreads();
        #pragma unroll
        for (int tt = 0; tt < 4; tt++) {
            // --- QK^T swapped: s[nt][r] = S[key=kc+nt*16+quad*4+r][query] ---
            f32x4 s[4];
            #pragma unroll
            for (int nt = 0; nt < 4; nt++) {
                v8s bk = *(const v8s*)&Ks[nt * 16 + mr][quad * 8];
                s[nt] = __builtin_amdgcn_mfma_f32_16x16x32_bf16(bk, aq[tt], z, 0, 0, 0);
            }
            int qg = (wave * 4 + tt) * 16 + mr;
            const float* bi = btab + (size_t)qg * WIN_N + kc;
            float mc = -3.0e38f;
            #pragma unroll
            for (int nt = 0; nt < 4; nt++) {
                f32x4 b4 = *(const f32x4*)(bi + nt * 16 + quad * 4);
                s[nt][0] += b4[0]; s[nt][1] += b4[1];
                s[nt][2] += b4[2]; s[nt][3] += b4[3];
                mc = fmaxf(mc, fmaxf(fmaxf(s[nt][0], s[nt][1]),
                                     fmaxf(s[nt][2], s[nt][3])));
            }
            mc = fmaxf(mc, __shfl_xor(mc, 16, 64));
            mc = fmaxf(mc, __shfl_xor(mc, 32, 64));
            float mn = fmaxf(m_r[tt], mc);
            float alpha = __expf(m_r[tt] - mn);
            m_r[tt] = mn;
            float ls = 0.f;
            #pragma unroll
            for (int nt = 0; nt < 4; nt++) {
                #pragma unroll
                for (int r = 0; r < 4; r++) {
                    float pp = __expf(s[nt][r] - mn);
                    ls += pp;
                    s[nt][r] = pp;
                }
            }
            ls += __shfl_xor(ls, 16, 64);
            ls += __shfl_xor(ls, 32, 64);
            l_r[tt] = l_r[tt] * alpha + ls;
            // --- pack P (bf16 pairs): dpk[nt][s] = keys nt*16+quad*4+{2s,2s+1}
            unsigned dpk[4][2];
            #pragma unroll
            for (int nt = 0; nt < 4; nt++) {
                dpk[nt][0] = packbf(s[nt][0], s[nt][1]);
                dpk[nt][1] = packbf(s[nt][2], s[nt][3]);
            }
            // --- rescale oacc rows (query = quad*4+r) by alpha ---
            #pragma unroll
            for (int r = 0; r < 4; r++) {
                float av = __shfl(alpha, quad * 4 + r, 64);
                oacc[tt][0][r] *= av;
                oacc[tt][1][r] *= av;
            }
            // --- PV: build A-frags via cross-lane shuffle, 2 chunks of K=32 --
            #pragma unroll
            for (int c = 0; c < 2; c++) {
                union { u32x4 u; v8s s8; } afu;
                #pragma unroll
                for (int t = 0; t < 4; t++) {
                    int srcl = (((quad * 2 + (t >> 1)) & 3) << 4) | mr;
                    unsigned r0 = (unsigned)__shfl((int)dpk[2 * c][t & 1], srcl, 64);
                    unsigned r1 = (unsigned)__shfl((int)dpk[2 * c + 1][t & 1], srcl, 64);
                    afu.u[t] = (quad & 2) ? r1 : r0;
                }
                #pragma unroll
                for (int dt = 0; dt < 2; dt++) {
                    v8s bv = *(const v8s*)&Vt[dt * 16 + mr][c * 32 + quad * 8];
                    oacc[tt][dt] = __builtin_amdgcn_mfma_f32_16x16x32_bf16(
                        afu.s8, bv, oacc[tt][dt], 0, 0, 0);
                }
            }
        }
        __syncthreads();
    }
    #pragma unroll
    for (int tt = 0; tt < 4; tt++) {
        float il = 1.f / l_r[tt];
        #pragma unroll
        for (int r = 0; r < 4; r++) {
            float ilr = __shfl(il, quad * 4 + r, 64);
            int m = (wave * 4 + tt) * 16 + quad * 4 + r;
            int nt_ = (wy * WS + (m >> 4)) * 64 + wx * WS + (m & 15);
            #pragma unroll
            for (int dt = 0; dt < 2; dt++) {
                int d = dt * 16 + mr;
                if (d >= HD) continue;
                outb[(brow + nt_) * KP1 + hh * HD + d] =
                    __float2bfloat16(oacc[tt][dt][r] * ilr);
            }
        }
    }
}

// ---------------- AC_MSA, MFMA flash, swapped QK^T -------------------------
// R17 structure + R19 bf16-qkv input (v8s loads, toks[] indirection).
__global__ __launch_bounds__(256, 4) void acmsa_mfma_kernel(const bf16* __restrict__ qkvb,
        const int* __restrict__ sidx, bf16* __restrict__ outb)
{
    int b = blockIdx.y;
    int g = blockIdx.x / NHEADS;
    int hh = blockIdx.x % NHEADS;
    int tid = threadIdx.x;
    int wave = tid >> 6, lane = tid & 63, quad = lane >> 4, mr = lane & 15;
    __shared__ int toks[GS];
    __shared__ __align__(16) unsigned short Ks[64][40];
    __shared__ __align__(16) unsigned short Vt[32][80];

    size_t brow = (size_t)b * NTOK;
    if (tid < GS) toks[tid] = sidx[brow + (size_t)g * GS + tid];
    __syncthreads();
    const unsigned short* qu = (const unsigned short*)qkvb;

    v8s aq[2];
    #pragma unroll
    for (int tt = 0; tt < 2; tt++) {
        int m = (wave * 2 + tt) * 16 + mr;
        aq[tt] = *(const v8s*)&qu[(brow + toks[m]) * QKVP + hh * 32 + quad * 8];
    }
    f32x4 z = {0.f, 0.f, 0.f, 0.f};
    f32x4 oacc[2][2] = {{z, z}, {z, z}};
    float m_r[2], l_r[2];
    #pragma unroll
    for (int tt = 0; tt < 2; tt++) { m_r[tt] = -3.0e38f; l_r[tt] = 0.f; }

    for (int kc = 0; kc < GS; kc += 64) {
        {
            int j = tid >> 2, dg = (tid & 3) * 8;
            int tok = toks[kc + j];
            const unsigned short* base = qu + (brow + tok) * QKVP + hh * 32;
            v8s kv = *(const v8s*)&base[192 + dg];
            v8s vv = *(const v8s*)&base[384 + dg];
            *(v8s*)&Ks[j][dg] = kv;
            #pragma unroll
            for (int jj = 0; jj < 8; jj++)
                Vt[dg + jj][j] = (unsigned short)vv[jj];
        }
        __syncthreads();
        #pragma unroll
        for (int tt = 0; tt < 2; tt++) {
            // --- QK^T swapped: s[nt][r] = S[key=kc+nt*16+quad*4+r][query=mr]
            f32x4 s[4];
            #pragma unroll
            for (int nt = 0; nt < 4; nt++) {
                v8s bk = *(const v8s*)&Ks[nt * 16 + mr][quad * 8];
                s[nt] = __builtin_amdgcn_mfma_f32_16x16x32_bf16(bk, aq[tt], z, 0, 0, 0);
            }
            float mc = -3.0e38f;
            #pragma unroll
            for (int nt = 0; nt < 4; nt++)
                mc = fmaxf(mc, fmaxf(fmaxf(s[nt][0], s[nt][1]),
                                     fmaxf(s[nt][2], s[nt][3])));
            mc = fmaxf(mc, __shfl_xor(mc, 16, 64));
            mc = fmaxf(mc, __shfl_xor(mc, 32, 64));
            float mn = fmaxf(m_r[tt], mc);
            float alpha = __expf(m_r[tt] - mn);
            m_r[tt] = mn;
            float ls = 0.f;
            #pragma unroll
            for (int nt = 0; nt < 4; nt++) {
                #pragma unroll
                for (int r = 0; r < 4; r++) {
                    float pp = __expf(s[nt][r] - mn);
                    ls += pp;
                    s[nt][r] = pp;
                }
            }
            ls += __shfl_xor(ls, 16, 64);
            ls += __shfl_xor(ls, 32, 64);
            l_r[tt] = l_r[tt] * alpha + ls;
            unsigned dpk[4][2];
            #pragma unroll
            for (int nt = 0; nt < 4; nt++) {
                dpk[nt][0] = packbf(s[nt][0], s[nt][1]);
                dpk[nt][1] = packbf(s[nt][2], s[nt][3]);
            }
            #pragma unroll
            for (int r = 0; r < 4; r++) {
                float av = __shfl(alpha, quad * 4 + r, 64);
                oacc[tt][0][r] *= av;
                oacc[tt][1][r] *= av;
            }
            #pragma unroll
            for (int c = 0; c < 2; c++) {
                union { u32x4 u; v8s s8; } afu;
                #pragma unroll
                for (int t = 0; t < 4; t++) {
                    int srcl = (((quad * 2 + (t >> 1)) & 3) << 4) | mr;
                    unsigned r0 = (unsigned)__shfl((int)dpk[2 * c][t & 1], srcl, 64);
                    unsigned r1 = (unsigned)__shfl((int)dpk[2 * c + 1][t & 1], srcl, 64);
                    afu.u[t] = (quad & 2) ? r1 : r0;
                }
                #pragma unroll
                for (int dt = 0; dt < 2; dt++) {
                    v8s bv = *(const v8s*)&Vt[dt * 16 + mr][c * 32 + quad * 8];
                    oacc[tt][dt] = __builtin_amdgcn_mfma_f32_16x16x32_bf16(
                        afu.s8, bv, oacc[tt][dt], 0, 0, 0);
                }
            }
        }
        __syncthreads();
    }
    #pragma unroll
    for (int tt = 0; tt < 2; tt++) {
        float il = 1.f / l_r[tt];
        #pragma unroll
        for (int r = 0; r < 4; r++) {
            float ilr = __shfl(il, quad * 4 + r, 64);
            int m = (wave * 2 + tt) * 16 + quad * 4 + r;
            int tok = toks[m];
            #pragma unroll
            for (int dt = 0; dt < 2; dt++) {
                int d = dt * 16 + mr;
                if (d >= HD) continue;
                outb[(brow + tok) * KP1 + hh * HD + d] =
                    __float2bfloat16(oacc[tt][dt][r] * ilr);
            }
        }
    }
}

// ---------------- LayerNorm: 4 rows/block, fp32 out + bf16 KP1 out ---------
// R21: 256 threads = 4 waves, each wave handles one row (bit-identical math).
__global__ __launch_bounds__(256) void ln_kernel(const float* __restrict__ x,
        const float* __restrict__ g, const float* __restrict__ be,
        float* __restrict__ out, bf16* __restrict__ outb)
{
    int row = blockIdx.x * 4 + (threadIdx.x >> 6);
    int t = threadIdx.x & 63;
    const float* xr = x + (size_t)row * CDIM;
    float v0 = xr[t];
    float v1 = xr[t + 64];
    float v2 = (t < CDIM - 128) ? xr[t + 128] : 0.f;
    float s1 = wave_sum(v0 + v1 + v2);
    float s2 = wave_sum(v0*v0 + v1*v1 + v2*v2);
    float mu = s1 / (float)CDIM;
    float var = s2 / (float)CDIM - mu * mu;
    float rs = rsqrtf(var + 1e-5f);
    float o0 = (v0 - mu) * rs * g[t]      + be[t];
    float o1 = (v1 - mu) * rs * g[t + 64] + be[t + 64];
    float o2 = (t < CDIM - 128) ? ((v2 - mu) * rs * g[t + 128] + be[t + 128]) : 0.f;
    float* o = out + (size_t)row * CDIM;
    o[t] = o0; o[t + 64] = o1;
    if (t < CDIM - 128) o[t + 128] = o2;
    bf16* ob = outb + (size_t)row * KP1;
    ob[t]       = __float2bfloat16(o0);
    ob[t + 64]  = __float2bfloat16(o1);
    ob[t + 128] = __float2bfloat16(o2);   // cols 180..191 get 0 (t>=52 -> o2=0)
}

// ---------------- Dictionary precompute: kkn (l2), vvT bf16, td_proj -------
__global__ __launch_bounds__(64) void td_pre_kernel(const float* __restrict__ td,
        const float* __restrict__ wk, const float* __restrict__ wkb,
        const float* __restrict__ wv, const float* __restrict__ wvb,
        const float* __restrict__ wtd, const float* __restrict__ wtdb,
        float* __restrict__ kkn, bf16* __restrict__ vvT, float* __restrict__ tdp)
{
    int blk = blockIdx.x;   // b*64 + m
    int b = blk >> 6, m = blk & 63;
    int t = threadIdx.x;
    __shared__ float tr[CDIM];
    __shared__ float sk[RD];
    __shared__ float snorm;
    const float* tdr = td + (size_t)blk * CDIM;
    tr[t] = tdr[t]; tr[t + 64] = tdr[t + 64];
    if (t < CDIM - 128) tr[t + 128] = tdr[t + 128];
    __syncthreads();
    if (t < RD) {
        float s = wkb[t];
        for (int k = 0; k < CDIM; k++) s += tr[k] * wk[k * RD + t];
        sk[t] = s;
    }
    __syncthreads();
    if (t == 0) {
        float s = 0.f;
        #pragma unroll
        for (int j = 0; j < RD; j++) s += sk[j] * sk[j];
        snorm = fmaxf(sqrtf(s), 1e-12f);
    }
    __syncthreads();
    if (t < RD) kkn[(size_t)blk * RD + t] = sk[t] / snorm;
    // vvT[b][c][m] bf16, c padded to 192 (tail rows zero)
    for (int c = t; c < 192; c += 64) {
        float s = 0.f;
        if (c < CDIM) {
            s = wvb[c];
            for (int k = 0; k < CDIM; k++) s += tr[k] * wv[k * CDIM + c];
        }
        vvT[((size_t)(b * 192 + c)) * MDICT + m] = __float2bfloat16(s);
    }
    {
        float s = wtdb[t];
        for (int k = 0; k < CDIM; k++) s += tr[k] * wtd[k * DTD + t];
        tdp[(size_t)blk * DTD + t] = s;
    }
}

// ---------------- ATD softmax/argmax: 4 rows/block (fp32 exact) ------------
// R21: 256 threads = 4 waves, each wave one row (wave-local, bit-identical).
__global__ __launch_bounds__(256) void atd_soft_kernel(const float* __restrict__ xn,
        const float* __restrict__ wq, const float* __restrict__ wqb,
        const float* __restrict__ scale_p, const float* __restrict__ kkn,
        bf16* __restrict__ Pout, int* __restrict__ tk_id)
{
    int row = blockIdx.x * 4 + (threadIdx.x >> 6);
    int b = row >> 12;
    int t = threadIdx.x & 63;
    const float* xrow = xn + (size_t)row * CDIM;
    float v0 = xrow[t];
    float v1 = xrow[t + 64];
    float v2 = (t < CDIM - 128) ? xrow[t + 128] : 0.f;
    // q-proj: all 64 lanes contribute; wave_sum broadcasts result to all lanes
    float sq[RD];
    #pragma unroll
    for (int j = 0; j < RD; j++) {
        float part = v0 * wq[t * RD + j] + v1 * wq[(t + 64) * RD + j];
        if (t < CDIM - 128) part += v2 * wq[(t + 128) * RD + j];
        sq[j] = wave_sum(part) + wqb[j];
    }
    float qn = 0.f;
    #pragma unroll
    for (int j = 0; j < RD; j++) qn += sq[j] * sq[j];
    qn = fmaxf(sqrtf(qn), 1e-12f);
    float ls = 1.0f + fminf(fmaxf(scale_p[0], 0.f), 3.f) * 4.158883083359672f;
    const float* kr = kkn + ((size_t)b * MDICT + t) * RD;
    float s = 0.f;
    #pragma unroll
    for (int j = 0; j < RD; j++) s += sq[j] * kr[j];
    s = s / qn * ls;
    // 64-lane softmax + first-index argmax (fp32 exact)
    float mv = s; int mi = t;
    #pragma unroll
    for (int off = 32; off > 0; off >>= 1) {
        float ov = __shfl_xor(mv, off, 64);
        int   oi = __shfl_xor(mi, off, 64);
        if (ov > mv || (ov == mv && oi < mi)) { mv = ov; mi = oi; }
    }
    float e = __expf(s - mv);
    float denom = wave_sum(e);
    Pout[(size_t)row * MDICT + t] = __float2bfloat16(e / denom);
    if (t == 0) tk_id[row] = mi;
}

// ---------------- Stable counting sort of tk_id ----------------------------
__global__ __launch_bounds__(256) void sort_kernel(const int* __restrict__ tk_id,
                                                   int* __restrict__ sidx)
{
    int b = blockIdx.x; int tid = threadIdx.x;
    __shared__ int keys[NTOK];
    __shared__ int cnt[256];
    __shared__ int off[256];
    const int* kb = tk_id + (size_t)b * NTOK;
    for (int i = tid; i < NTOK; i += 256) keys[i] = kb[i];
    __syncthreads();
    int v = tid >> 2, seg = tid & 3;
    int lo = seg * 1024, hi = lo + 1024;
    int c = 0;
    for (int i = lo; i < hi; i++) c += (keys[i] == v);
    cnt[tid] = c;
    __syncthreads();
    if (tid == 0) {
        int run = 0;
        for (int l = 0; l < 256; l++) { off[l] = run; run += cnt[l]; }
    }
    __syncthreads();
    int o = off[tid];
    int* sb = sidx + (size_t)b * NTOK;
    for (int i = lo; i < hi; i++) if (keys[i] == v) sb[o++] = i;
}

// ---------------- Gather dictionary features into hc[:, 360:424] -----------
__global__ __launch_bounds__(256) void gather_td_kernel(const int* __restrict__ tk_id,
        const float* __restrict__ tdp, float* __restrict__ hc)
{
    int idx = blockIdx.x * 256 + threadIdx.x;
    int row = idx >> 6, j = idx & 63;
    int b = row >> 12;
    int tk = tk_id[row];
    hc[(size_t)row * CCAT + MHID + j] = tdp[((size_t)b * MDICT + tk) * DTD + j];
}

// ---------------- Depthwise 5x5 conv: CHK=64, 8x8 tile, bf16 KP2 out -------
// R15 VERBATIM (proven 3x: ~98.5us, VGPR 68, conflicts 0, writes ideal):
// write-ownership layout (block owns full 128B output lines) + b128 LDS
// reads. sh[144][68] pixel-major (272B rows, uniform 8/bank). 4 f32x4
// subgroups sequential; sched_barrier(0) per 5-tap row caps load hoisting.
#define CHK3 64
#define CTW  8
#define CTH  8
#define CHW  12     // halo width/height = tile + 4
#define CHP  144    // 12*12 halo pixels
#define CSPX 68     // floats per pixel row (64 + 4 pad) = 272B, 16B-aligned
__global__ __launch_bounds__(256) void conv_kernel(const float* __restrict__ hc,
        const float* __restrict__ w, const float* __restrict__ wb,
        bf16* __restrict__ outb)
{
    int ch0 = blockIdx.x * CHK3;        // 0,64,...,384 (7 blocks; 424..447 zeroed)
    int tile = blockIdx.y;              // 64 tiles of 8x8
    int b = blockIdx.z;
    int ty0 = (tile >> 3) * CTH, tx0 = (tile & 7) * CTW;
    __shared__ __align__(16) float sh[CHP][CSPX];   // 39168 B
    __shared__ __align__(16) float wt[25][CHK3];    // 6400 B
    int tid = threadIdx.x;
    // stage input: lanes cover 64 contiguous channels of one pixel (256B)
    for (int idx = tid; idx < CHP * CHK3; idx += 256) {
        int pix = idx >> 6, ch = idx & 63;
        int gy = ty0 + pix / CHW - 2, gx = tx0 + pix % CHW - 2;
        int chg = ch0 + ch;
        float v = 0.f;
        if (gy >= 0 && gy < 64 && gx >= 0 && gx < 64 && chg < CCAT)
            v = hc[((size_t)b * NTOK + gy * 64 + gx) * CCAT + chg];
        sh[pix][ch] = v;
    }
    for (int idx = tid; idx < 25 * CHK3; idx += 256) {
        int kk = idx >> 6, ch = idx & 63;
        int chg = ch0 + ch;
        wt[kk][ch] = (chg < CCAT) ? w[chg * 25 + kk] : 0.f;
    }
    __syncthreads();
    int q = tid & 3, p = tid >> 2;      // p: pixel 0..63; q: 16-ch subgroup
    int px = p & 7, py = p >> 3;
    int cb = q * 16;
    int pc = py * CHW + px;             // top-left of 5x5 window
    v8s pk0, pk1;
    #pragma unroll
    for (int sub = 0; sub < 4; sub++) {
        int cs = cb + sub * 4;
        f32x4 acc = {0.f, 0.f, 0.f, 0.f};
        #pragma unroll
        for (int dy = 0; dy < 5; dy++) {
            #pragma unroll
            for (int dx = 0; dx < 5; dx++) {
                f32x4 sv = *(const f32x4*)&sh[pc + dy * CHW + dx][cs];
                f32x4 wv = *(const f32x4*)&wt[dy * 5 + dx][cs];
                acc += sv * wv;
            }
            __builtin_amdgcn_sched_barrier(0);   // cap hoisting at one row
        }
        f32x4 ctr = *(const f32x4*)&sh[pc + 2 * CHW + 2][cs];
        #pragma unroll
        for (int c = 0; c < 4; c++) {
            int chg = ch0 + cs + c;
            float v = 0.f;
            if (chg < CCAT) {
                float gv = gelu_exact(acc[c] + wb[chg]);
                v = ctr[c] + gv;
            }
            int lc = sub * 4 + c;
            if (lc < 8) pk0[lc] = (short)f2b(v);
            else        pk1[lc - 8] = (short)f2b(v);
        }
        __builtin_amdgcn_sched_barrier(0);
    }
    size_t obase = ((size_t)b * NTOK + (ty0 + py) * 64 + tx0 + px) * KP2 + ch0 + cb;
    unsigned short* ob = (unsigned short*)outb + obase;   // 32B-aligned
    *(v8s*)ob = pk0;
    *(v8s*)(ob + 8) = pk1;
}

// ---------------------------------------------------------------------------
extern "C" void kernel_launch(void* const* d_in, const int* in_sizes, int n_in,
                              void* d_out, int out_size, void* d_ws, size_t ws_size,
                              hipStream_t stream)
{
    (void)n_in; (void)ws_size; (void)out_size;
    const int* rpi = (const int*)d_in[28];

    // ---- workspace carve-up ----
    float* p = (float*)d_ws;
    float* xn    = p; p += (size_t)ROWS * CDIM;
    float* acc   = p; p += (size_t)ROWS * CDIM;
    float* tmp1  = p; p += (size_t)ROWS * CDIM;    // alias: P bf16 (head), fc2 out
    float* qkv   = p; p += (size_t)ROWS * C3;      // alias: qkvb bf16; hc fp32 post-win
    float* hcnew = p; p += (size_t)ROWS * CCAT;    // alias: xnb/tmp1b; then conv bf16 out
    float* kkn   = p; p += (size_t)BB * MDICT * RD;
    bf16*  vvT   = (bf16*)p; p += (size_t)BB * 192 * MDICT / 2;   // bf16 [8][192][64]
    float* tdp   = p; p += (size_t)BB * MDICT * DTD;
    int*   tk_id = (int*)p; p += ROWS;
    int*   sidx  = (int*)p; p += ROWS;
    int*   flag  = (int*)p; p += 64;
    int*   diag  = (int*)p; p += 64;
    bf16* wtqkv = (bf16*)p; p += 576 * KP1 / 2;
    bf16* wtaca = (bf16*)p; p += 192 * KP1 / 2;
    bf16* wtwin = (bf16*)p; p += 192 * KP1 / 2;
    bf16* wtfc1 = (bf16*)p; p += 384 * KP1 / 2;
    bf16* wtfc2 = (bf16*)p; p += 192 * KP2 / 2;
    float* cin[28];
    for (int i = 0; i < 28; i++) { cin[i] = p; p += in_sizes[i]; }
    float* bias_t = p; p += (size_t)NHEADS * WIN_N * WIN_N;   // 1.5 MB

    float* hc      = qkv;                // fp32 [ROWS,CCAT]; born after win (qkv dead)
    bf16*  qkvb    = (bf16*)qkv;         // bf16 [ROWS,576] padded; dies at win
    bf16*  xnb     = (bf16*)hcnew;                            // [ROWS,KP1]; dies at fc1
    bf16*  tmp1b   = (bf16*)(hcnew + (size_t)ROWS * KP1 / 2); // [ROWS,KP1]; dies at winp
    bf16*  hcnewb2 = (bf16*)hcnew;       // [ROWS,KP2] bf16; born at conv
    bf16*  Pbuf    = (bf16*)tmp1;        // [ROWS,64] bf16 = 4MB; dies after av_mgemm
                                         // (tmp1 fp32 reborn at fc2 much later)

    // ---- dtype detect (+diag=0) + batched input normalize to fp32 ----
    detect_kernel<<<1, 256, 0, stream>>>(d_in[0], flag, diag);
    {
        CvtArgs ca;
        int total = 0, s = 0;
        for (int i = 0; i < 28; i++) {
            if (i == 4 || i == 13 || i == 16 || i == 20 || i == 24) continue;
            ca.src[s] = d_in[i];
            ca.dst[s] = cin[i];
            ca.cum[s] = total;
            total += in_sizes[i];
            s++;
        }
        ca.cum[s] = total;
        convert_all_kernel<<<(total + 255) / 256, 256, 0, stream>>>(ca, total, flag);
    }
    const float *x = cin[0], *td = cin[1], *n1g = cin[2], *n1b = cin[3],
        *wqkv_b = cin[5], *wq_w = cin[6], *wq_b = cin[7],
        *wk_w = cin[8], *wk_b = cin[9], *wv_w = cin[10], *wv_b = cin[11],
        *atd_scale = cin[12], *aca_b = cin[14], *win_rpb = cin[15],
        *winp_b = cin[17], *fctd_w = cin[18], *fctd_b = cin[19],
        *fc1_b = cin[21], *dw_w = cin[22], *dw_b = cin[23], *fc2_b = cin[25],
        *n2g = cin[26], *n2b = cin[27];

    // ---- adaptive weight repacks (by value) + bias table ----
    packW_kernel<<<576 * KP1 / 256, 256, 0, stream>>>(d_in[4],  wtqkv, CDIM, C3,   KP1, 576 * KP1, flag);
    packW_kernel<<<192 * KP1 / 256, 256, 0, stream>>>(d_in[13], wtaca, CDIM, CDIM, KP1, 192 * KP1, flag);
    packW_kernel<<<192 * KP1 / 256, 256, 0, stream>>>(d_in[16], wtwin, CDIM, CDIM, KP1, 192 * KP1, flag);
    packW_kernel<<<384 * KP1 / 256, 256, 0, stream>>>(d_in[20], wtfc1, CDIM, MHID, KP1, 384 * KP1, flag);
    packW_kernel<<<192 * KP2 / 256, 256, 0, stream>>>(d_in[24], wtfc2, CCAT, CDIM, KP2, 192 * KP2, flag);
    bias_pre_kernel<<<NHEADS * WIN_N * WIN_N / 256, 256, 0, stream>>>(rpi, win_rpb, bias_t);

    td_pre_kernel<<<BB * MDICT, 64, 0, stream>>>(td, wk_w, wk_b, wv_w, wv_b,
                                                 fctd_w, fctd_b, kkn, vvT, tdp);
    // LN1 with fused bf16-KP1 output (4 rows/block)
    ln_kernel<<<ROWS / 4, 256, 0, stream>>>(x, n1g, n1b, xn, xnb);
    // qkv gemm: bf16 padded output (Q pre-scaled), then zero pad slots
    mgemm_kernel<false, false, true, 1><<<dim3(9, ROWS / 128), 256, 0, stream>>>(
        xnb, KP1, wtqkv, KP1, wqkv_b, nullptr, 0, (float*)qkvb, QKVP, C3, KP1);
    zero_qkvpad_kernel<<<ROWS * 36 / 256, 256, 0, stream>>>(qkvb);
    // ATD: fp32 softmax/argmax -> P bf16 + tk_id; then batched MFMA AV
    atd_soft_kernel<<<ROWS / 4, 256, 0, stream>>>(xn, wq_w, wq_b, atd_scale, kkn, Pbuf, tk_id);
    av_mgemm_kernel<<<dim3(3, NTOK / 64, BB), 256, 0, stream>>>(Pbuf, vvT, x, acc);
    sort_kernel<<<BB, 256, 0, stream>>>(tk_id, sidx);
    // zero K-tail of tmp1b once; both attentions leave cols 180..191 untouched
    zero_tail_kernel<<<ROWS * 12 / 256, 256, 0, stream>>>(tmp1b);
    // MFMA flash AC_MSA -> tmp1b (bf16 direct)
    acmsa_mfma_kernel<<<dim3(NG * NHEADS, BB), 256, 0, stream>>>(qkvb, sidx, tmp1b);
    mgemm_kernel<false, true, true, 0><<<dim3(3, ROWS / 128), 256, 0, stream>>>(
        tmp1b, KP1, wtaca, KP1, aca_b, acc, CDIM, acc, CDIM, CDIM, KP1);
    // MFMA flash window attention -> tmp1b (bf16 direct)
    win_mfma_kernel<<<dim3(16 * NHEADS, BB), 256, 0, stream>>>(qkvb, bias_t, tmp1b);
    mgemm_kernel<false, true, true, 0><<<dim3(3, ROWS / 128), 256, 0, stream>>>(
        tmp1b, KP1, wtwin, KP1, winp_b, acc, CDIM, acc, CDIM, CDIM, KP1);
    // FFN: LN2 fused bf16 out -> fc1 -> gather -> conv (bf16 KP2 direct) -> fc2
    ln_kernel<<<ROWS / 4, 256, 0, stream>>>(acc, n2g, n2b, xn, xnb);
    mgemm_kernel<true, false, true, 0><<<dim3(6, ROWS / 128), 256, 0, stream>>>(
        xnb, KP1, wtfc1, KP1, fc1_b, nullptr, 0, hc, CCAT, MHID, KP1);
    gather_td_kernel<<<ROWS * 64 / 256, 256, 0, stream>>>(tk_id, tdp, hc);
    conv_kernel<<<dim3(7, 64, BB), 256, 0, stream>>>(hc, dw_w, dw_b, hcnewb2);
    mgemm_kernel<false, true, true, 0><<<dim3(3, ROWS / 128), 256, 0, stream>>>(
        hcnewb2, KP2, wtfc2, KP2, fc2_b, acc, CDIM, tmp1, CDIM, CDIM, KP2);
    check_f32_kernel<<<(ROWS * CDIM + 255) / 256, 256, 0, stream>>>(tmp1, ROWS * CDIM, 8, diag);
    emit_kernel<<<(ROWS * CDIM + 255) / 256, 256, 0, stream>>>(
        tmp1, d_out, flag, diag, ROWS * CDIM);
}

// Round 11
// 690.160 us; speedup vs baseline: 1.0918x; 1.0171x over previous
//
#include <hip/hip_runtime.h>
#include <hip/hip_bf16.h>
#include <math.h>

// MPv2_3d_arch: B=8, n=64*64=4096, c=180, heads=6 (hd=30), dict M=64, rd=10,
// dtd=64, mlp_hid=360, cat C=424, window 16x16, groups of 128.
// R22: R21 (passing, 702us) + bit-identical consolidation:
// (a) ln1+atd fused (atd consumed exactly ln1's fp32 regs; xn buffer dead:
//     -47MB traffic, -1 launch); (b) ln2 drops fp32 out (-24MB);
// (c) NaN check folded into fc2 epilogue (OM=2; -24MB read, -1 launch);
// (d) zero_tail+zero_qkvpad merged (-1 launch). Conv = R15 verbatim (proven
// 98.5us x4). All numerics bit-identical to R21.
// SESSION RULE: input dtype VARIES per run (bf16 or fp32) — every d_in
// access must go through *flag (by value). Raw-bit reads = NaN.
#define BB      8
#define NTOK    4096
#define CDIM    180
#define C3      540
#define NHEADS  6
#define HD      30
#define MDICT   64
#define RD      10
#define DTD     64
#define MHID    360
#define CCAT    424
#define WS      16
#define WIN_N   256
#define GS      128
#define NG      32
#define ROWS    (BB*NTOK)   // 32768
#define KP1     192         // Kpad for K=180
#define KP2     448         // Kpad for K=424
#define QKVP    576         // padded qkv row: 3 sec * 6 heads * 32

typedef __hip_bfloat16 bf16;
typedef short v8s __attribute__((ext_vector_type(8)));
typedef float f32x4 __attribute__((ext_vector_type(4)));
typedef unsigned int u32x4 __attribute__((ext_vector_type(4)));

__device__ __forceinline__ float gelu_exact(float x) {
    return 0.5f * x * (1.0f + erff(x * 0.70710678118654752f));
}
__device__ __forceinline__ float wave_sum(float v) {
    #pragma unroll
    for (int off = 32; off > 0; off >>= 1) v += __shfl_xor(v, off, 64);
    return v;
}
// fp32 <-> bf16 bits without type-punning (RNE)
__device__ __forceinline__ unsigned short f2b(float v) {
    unsigned u = __float_as_uint(v);
    return (unsigned short)((u + 0x7FFFu + ((u >> 16) & 1u)) >> 16);
}
__device__ __forceinline__ float b2f(unsigned short h) {
    return __uint_as_float(((unsigned)h) << 16);
}
__device__ __forceinline__ unsigned packbf(float lo, float hi) {
    return (unsigned)f2b(lo) | ((unsigned)f2b(hi) << 16);
}
// async global->LDS 16B (gfx950); size must be literal; lds addr = per-lane
// slot in lane-order-contiguous slab (wave-uniform base + lane*16).
__device__ __forceinline__ void gload16(const void* g, void* l) {
    __builtin_amdgcn_global_load_lds(
        (const __attribute__((address_space(1))) void*)g,
        (__attribute__((address_space(3))) void*)l, 16, 0, 0);
}

// ---------------- dtype detector: flag=1 if inputs are fp32, 0 if bf16 -----
__global__ __launch_bounds__(256) void detect_kernel(const void* __restrict__ x,
                                                     int* __restrict__ flag,
                                                     int* __restrict__ diag)
{
    __shared__ int cnt;
    if (threadIdx.x == 0) { cnt = 0; *diag = 0; }
    __syncthreads();
    const unsigned short* u = (const unsigned short*)x;
    int c = 0;
    for (int i = threadIdx.x; i < 2048; i += 256) {
        unsigned short e = u[2 * i] & 0x7F80;
        if (e >= 0x4300) c++;
    }
    atomicAdd(&cnt, c);
    __syncthreads();
    if (threadIdx.x == 0) *flag = (cnt > 16) ? 1 : 0;
}

// ---------------- batched dtype-flexible input -> fp32 conversion ----------
#define NCVT 23
struct CvtArgs {
    const void* src[NCVT];
    float* dst[NCVT];
    int cum[NCVT + 1];
};
__global__ __launch_bounds__(256) void convert_all_kernel(CvtArgs a, int total,
        const int* __restrict__ flag)
{
    int i = blockIdx.x * 256 + threadIdx.x;
    if (i >= total) return;
    int s = 0;
    while (i >= a.cum[s + 1]) s++;   // x is segment 0 -> most threads exit fast
    int off = i - a.cum[s];
    if (*flag) a.dst[s][off] = ((const float*)a.src[s])[off];
    else       a.dst[s][off] = __bfloat162float(((const bf16*)a.src[s])[off]);
}

// ---------------- output emit: fp32 src -> d_out in detected dtype ---------
__global__ __launch_bounds__(256) void emit_kernel(const float* __restrict__ src,
        void* __restrict__ out, const int* __restrict__ flag,
        const int* __restrict__ diag, int n)
{
    int i = blockIdx.x * 256 + threadIdx.x;
    if (i >= n) return;
    float v = src[i];
    int d = *diag;
    if (d) v = 100.f + 32.f * (float)d;   // NaN stage code -> absmax bin
    if (*flag) ((float*)out)[i] = v;
    else       ((bf16*)out)[i]  = __float2bfloat16(v);
}

// ---------------- merged zeroing: tmp1b cols 180..191 + qkvb pad slots -----
__global__ __launch_bounds__(256) void zero_aux_kernel(bf16* __restrict__ tb,
        bf16* __restrict__ qb)
{
    int idx = blockIdx.x * 256 + threadIdx.x;   // ROWS*48
    if (idx < ROWS * 12) {
        int row = idx / 12, c = idx % 12;
        tb[(size_t)row * KP1 + CDIM + c] = __float2bfloat16(0.f);
    } else {
        int j = idx - ROWS * 12;
        int row = j / 36, r = j % 36;
        int sec = r / 12, rr = r % 12, hh = rr >> 1, d = 30 + (rr & 1);
        qb[(size_t)row * QKVP + sec * 192 + hh * 32 + d] = __float2bfloat16(0.f);
    }
}

// ---------------- adaptive weight repack: W[K,N] -> Wt[Npad,Kpad] bf16 -----
__global__ __launch_bounds__(256) void packW_kernel(const void* __restrict__ W,
        bf16* __restrict__ Wt, int K, int N, int Kpad, int total,
        const int* __restrict__ flag)
{
    int idx = blockIdx.x * 256 + threadIdx.x;
    if (idx >= total) return;
    int n = idx / Kpad, k = idx % Kpad;
    float v = 0.f;
    if (k < K && n < N) {
        size_t src = (size_t)k * N + n;
        v = (*flag) ? ((const float*)W)[src]
                    : __bfloat162float(((const bf16*)W)[src]);
    }
    Wt[idx] = __float2bfloat16(v);
}

// ---------------- window-attention bias table: [6][256][256] ---------------
__global__ __launch_bounds__(256) void bias_pre_kernel(const int* __restrict__ rpi,
        const float* __restrict__ rpb, float* __restrict__ bias_t)
{
    int idx = blockIdx.x * 256 + threadIdx.x;   // 6*65536
    int h = idx >> 16, ij = idx & 65535;
    bias_t[idx] = rpb[rpi[ij] * NHEADS + h];
}

// ---------------- MFMA GEMM: out = act(A@W [+bias]) [+ res] ----------------
// R18 structure: 128(M)x64(N) tile, 256 threads, global_load_lds staging,
// 8 MFMA/k-step/wave. OM=1: bf16 out to padded qkv layout (Q pre-scaled).
// OM=2: fp32 out + res + fused NaN check into diag (replaces check kernel).
template<bool GELU_, bool ADDRES, bool BIAS_, int OM>
__global__ __launch_bounds__(256) void mgemm_kernel(
        const bf16* __restrict__ A, int lda,
        const bf16* __restrict__ Wt, int ldw,
        const float* __restrict__ bias,
        const float* __restrict__ res, int ldr,
        float* __restrict__ outF, int ldo, int N, int K,
        int* __restrict__ diag)
{
    __shared__ __align__(16) unsigned short As[128][32];   // 8 KB
    __shared__ __align__(16) unsigned short Bs[64][32];    // 4 KB
    int tid = threadIdx.x;
    int wave = tid >> 6, lane = tid & 63;
    int quad = lane >> 4, mr = lane & 15;
    int row0 = blockIdx.y * 128, col0 = blockIdx.x * 64;
    int ar = tid >> 2, ac = (tid & 3) * 8;   // LDS slot byte off = tid*16
    f32x4 z = {0.f, 0.f, 0.f, 0.f};
    f32x4 acc[2][4] = {{z, z, z, z}, {z, z, z, z}};
    const unsigned short* Au = (const unsigned short*)A;
    const unsigned short* Wu = (const unsigned short*)Wt;
    for (int k0 = 0; k0 < K; k0 += 32) {
        gload16(&Au[(size_t)(row0 + ar) * lda + k0 + ac],      &As[ar][ac]);
        gload16(&Au[(size_t)(row0 + 64 + ar) * lda + k0 + ac], &As[64 + ar][ac]);
        gload16(&Wu[(size_t)(col0 + ar) * ldw + k0 + ac],      &Bs[ar][ac]);
        __syncthreads();   // compiler emits vmcnt(0) drain before barrier
        v8s bfr[4];
        #pragma unroll
        for (int ni = 0; ni < 4; ni++)
            bfr[ni] = *(const v8s*)&Bs[ni * 16 + mr][quad * 8];
        #pragma unroll
        for (int s = 0; s < 2; s++) {
            v8s a = *(const v8s*)&As[wave * 32 + s * 16 + mr][quad * 8];
            #pragma unroll
            for (int ni = 0; ni < 4; ni++)
                acc[s][ni] = __builtin_amdgcn_mfma_f32_16x16x32_bf16(
                    a, bfr[ni], acc[s][ni], 0, 0, 0);
        }
        __syncthreads();
    }
    if (OM == 1) {
        bf16* outb = (bf16*)outF;
        #pragma unroll
        for (int ni = 0; ni < 4; ni++) {
            int gc = col0 + ni * 16 + mr;
            if (gc >= N) continue;
            float bv = bias[gc];
            int sec = gc / 180, rem = gc - sec * 180;
            int hh = rem / 30, d = rem - hh * 30;
            int slot = sec * 192 + hh * 32 + d;
            float sc = (sec == 0) ? 0.18257418583505536f : 1.f;
            #pragma unroll
            for (int s = 0; s < 2; s++) {
                #pragma unroll
                for (int r = 0; r < 4; r++) {
                    int gr = row0 + wave * 32 + s * 16 + quad * 4 + r;
                    outb[(size_t)gr * QKVP + slot] =
                        __float2bfloat16((acc[s][ni][r] + bv) * sc);
                }
            }
        }
        return;
    }
    #pragma unroll
    for (int ni = 0; ni < 4; ni++) {
        int gc = col0 + ni * 16 + mr;
        if (gc >= N) continue;
        float bv = BIAS_ ? bias[gc] : 0.f;
        #pragma unroll
        for (int s = 0; s < 2; s++) {
            #pragma unroll
            for (int r = 0; r < 4; r++) {
                int gr = row0 + wave * 32 + s * 16 + quad * 4 + r;
                float v = acc[s][ni][r] + bv;
                if (GELU_) v = gelu_exact(v);
                if (ADDRES) v += res[(size_t)gr * ldr + gc];
                if (OM == 2) {
                    unsigned u = __float_as_uint(v);
                    if ((u & 0x7F800000u) == 0x7F800000u) atomicOr(diag, 8);
                }
                outF[(size_t)gr * ldo + gc] = v;
            }
        }
    }
}

// ---------------- batched AV GEMM: acc[b] = P[b]@vvT[b] + x[b] -------------
// grid (3, 64, 8). P bf16 [b][4096][64]; vvT bf16 [b][192][64]; K=64.
__global__ __launch_bounds__(256) void av_mgemm_kernel(
        const bf16* __restrict__ P, const bf16* __restrict__ vvT,
        const float* __restrict__ xres, float* __restrict__ accout)
{
    __shared__ unsigned short As[64][32];
    __shared__ unsigned short Bs[64][32];
    int tid = threadIdx.x;
    int wave = tid >> 6, lane = tid & 63;
    int quad = lane >> 4, mr = lane & 15;
    int row0 = blockIdx.y * 64, col0 = blockIdx.x * 64;
    int bz = blockIdx.z;
    const unsigned short* Au = (const unsigned short*)P + (size_t)bz * NTOK * MDICT;
    const unsigned short* Wu = (const unsigned short*)vvT + (size_t)bz * 192 * MDICT;
    const float* res = xres + (size_t)bz * NTOK * CDIM;
    float* outF = accout + (size_t)bz * NTOK * CDIM;
    f32x4 z = {0.f, 0.f, 0.f, 0.f};
    f32x4 acc[4] = {z, z, z, z};
    for (int k0 = 0; k0 < MDICT; k0 += 32) {
        #pragma unroll
        for (int e = 0; e < 8; e++) {
            int idx = tid * 8 + e;
            int r = idx >> 5, c = idx & 31;
            As[r][c] = Au[(size_t)(row0 + r) * MDICT + k0 + c];
            Bs[r][c] = Wu[(size_t)(col0 + r) * MDICT + k0 + c];
        }
        __syncthreads();
        v8s a;
        #pragma unroll
        for (int j = 0; j < 8; j++) a[j] = (short)As[wave * 16 + mr][quad * 8 + j];
        #pragma unroll
        for (int ni = 0; ni < 4; ni++) {
            v8s b;
            #pragma unroll
            for (int j = 0; j < 8; j++) b[j] = (short)Bs[ni * 16 + mr][quad * 8 + j];
            acc[ni] = __builtin_amdgcn_mfma_f32_16x16x32_bf16(a, b, acc[ni], 0, 0, 0);
        }
        __syncthreads();
    }
    #pragma unroll
    for (int ni = 0; ni < 4; ni++) {
        int gc = col0 + ni * 16 + mr;
        if (gc >= CDIM) continue;
        #pragma unroll
        for (int r = 0; r < 4; r++) {
            int gr = row0 + wave * 16 + quad * 4 + r;
            float v = acc[ni][r] + res[(size_t)gr * CDIM + gc];
            outF[(size_t)gr * CDIM + gc] = v;
        }
    }
}

// ---------------- Window attention, MFMA flash (bf16 KP1 out) --------------
// R12 structure + R19 bf16-qkv input: Q/K/V loaded as aligned v8s from the
// padded [ROWS][576] layout (Q pre-scaled, pads zero) — no f2b at load.
__global__ __launch_bounds__(256, 4) void win_mfma_kernel(const bf16* __restrict__ qkvb,
        const float* __restrict__ bias_t, bf16* __restrict__ outb)
{
    int b = blockIdx.y;
    int widx = blockIdx.x / NHEADS;
    int hh = blockIdx.x % NHEADS;
    int wy = widx >> 2, wx = widx & 3;
    int tid = threadIdx.x;
    int wave = tid >> 6, lane = tid & 63, quad = lane >> 4, mr = lane & 15;
    __shared__ __align__(16) unsigned short Ks[64][40];
    __shared__ __align__(16) unsigned short Vt[32][80];

    size_t brow = (size_t)b * NTOK;
    const unsigned short* qu = (const unsigned short*)qkvb;

    v8s aq[4];
    #pragma unroll
    for (int tt = 0; tt < 4; tt++) {
        int m = (wave * 4 + tt) * 16 + mr;
        int nt_ = (wy * WS + (m >> 4)) * 64 + wx * WS + (m & 15);
        aq[tt] = *(const v8s*)&qu[(brow + nt_) * QKVP + hh * 32 + quad * 8];
    }
    f32x4 z = {0.f, 0.f, 0.f, 0.f};
    f32x4 oacc[4][2] = {{z, z}, {z, z}, {z, z}, {z, z}};
    float m_r[4], l_r[4];
    #pragma unroll
    for (int tt = 0; tt < 4; tt++) { m_r[tt] = -3.0e38f; l_r[tt] = 0.f; }
    const float* btab = bias_t + (size_t)hh * WIN_N * WIN_N;

    for (int kc = 0; kc < WIN_N; kc += 64) {
        {
            int j = tid >> 2, dg = (tid & 3) * 8;
            int tok = kc + j;
            int nt_ = (wy * WS + (tok >> 4)) * 64 + wx * WS + (tok & 15);
            const unsigned short* base = qu + (brow + nt_) * QKVP + hh * 32;
            v8s kv = *(const v8s*)&base[192 + dg];
            v8s vv = *(const v8s*)&base[384 + dg];
            *(v8s*)&Ks[j][dg] = kv;
            #pragma unroll
            for (int jj = 0; jj < 8; jj++)
                Vt[dg + jj][j] = (unsigned short)vv[jj];
        }
        __syncthreads();
        #pragma unroll
        for (int tt = 0; tt < 4; tt++) {
            // --- QK^T swapped: s[nt][r] = S[key=kc+nt*16+quad*4+r][query] ---
            f32x4 s[4];
            #pragma unroll
            for (int nt = 0; nt < 4; nt++) {
                v8s bk = *(const v8s*)&Ks[nt * 16 + mr][quad * 8];
                s[nt] = __builtin_amdgcn_mfma_f32_16x16x32_bf16(bk, aq[tt], z, 0, 0, 0);
            }
            int qg = (wave * 4 + tt) * 16 + mr;
            const float* bi = btab + (size_t)qg * WIN_N + kc;
            float mc = -3.0e38f;
            #pragma unroll
            for (int nt = 0; nt < 4; nt++) {
                f32x4 b4 = *(const f32x4*)(bi + nt * 16 + quad * 4);
                s[nt][0] += b4[0]; s[nt][1] += b4[1];
                s[nt][2] += b4[2]; s[nt][3] += b4[3];
                mc = fmaxf(mc, fmaxf(fmaxf(s[nt][0], s[nt][1]),
                                     fmaxf(s[nt][2], s[nt][3])));
            }
            mc = fmaxf(mc, __shfl_xor(mc, 16, 64));
            mc = fmaxf(mc, __shfl_xor(mc, 32, 64));
            float mn = fmaxf(m_r[tt], mc);
            float alpha = __expf(m_r[tt] - mn);
            m_r[tt] = mn;
            float ls = 0.f;
            #pragma unroll
            for (int nt = 0; nt < 4; nt++) {
                #pragma unroll
                for (int r = 0; r < 4; r++) {
                    float pp = __expf(s[nt][r] - mn);
                    ls += pp;
                    s[nt][r] = pp;
                }
            }
            ls += __shfl_xor(ls, 16, 64);
            ls += __shfl_xor(ls, 32, 64);
            l_r[tt] = l_r[tt] * alpha + ls;
            // --- pack P (bf16 pairs): dpk[nt][s] = keys nt*16+quad*4+{2s,2s+1}
            unsigned dpk[4][2];
            #pragma unroll
            for (int nt = 0; nt < 4; nt++) {
                dpk[nt][0] = packbf(s[nt][0], s[nt][1]);
                dpk[nt][1] = packbf(s[nt][2], s[nt][3]);
            }
            // --- rescale oacc rows (query = quad*4+r) by alpha ---
            #pragma unroll
            for (int r = 0; r < 4; r++) {
                float av = __shfl(alpha, quad * 4 + r, 64);
                oacc[tt][0][r] *= av;
                oacc[tt][1][r] *= av;
            }
            // --- PV: build A-frags via cross-lane shuffle, 2 chunks of K=32 --
            #pragma unroll
            for (int c = 0; c < 2; c++) {
                union { u32x4 u; v8s s8; } afu;
                #pragma unroll
                for (int t = 0; t < 4; t++) {
                    int srcl = (((quad * 2 + (t >> 1)) & 3) << 4) | mr;
                    unsigned r0 = (unsigned)__shfl((int)dpk[2 * c][t & 1], srcl, 64);
                    unsigned r1 = (unsigned)__shfl((int)dpk[2 * c + 1][t & 1], srcl, 64);
                    afu.u[t] = (quad & 2) ? r1 : r0;
                }
                #pragma unroll
                for (int dt = 0; dt < 2; dt++) {
                    v8s bv = *(const v8s*)&Vt[dt * 16 + mr][c * 32 + quad * 8];
                    oacc[tt][dt] = __builtin_amdgcn_mfma_f32_16x16x32_bf16(
                        afu.s8, bv, oacc[tt][dt], 0, 0, 0);
                }
            }
        }
        __syncthreads();
    }
    #pragma unroll
    for (int tt = 0; tt < 4; tt++) {
        float il = 1.f / l_r[tt];
        #pragma unroll
        for (int r = 0; r < 4; r++) {
            float ilr = __shfl(il, quad * 4 + r, 64);
            int m = (wave * 4 + tt) * 16 + quad * 4 + r;
            int nt_ = (wy * WS + (m >> 4)) * 64 + wx * WS + (m & 15);
            #pragma unroll
            for (int dt = 0; dt < 2; dt++) {
                int d = dt * 16 + mr;
                if (d >= HD) continue;
                outb[(brow + nt_) * KP1 + hh * HD + d] =
                    __float2bfloat16(oacc[tt][dt][r] * ilr);
            }
        }
    }
}

// ---------------- AC_MSA, MFMA flash, swapped QK^T -------------------------
// R17 structure + R19 bf16-qkv input (v8s loads, toks[] indirection).
__global__ __launch_bounds__(256, 4) void acmsa_mfma_kernel(const bf16* __restrict__ qkvb,
        const int* __restrict__ sidx, bf16* __restrict__ outb)
{
    int b = blockIdx.y;
    int g = blockIdx.x / NHEADS;
    int hh = blockIdx.x % NHEADS;
    int tid = threadIdx.x;
    int wave = tid >> 6, lane = tid & 63, quad = lane >> 4, mr = lane & 15;
    __shared__ int toks[GS];
    __shared__ __align__(16) unsigned short Ks[64][40];
    __shared__ __align__(16) unsigned short Vt[32][80];

    size_t brow = (size_t)b * NTOK;
    if (tid < GS) toks[tid] = sidx[brow + (size_t)g * GS + tid];
    __syncthreads();
    const unsigned short* qu = (const unsigned short*)qkvb;

    v8s aq[2];
    #pragma unroll
    for (int tt = 0; tt < 2; tt++) {
        int m = (wave * 2 + tt) * 16 + mr;
        aq[tt] = *(const v8s*)&qu[(brow + toks[m]) * QKVP + hh * 32 + quad * 8];
    }
    f32x4 z = {0.f, 0.f, 0.f, 0.f};
    f32x4 oacc[2][2] = {{z, z}, {z, z}};
    float m_r[2], l_r[2];
    #pragma unroll
    for (int tt = 0; tt < 2; tt++) { m_r[tt] = -3.0e38f; l_r[tt] = 0.f; }

    for (int kc = 0; kc < GS; kc += 64) {
        {
            int j = tid >> 2, dg = (tid & 3) * 8;
            int tok = toks[kc + j];
            const unsigned short* base = qu + (brow + tok) * QKVP + hh * 32;
            v8s kv = *(const v8s*)&base[192 + dg];
            v8s vv = *(const v8s*)&base[384 + dg];
            *(v8s*)&Ks[j][dg] = kv;
            #pragma unroll
            for (int jj = 0; jj < 8; jj++)
                Vt[dg + jj][j] = (unsigned short)vv[jj];
        }
        __syncthreads();
        #pragma unroll
        for (int tt = 0; tt < 2; tt++) {
            // --- QK^T swapped: s[nt][r] = S[key=kc+nt*16+quad*4+r][query=mr]
            f32x4 s[4];
            #pragma unroll
            for (int nt = 0; nt < 4; nt++) {
                v8s bk = *(const v8s*)&Ks[nt * 16 + mr][quad * 8];
                s[nt] = __builtin_amdgcn_mfma_f32_16x16x32_bf16(bk, aq[tt], z, 0, 0, 0);
            }
            float mc = -3.0e38f;
            #pragma unroll
            for (int nt = 0; nt < 4; nt++)
                mc = fmaxf(mc, fmaxf(fmaxf(s[nt][0], s[nt][1]),
                                     fmaxf(s[nt][2], s[nt][3])));
            mc = fmaxf(mc, __shfl_xor(mc, 16, 64));
            mc = fmaxf(mc, __shfl_xor(mc, 32, 64));
            float mn = fmaxf(m_r[tt], mc);
            float alpha = __expf(m_r[tt] - mn);
            m_r[tt] = mn;
            float ls = 0.f;
            #pragma unroll
            for (int nt = 0; nt < 4; nt++) {
                #pragma unroll
                for (int r = 0; r < 4; r++) {
                    float pp = __expf(s[nt][r] - mn);
                    ls += pp;
                    s[nt][r] = pp;
                }
            }
            ls += __shfl_xor(ls, 16, 64);
            ls += __shfl_xor(ls, 32, 64);
            l_r[tt] = l_r[tt] * alpha + ls;
            unsigned dpk[4][2];
            #pragma unroll
            for (int nt = 0; nt < 4; nt++) {
                dpk[nt][0] = packbf(s[nt][0], s[nt][1]);
                dpk[nt][1] = packbf(s[nt][2], s[nt][3]);
            }
            #pragma unroll
            for (int r = 0; r < 4; r++) {
                float av = __shfl(alpha, quad * 4 + r, 64);
                oacc[tt][0][r] *= av;
                oacc[tt][1][r] *= av;
            }
            #pragma unroll
            for (int c = 0; c < 2; c++) {
                union { u32x4 u; v8s s8; } afu;
                #pragma unroll
                for (int t = 0; t < 4; t++) {
                    int srcl = (((quad * 2 + (t >> 1)) & 3) << 4) | mr;
                    unsigned r0 = (unsigned)__shfl((int)dpk[2 * c][t & 1], srcl, 64);
                    unsigned r1 = (unsigned)__shfl((int)dpk[2 * c + 1][t & 1], srcl, 64);
                    afu.u[t] = (quad & 2) ? r1 : r0;
                }
                #pragma unroll
                for (int dt = 0; dt < 2; dt++) {
                    v8s bv = *(const v8s*)&Vt[dt * 16 + mr][c * 32 + quad * 8];
                    oacc[tt][dt] = __builtin_amdgcn_mfma_f32_16x16x32_bf16(
                        afu.s8, bv, oacc[tt][dt], 0, 0, 0);
                }
            }
        }
        __syncthreads();
    }
    #pragma unroll
    for (int tt = 0; tt < 2; tt++) {
        float il = 1.f / l_r[tt];
        #pragma unroll
        for (int r = 0; r < 4; r++) {
            float ilr = __shfl(il, quad * 4 + r, 64);
            int m = (wave * 2 + tt) * 16 + quad * 4 + r;
            int tok = toks[m];
            #pragma unroll
            for (int dt = 0; dt < 2; dt++) {
                int d = dt * 16 + mr;
                if (d >= HD) continue;
                outb[(brow + tok) * KP1 + hh * HD + d] =
                    __float2bfloat16(oacc[tt][dt][r] * ilr);
            }
        }
    }
}

// ---------------- Fused LN1 + ATD softmax/argmax (4 rows/block) ------------
// R22: atd consumed exactly ln1's fp32 register values (fp32 store/load
// round-trip is exact) -> fuse; xn buffer eliminated. Bit-identical.
__global__ __launch_bounds__(256) void ln_atd_kernel(const float* __restrict__ x,
        const float* __restrict__ g, const float* __restrict__ be,
        bf16* __restrict__ outb,
        const float* __restrict__ wq, const float* __restrict__ wqb,
        const float* __restrict__ scale_p, const float* __restrict__ kkn,
        bf16* __restrict__ Pout, int* __restrict__ tk_id)
{
    int row = blockIdx.x * 4 + (threadIdx.x >> 6);
    int b = row >> 12;
    int t = threadIdx.x & 63;
    const float* xr = x + (size_t)row * CDIM;
    float v0 = xr[t];
    float v1 = xr[t + 64];
    float v2 = (t < CDIM - 128) ? xr[t + 128] : 0.f;
    float s1 = wave_sum(v0 + v1 + v2);
    float s2 = wave_sum(v0*v0 + v1*v1 + v2*v2);
    float mu = s1 / (float)CDIM;
    float var = s2 / (float)CDIM - mu * mu;
    float rs = rsqrtf(var + 1e-5f);
    float o0 = (v0 - mu) * rs * g[t]      + be[t];
    float o1 = (v1 - mu) * rs * g[t + 64] + be[t + 64];
    float o2 = (t < CDIM - 128) ? ((v2 - mu) * rs * g[t + 128] + be[t + 128]) : 0.f;
    bf16* ob = outb + (size_t)row * KP1;
    ob[t]       = __float2bfloat16(o0);
    ob[t + 64]  = __float2bfloat16(o1);
    ob[t + 128] = __float2bfloat16(o2);   // cols 180..191 get 0 (t>=52 -> o2=0)
    // ---- ATD on the same fp32 values (o0..o2 == xn row) ----
    float sq[RD];
    #pragma unroll
    for (int j = 0; j < RD; j++) {
        float part = o0 * wq[t * RD + j] + o1 * wq[(t + 64) * RD + j];
        if (t < CDIM - 128) part += o2 * wq[(t + 128) * RD + j];
        sq[j] = wave_sum(part) + wqb[j];
    }
    float qn = 0.f;
    #pragma unroll
    for (int j = 0; j < RD; j++) qn += sq[j] * sq[j];
    qn = fmaxf(sqrtf(qn), 1e-12f);
    float ls = 1.0f + fminf(fmaxf(scale_p[0], 0.f), 3.f) * 4.158883083359672f;
    const float* kr = kkn + ((size_t)b * MDICT + t) * RD;
    float s = 0.f;
    #pragma unroll
    for (int j = 0; j < RD; j++) s += sq[j] * kr[j];
    s = s / qn * ls;
    float mv = s; int mi = t;
    #pragma unroll
    for (int off = 32; off > 0; off >>= 1) {
        float ov = __shfl_xor(mv, off, 64);
        int   oi = __shfl_xor(mi, off, 64);
        if (ov > mv || (ov == mv && oi < mi)) { mv = ov; mi = oi; }
    }
    float e = __expf(s - mv);
    float denom = wave_sum(e);
    Pout[(size_t)row * MDICT + t] = __float2bfloat16(e / denom);
    if (t == 0) tk_id[row] = mi;
}

// ---------------- LayerNorm (bf16 KP1 out only; fp32 out dropped) ----------
__global__ __launch_bounds__(256) void ln_kernel(const float* __restrict__ x,
        const float* __restrict__ g, const float* __restrict__ be,
        bf16* __restrict__ outb)
{
    int row = blockIdx.x * 4 + (threadIdx.x >> 6);
    int t = threadIdx.x & 63;
    const float* xr = x + (size_t)row * CDIM;
    float v0 = xr[t];
    float v1 = xr[t + 64];
    float v2 = (t < CDIM - 128) ? xr[t + 128] : 0.f;
    float s1 = wave_sum(v0 + v1 + v2);
    float s2 = wave_sum(v0*v0 + v1*v1 + v2*v2);
    float mu = s1 / (float)CDIM;
    float var = s2 / (float)CDIM - mu * mu;
    float rs = rsqrtf(var + 1e-5f);
    float o0 = (v0 - mu) * rs * g[t]      + be[t];
    float o1 = (v1 - mu) * rs * g[t + 64] + be[t + 64];
    float o2 = (t < CDIM - 128) ? ((v2 - mu) * rs * g[t + 128] + be[t + 128]) : 0.f;
    bf16* ob = outb + (size_t)row * KP1;
    ob[t]       = __float2bfloat16(o0);
    ob[t + 64]  = __float2bfloat16(o1);
    ob[t + 128] = __float2bfloat16(o2);   // cols 180..191 get 0 (t>=52 -> o2=0)
}

// ---------------- Dictionary precompute: kkn (l2), vvT bf16, td_proj -------
__global__ __launch_bounds__(64) void td_pre_kernel(const float* __restrict__ td,
        const float* __restrict__ wk, const float* __restrict__ wkb,
        const float* __restrict__ wv, const float* __restrict__ wvb,
        const float* __restrict__ wtd, const float* __restrict__ wtdb,
        float* __restrict__ kkn, bf16* __restrict__ vvT, float* __restrict__ tdp)
{
    int blk = blockIdx.x;   // b*64 + m
    int b = blk >> 6, m = blk & 63;
    int t = threadIdx.x;
    __shared__ float tr[CDIM];
    __shared__ float sk[RD];
    __shared__ float snorm;
    const float* tdr = td + (size_t)blk * CDIM;
    tr[t] = tdr[t]; tr[t + 64] = tdr[t + 64];
    if (t < CDIM - 128) tr[t + 128] = tdr[t + 128];
    __syncthreads();
    if (t < RD) {
        float s = wkb[t];
        for (int k = 0; k < CDIM; k++) s += tr[k] * wk[k * RD + t];
        sk[t] = s;
    }
    __syncthreads();
    if (t == 0) {
        float s = 0.f;
        #pragma unroll
        for (int j = 0; j < RD; j++) s += sk[j] * sk[j];
        snorm = fmaxf(sqrtf(s), 1e-12f);
    }
    __syncthreads();
    if (t < RD) kkn[(size_t)blk * RD + t] = sk[t] / snorm;
    // vvT[b][c][m] bf16, c padded to 192 (tail rows zero)
    for (int c = t; c < 192; c += 64) {
        float s = 0.f;
        if (c < CDIM) {
            s = wvb[c];
            for (int k = 0; k < CDIM; k++) s += tr[k] * wv[k * CDIM + c];
        }
        vvT[((size_t)(b * 192 + c)) * MDICT + m] = __float2bfloat16(s);
    }
    {
        float s = wtdb[t];
        for (int k = 0; k < CDIM; k++) s += tr[k] * wtd[k * DTD + t];
        tdp[(size_t)blk * DTD + t] = s;
    }
}

// ---------------- Stable counting sort of tk_id ----------------------------
__global__ __launch_bounds__(256) void sort_kernel(const int* __restrict__ tk_id,
                                                   int* __restrict__ sidx)
{
    int b = blockIdx.x; int tid = threadIdx.x;
    __shared__ int keys[NTOK];
    __shared__ int cnt[256];
    __shared__ int off[256];
    const int* kb = tk_id + (size_t)b * NTOK;
    for (int i = tid; i < NTOK; i += 256) keys[i] = kb[i];
    __syncthreads();
    int v = tid >> 2, seg = tid & 3;
    int lo = seg * 1024, hi = lo + 1024;
    int c = 0;
    for (int i = lo; i < hi; i++) c += (keys[i] == v);
    cnt[tid] = c;
    __syncthreads();
    if (tid == 0) {
        int run = 0;
        for (int l = 0; l < 256; l++) { off[l] = run; run += cnt[l]; }
    }
    __syncthreads();
    int o = off[tid];
    int* sb = sidx + (size_t)b * NTOK;
    for (int i = lo; i < hi; i++) if (keys[i] == v) sb[o++] = i;
}

// ---------------- Gather dictionary features into hc[:, 360:424] -----------
__global__ __launch_bounds__(256) void gather_td_kernel(const int* __restrict__ tk_id,
        const float* __restrict__ tdp, float* __restrict__ hc)
{
    int idx = blockIdx.x * 256 + threadIdx.x;
    int row = idx >> 6, j = idx & 63;
    int b = row >> 12;
    int tk = tk_id[row];
    hc[(size_t)row * CCAT + MHID + j] = tdp[((size_t)b * MDICT + tk) * DTD + j];
}

// ---------------- Depthwise 5x5 conv: CHK=64, 8x8 tile, bf16 KP2 out -------
// R15 VERBATIM (proven 4x: ~98.5us, VGPR 68, conflicts 0, writes ideal):
// write-ownership layout (block owns full 128B output lines) + b128 LDS
// reads. sh[144][68] pixel-major (272B rows, uniform 8/bank). 4 f32x4
// subgroups sequential; sched_barrier(0) per 5-tap row caps load hoisting.
#define CHK3 64
#define CTW  8
#define CTH  8
#define CHW  12     // halo width/height = tile + 4
#define CHP  144    // 12*12 halo pixels
#define CSPX 68     // floats per pixel row (64 + 4 pad) = 272B, 16B-aligned
__global__ __launch_bounds__(256) void conv_kernel(const float* __restrict__ hc,
        const float* __restrict__ w, const float* __restrict__ wb,
        bf16* __restrict__ outb)
{
    int ch0 = blockIdx.x * CHK3;        // 0,64,...,384 (7 blocks; 424..447 zeroed)
    int tile = blockIdx.y;              // 64 tiles of 8x8
    int b = blockIdx.z;
    int ty0 = (tile >> 3) * CTH, tx0 = (tile & 7) * CTW;
    __shared__ __align__(16) float sh[CHP][CSPX];   // 39168 B
    __shared__ __align__(16) float wt[25][CHK3];    // 6400 B
    int tid = threadIdx.x;
    // stage input: lanes cover 64 contiguous channels of one pixel (256B)
    for (int idx = tid; idx < CHP * CHK3; idx += 256) {
        int pix = idx >> 6, ch = idx & 63;
        int gy = ty0 + pix / CHW - 2, gx = tx0 + pix % CHW - 2;
        int chg = ch0 + ch;
        float v = 0.f;
        if (gy >= 0 && gy < 64 && gx >= 0 && gx < 64 && chg < CCAT)
            v = hc[((size_t)b * NTOK + gy * 64 + gx) * CCAT + chg];
        sh[pix][ch] = v;
    }
    for (int idx = tid; idx < 25 * CHK3; idx += 256) {
        int kk = idx >> 6, ch = idx & 63;
        int chg = ch0 + ch;
        wt[kk][ch] = (chg < CCAT) ? w[chg * 25 + kk] : 0.f;
    }
    __syncthreads();
    int q = tid & 3, p = tid >> 2;      // p: pixel 0..63; q: 16-ch subgroup
    int px = p & 7, py = p >> 3;
    int cb = q * 16;
    int pc = py * CHW + px;             // top-left of 5x5 window
    v8s pk0, pk1;
    #pragma unroll
    for (int sub = 0; sub < 4; sub++) {
        int cs = cb + sub * 4;
        f32x4 acc = {0.f, 0.f, 0.f, 0.f};
        #pragma unroll
        for (int dy = 0; dy < 5; dy++) {
            #pragma unroll
            for (int dx = 0; dx < 5; dx++) {
                f32x4 sv = *(const f32x4*)&sh[pc + dy * CHW + dx][cs];
                f32x4 wv = *(const f32x4*)&wt[dy * 5 + dx][cs];
                acc += sv * wv;
            }
            __builtin_amdgcn_sched_barrier(0);   // cap hoisting at one row
        }
        f32x4 ctr = *(const f32x4*)&sh[pc + 2 * CHW + 2][cs];
        #pragma unroll
        for (int c = 0; c < 4; c++) {
            int chg = ch0 + cs + c;
            float v = 0.f;
            if (chg < CCAT) {
                float gv = gelu_exact(acc[c] + wb[chg]);
                v = ctr[c] + gv;
            }
            int lc = sub * 4 + c;
            if (lc < 8) pk0[lc] = (short)f2b(v);
            else        pk1[lc - 8] = (short)f2b(v);
        }
        __builtin_amdgcn_sched_barrier(0);
    }
    size_t obase = ((size_t)b * NTOK + (ty0 + py) * 64 + tx0 + px) * KP2 + ch0 + cb;
    unsigned short* ob = (unsigned short*)outb + obase;   // 32B-aligned
    *(v8s*)ob = pk0;
    *(v8s*)(ob + 8) = pk1;
}

// ---------------------------------------------------------------------------
extern "C" void kernel_launch(void* const* d_in, const int* in_sizes, int n_in,
                              void* d_out, int out_size, void* d_ws, size_t ws_size,
                              hipStream_t stream)
{
    (void)n_in; (void)ws_size; (void)out_size;
    const int* rpi = (const int*)d_in[28];

    // ---- workspace carve-up ----
    float* p = (float*)d_ws;
    float* xn    = p; p += (size_t)ROWS * CDIM;    // (dead since R22; kept for layout)
    float* acc   = p; p += (size_t)ROWS * CDIM;
    float* tmp1  = p; p += (size_t)ROWS * CDIM;    // alias: P bf16 (head), fc2 out
    float* qkv   = p; p += (size_t)ROWS * C3;      // alias: qkvb bf16; hc fp32 post-win
    float* hcnew = p; p += (size_t)ROWS * CCAT;    // alias: xnb/tmp1b; then conv bf16 out
    float* kkn   = p; p += (size_t)BB * MDICT * RD;
    bf16*  vvT   = (bf16*)p; p += (size_t)BB * 192 * MDICT / 2;   // bf16 [8][192][64]
    float* tdp   = p; p += (size_t)BB * MDICT * DTD;
    int*   tk_id = (int*)p; p += ROWS;
    int*   sidx  = (int*)p; p += ROWS;
    int*   flag  = (int*)p; p += 64;
    int*   diag  = (int*)p; p += 64;
    bf16* wtqkv = (bf16*)p; p += 576 * KP1 / 2;
    bf16* wtaca = (bf16*)p; p += 192 * KP1 / 2;
    bf16* wtwin = (bf16*)p; p += 192 * KP1 / 2;
    bf16* wtfc1 = (bf16*)p; p += 384 * KP1 / 2;
    bf16* wtfc2 = (bf16*)p; p += 192 * KP2 / 2;
    float* cin[28];
    for (int i = 0; i < 28; i++) { cin[i] = p; p += in_sizes[i]; }
    float* bias_t = p; p += (size_t)NHEADS * WIN_N * WIN_N;   // 1.5 MB
    (void)xn;

    float* hc      = qkv;                // fp32 [ROWS,CCAT]; born after win (qkv dead)
    bf16*  qkvb    = (bf16*)qkv;         // bf16 [ROWS,576] padded; dies at win
    bf16*  xnb     = (bf16*)hcnew;                            // [ROWS,KP1]; dies at fc1
    bf16*  tmp1b   = (bf16*)(hcnew + (size_t)ROWS * KP1 / 2); // [ROWS,KP1]; dies at winp
    bf16*  hcnewb2 = (bf16*)hcnew;       // [ROWS,KP2] bf16; born at conv
    bf16*  Pbuf    = (bf16*)tmp1;        // [ROWS,64] bf16 = 4MB; dies after av_mgemm
                                         // (tmp1 fp32 reborn at fc2 much later)

    // ---- dtype detect (+diag=0) + batched input normalize to fp32 ----
    detect_kernel<<<1, 256, 0, stream>>>(d_in[0], flag, diag);
    {
        CvtArgs ca;
        int total = 0, s = 0;
        for (int i = 0; i < 28; i++) {
            if (i == 4 || i == 13 || i == 16 || i == 20 || i == 24) continue;
            ca.src[s] = d_in[i];
            ca.dst[s] = cin[i];
            ca.cum[s] = total;
            total += in_sizes[i];
            s++;
        }
        ca.cum[s] = total;
        convert_all_kernel<<<(total + 255) / 256, 256, 0, stream>>>(ca, total, flag);
    }
    const float *x = cin[0], *td = cin[1], *n1g = cin[2], *n1b = cin[3],
        *wqkv_b = cin[5], *wq_w = cin[6], *wq_b = cin[7],
        *wk_w = cin[8], *wk_b = cin[9], *wv_w = cin[10], *wv_b = cin[11],
        *atd_scale = cin[12], *aca_b = cin[14], *win_rpb = cin[15],
        *winp_b = cin[17], *fctd_w = cin[18], *fctd_b = cin[19],
        *fc1_b = cin[21], *dw_w = cin[22], *dw_b = cin[23], *fc2_b = cin[25],
        *n2g = cin[26], *n2b = cin[27];

    // ---- adaptive weight repacks (by value) + bias table ----
    packW_kernel<<<576 * KP1 / 256, 256, 0, stream>>>(d_in[4],  wtqkv, CDIM, C3,   KP1, 576 * KP1, flag);
    packW_kernel<<<192 * KP1 / 256, 256, 0, stream>>>(d_in[13], wtaca, CDIM, CDIM, KP1, 192 * KP1, flag);
    packW_kernel<<<192 * KP1 / 256, 256, 0, stream>>>(d_in[16], wtwin, CDIM, CDIM, KP1, 192 * KP1, flag);
    packW_kernel<<<384 * KP1 / 256, 256, 0, stream>>>(d_in[20], wtfc1, CDIM, MHID, KP1, 384 * KP1, flag);
    packW_kernel<<<192 * KP2 / 256, 256, 0, stream>>>(d_in[24], wtfc2, CCAT, CDIM, KP2, 192 * KP2, flag);
    bias_pre_kernel<<<NHEADS * WIN_N * WIN_N / 256, 256, 0, stream>>>(rpi, win_rpb, bias_t);

    td_pre_kernel<<<BB * MDICT, 64, 0, stream>>>(td, wk_w, wk_b, wv_w, wv_b,
                                                 fctd_w, fctd_b, kkn, vvT, tdp);
    // Fused LN1 + ATD: xnb bf16 + P + tk_id in one pass (xn fp32 eliminated)
    ln_atd_kernel<<<ROWS / 4, 256, 0, stream>>>(x, n1g, n1b, xnb,
                                                wq_w, wq_b, atd_scale, kkn, Pbuf, tk_id);
    // qkv gemm: bf16 padded output (Q pre-scaled)
    mgemm_kernel<false, false, true, 1><<<dim3(9, ROWS / 128), 256, 0, stream>>>(
        xnb, KP1, wtqkv, KP1, wqkv_b, nullptr, 0, (float*)qkvb, QKVP, C3, KP1, nullptr);
    // merged zeroing: tmp1b K-tail + qkvb pad slots
    zero_aux_kernel<<<ROWS * 48 / 256, 256, 0, stream>>>(tmp1b, qkvb);
    av_mgemm_kernel<<<dim3(3, NTOK / 64, BB), 256, 0, stream>>>(Pbuf, vvT, x, acc);
    sort_kernel<<<BB, 256, 0, stream>>>(tk_id, sidx);
    // MFMA flash AC_MSA -> tmp1b (bf16 direct)
    acmsa_mfma_kernel<<<dim3(NG * NHEADS, BB), 256, 0, stream>>>(qkvb, sidx, tmp1b);
    mgemm_kernel<false, true, true, 0><<<dim3(3, ROWS / 128), 256, 0, stream>>>(
        tmp1b, KP1, wtaca, KP1, aca_b, acc, CDIM, acc, CDIM, CDIM, KP1, nullptr);
    // MFMA flash window attention -> tmp1b (bf16 direct)
    win_mfma_kernel<<<dim3(16 * NHEADS, BB), 256, 0, stream>>>(qkvb, bias_t, tmp1b);
    mgemm_kernel<false, true, true, 0><<<dim3(3, ROWS / 128), 256, 0, stream>>>(
        tmp1b, KP1, wtwin, KP1, winp_b, acc, CDIM, acc, CDIM, CDIM, KP1, nullptr);
    // FFN: LN2 (bf16 out only) -> fc1 -> gather -> conv -> fc2 (+NaN check)
    ln_kernel<<<ROWS / 4, 256, 0, stream>>>(acc, n2g, n2b, xnb);
    mgemm_kernel<true, false, true, 0><<<dim3(6, ROWS / 128), 256, 0, stream>>>(
        xnb, KP1, wtfc1, KP1, fc1_b, nullptr, 0, hc, CCAT, MHID, KP1, nullptr);
    gather_td_kernel<<<ROWS * 64 / 256, 256, 0, stream>>>(tk_id, tdp, hc);
    conv_kernel<<<dim3(7, 64, BB), 256, 0, stream>>>(hc, dw_w, dw_b, hcnewb2);
    mgemm_kernel<false, true, true, 2><<<dim3(3, ROWS / 128), 256, 0, stream>>>(
        hcnewb2, KP2, wtfc2, KP2, fc2_b, acc, CDIM, tmp1, CDIM, CDIM, KP2, diag);
    emit_kernel<<<(ROWS * CDIM + 255) / 256, 256, 0, stream>>>(
        tmp1, d_out, flag, diag, ROWS * CDIM);
}

// Round 13
// 666.943 us; speedup vs baseline: 1.1298x; 1.0348x over previous
//
#include <hip/hip_runtime.h>
#include <hip/hip_bf16.h>
#include <math.h>

// MPv2_3d_arch: B=8, n=64*64=4096, c=180, heads=6 (hd=30), dict M=64, rd=10,
// dtd=64, mlp_hid=360, cat C=424, window 16x16, groups of 128.
// R24 == R23 resubmit (R23 bench hit "container failed twice" = infra, not
// kernel; full re-audit found no OOB/capture violations).
// R23: R22 (passing, 690us) + traffic/launch consolidation round 2:
// (a) aca+winp gemms merged into one dual-A K=384 gemm (acmsa->tmp2b in the
//     dead xn region; combined wtcomb[192][384]; bias summed): -47MB acc
//     pass, -1 launch. Reassociation-equal fp32.
// (b) x (d_in[0]) read dtype-flex inline in ln_atd + av_mgemm; x removed
//     from convert_all: -47MB. Bit-identical.
// (c) zero_aux also zeroes tmp2b K-tail. Conv = R15 verbatim (proven 5x).
// SESSION RULE: input dtype VARIES per run (bf16 or fp32) — every d_in
// access must go through *flag (by value). Raw-bit reads = NaN.
#define BB      8
#define NTOK    4096
#define CDIM    180
#define C3      540
#define NHEADS  6
#define HD      30
#define MDICT   64
#define RD      10
#define DTD     64
#define MHID    360
#define CCAT    424
#define WS      16
#define WIN_N   256
#define GS      128
#define NG      32
#define ROWS    (BB*NTOK)   // 32768
#define KP1     192         // Kpad for K=180
#define KP2     448         // Kpad for K=424
#define QKVP    576         // padded qkv row: 3 sec * 6 heads * 32

typedef __hip_bfloat16 bf16;
typedef short v8s __attribute__((ext_vector_type(8)));
typedef float f32x4 __attribute__((ext_vector_type(4)));
typedef unsigned int u32x4 __attribute__((ext_vector_type(4)));

__device__ __forceinline__ float gelu_exact(float x) {
    return 0.5f * x * (1.0f + erff(x * 0.70710678118654752f));
}
__device__ __forceinline__ float wave_sum(float v) {
    #pragma unroll
    for (int off = 32; off > 0; off >>= 1) v += __shfl_xor(v, off, 64);
    return v;
}
// fp32 <-> bf16 bits without type-punning (RNE)
__device__ __forceinline__ unsigned short f2b(float v) {
    unsigned u = __float_as_uint(v);
    return (unsigned short)((u + 0x7FFFu + ((u >> 16) & 1u)) >> 16);
}
__device__ __forceinline__ float b2f(unsigned short h) {
    return __uint_as_float(((unsigned)h) << 16);
}
__device__ __forceinline__ unsigned packbf(float lo, float hi) {
    return (unsigned)f2b(lo) | ((unsigned)f2b(hi) << 16);
}
// async global->LDS 16B (gfx950); size must be literal; lds addr = per-lane
// slot in lane-order-contiguous slab (wave-uniform base + lane*16).
__device__ __forceinline__ void gload16(const void* g, void* l) {
    __builtin_amdgcn_global_load_lds(
        (const __attribute__((address_space(1))) void*)g,
        (__attribute__((address_space(3))) void*)l, 16, 0, 0);
}

// ---------------- dtype detector: flag=1 if inputs are fp32, 0 if bf16 -----
__global__ __launch_bounds__(256) void detect_kernel(const void* __restrict__ x,
                                                     int* __restrict__ flag,
                                                     int* __restrict__ diag)
{
    __shared__ int cnt;
    if (threadIdx.x == 0) { cnt = 0; *diag = 0; }
    __syncthreads();
    const unsigned short* u = (const unsigned short*)x;
    int c = 0;
    for (int i = threadIdx.x; i < 2048; i += 256) {
        unsigned short e = u[2 * i] & 0x7F80;
        if (e >= 0x4300) c++;
    }
    atomicAdd(&cnt, c);
    __syncthreads();
    if (threadIdx.x == 0) *flag = (cnt > 16) ? 1 : 0;
}

// ---------------- batched dtype-flexible input -> fp32 conversion ----------
#define NCVT 23
struct CvtArgs {
    const void* src[NCVT];
    float* dst[NCVT];
    int cum[NCVT + 1];
};
__global__ __launch_bounds__(256) void convert_all_kernel(CvtArgs a, int total,
        const int* __restrict__ flag)
{
    int i = blockIdx.x * 256 + threadIdx.x;
    if (i >= total) return;
    int s = 0;
    while (i >= a.cum[s + 1]) s++;
    int off = i - a.cum[s];
    if (*flag) a.dst[s][off] = ((const float*)a.src[s])[off];
    else       a.dst[s][off] = __bfloat162float(((const bf16*)a.src[s])[off]);
}

// ---------------- output emit: fp32 src -> d_out in detected dtype ---------
__global__ __launch_bounds__(256) void emit_kernel(const float* __restrict__ src,
        void* __restrict__ out, const int* __restrict__ flag,
        const int* __restrict__ diag, int n)
{
    int i = blockIdx.x * 256 + threadIdx.x;
    if (i >= n) return;
    float v = src[i];
    int d = *diag;
    if (d) v = 100.f + 32.f * (float)d;   // NaN stage code -> absmax bin
    if (*flag) ((float*)out)[i] = v;
    else       ((bf16*)out)[i]  = __float2bfloat16(v);
}

// ---------------- merged zeroing: tmp1b/tmp2b tails + qkvb pad slots -------
__global__ __launch_bounds__(256) void zero_aux_kernel(bf16* __restrict__ t1,
        bf16* __restrict__ t2, bf16* __restrict__ qb)
{
    int idx = blockIdx.x * 256 + threadIdx.x;   // ROWS*60
    if (idx < ROWS * 12) {
        int row = idx / 12, c = idx % 12;
        t1[(size_t)row * KP1 + CDIM + c] = __float2bfloat16(0.f);
    } else if (idx < ROWS * 24) {
        int j = idx - ROWS * 12;
        int row = j / 12, c = j % 12;
        t2[(size_t)row * KP1 + CDIM + c] = __float2bfloat16(0.f);
    } else {
        int j = idx - ROWS * 24;
        int row = j / 36, r = j % 36;
        int sec = r / 12, rr = r % 12, hh = rr >> 1, d = 30 + (rr & 1);
        qb[(size_t)row * QKVP + sec * 192 + hh * 32 + d] = __float2bfloat16(0.f);
    }
}

// -------- adaptive weight repack: W[K,N] -> Wt[n*ldw + koff + k] bf16 ------
__global__ __launch_bounds__(256) void packW_kernel(const void* __restrict__ W,
        bf16* __restrict__ Wt, int K, int N, int Kpad, int ldw, int koff,
        int total, const int* __restrict__ flag)
{
    int idx = blockIdx.x * 256 + threadIdx.x;
    if (idx >= total) return;
    int n = idx / Kpad, k = idx % Kpad;
    float v = 0.f;
    if (k < K && n < N) {
        size_t src = (size_t)k * N + n;
        v = (*flag) ? ((const float*)W)[src]
                    : __bfloat162float(((const bf16*)W)[src]);
    }
    Wt[(size_t)n * ldw + koff + k] = __float2bfloat16(v);
}

// ---------------- window-attention bias table: [6][256][256] ---------------
__global__ __launch_bounds__(256) void bias_pre_kernel(const int* __restrict__ rpi,
        const float* __restrict__ rpb, float* __restrict__ bias_t)
{
    int idx = blockIdx.x * 256 + threadIdx.x;   // 6*65536
    int h = idx >> 16, ij = idx & 65535;
    bias_t[idx] = rpb[rpi[ij] * NHEADS + h];
}

// ---------------- MFMA GEMM: out = act(A@W [+bias]) [+ res] ----------------
// R18 structure: 128(M)x64(N) tile, 256 threads, global_load_lds staging,
// 8 MFMA/k-step/wave. OM=1: bf16 out to padded qkv layout (Q pre-scaled).
// OM=2: fp32 out + res + fused NaN check into diag. OM=3: dual-A (k<KP1
// from A, k>=KP1 from A2; ldw spans both halves; bias = bias+bias2).
template<bool GELU_, bool ADDRES, bool BIAS_, int OM>
__global__ __launch_bounds__(256) void mgemm_kernel(
        const bf16* __restrict__ A, int lda,
        const bf16* __restrict__ Wt, int ldw,
        const float* __restrict__ bias,
        const float* __restrict__ res, int ldr,
        float* __restrict__ outF, int ldo, int N, int K,
        int* __restrict__ diag,
        const bf16* __restrict__ A2, const float* __restrict__ bias2)
{
    __shared__ __align__(16) unsigned short As[128][32];   // 8 KB
    __shared__ __align__(16) unsigned short Bs[64][32];    // 4 KB
    int tid = threadIdx.x;
    int wave = tid >> 6, lane = tid & 63;
    int quad = lane >> 4, mr = lane & 15;
    int row0 = blockIdx.y * 128, col0 = blockIdx.x * 64;
    int ar = tid >> 2, ac = (tid & 3) * 8;   // LDS slot byte off = tid*16
    f32x4 z = {0.f, 0.f, 0.f, 0.f};
    f32x4 acc[2][4] = {{z, z, z, z}, {z, z, z, z}};
    const unsigned short* Au = (const unsigned short*)A;
    const unsigned short* A2u = (const unsigned short*)A2;
    const unsigned short* Wu = (const unsigned short*)Wt;
    for (int k0 = 0; k0 < K; k0 += 32) {
        const unsigned short* Asel = Au;
        int kk = k0;
        if (OM == 3 && k0 >= KP1) { Asel = A2u; kk = k0 - KP1; }
        gload16(&Asel[(size_t)(row0 + ar) * lda + kk + ac],      &As[ar][ac]);
        gload16(&Asel[(size_t)(row0 + 64 + ar) * lda + kk + ac], &As[64 + ar][ac]);
        gload16(&Wu[(size_t)(col0 + ar) * ldw + k0 + ac],        &Bs[ar][ac]);
        __syncthreads();   // compiler emits vmcnt(0) drain before barrier
        v8s bfr[4];
        #pragma unroll
        for (int ni = 0; ni < 4; ni++)
            bfr[ni] = *(const v8s*)&Bs[ni * 16 + mr][quad * 8];
        #pragma unroll
        for (int s = 0; s < 2; s++) {
            v8s a = *(const v8s*)&As[wave * 32 + s * 16 + mr][quad * 8];
            #pragma unroll
            for (int ni = 0; ni < 4; ni++)
                acc[s][ni] = __builtin_amdgcn_mfma_f32_16x16x32_bf16(
                    a, bfr[ni], acc[s][ni], 0, 0, 0);
        }
        __syncthreads();
    }
    if (OM == 1) {
        bf16* outb = (bf16*)outF;
        #pragma unroll
        for (int ni = 0; ni < 4; ni++) {
            int gc = col0 + ni * 16 + mr;
            if (gc >= N) continue;
            float bv = bias[gc];
            int sec = gc / 180, rem = gc - sec * 180;
            int hh = rem / 30, d = rem - hh * 30;
            int slot = sec * 192 + hh * 32 + d;
            float sc = (sec == 0) ? 0.18257418583505536f : 1.f;
            #pragma unroll
            for (int s = 0; s < 2; s++) {
                #pragma unroll
                for (int r = 0; r < 4; r++) {
                    int gr = row0 + wave * 32 + s * 16 + quad * 4 + r;
                    outb[(size_t)gr * QKVP + slot] =
                        __float2bfloat16((acc[s][ni][r] + bv) * sc);
                }
            }
        }
        return;
    }
    #pragma unroll
    for (int ni = 0; ni < 4; ni++) {
        int gc = col0 + ni * 16 + mr;
        if (gc >= N) continue;
        float bv = BIAS_ ? bias[gc] : 0.f;
        if (OM == 3) bv += bias2[gc];
        #pragma unroll
        for (int s = 0; s < 2; s++) {
            #pragma unroll
            for (int r = 0; r < 4; r++) {
                int gr = row0 + wave * 32 + s * 16 + quad * 4 + r;
                float v = acc[s][ni][r] + bv;
                if (GELU_) v = gelu_exact(v);
                if (ADDRES) v += res[(size_t)gr * ldr + gc];
                if (OM == 2) {
                    unsigned u = __float_as_uint(v);
                    if ((u & 0x7F800000u) == 0x7F800000u) atomicOr(diag, 8);
                }
                outF[(size_t)gr * ldo + gc] = v;
            }
        }
    }
}

// ---------------- batched AV GEMM: acc[b] = P[b]@vvT[b] + x[b] -------------
// grid (3, 64, 8). P bf16 [b][4096][64]; vvT bf16 [b][192][64]; K=64.
// R23: residual x read dtype-flex from raw d_in[0] via flag (bit-identical).
__global__ __launch_bounds__(256) void av_mgemm_kernel(
        const bf16* __restrict__ P, const bf16* __restrict__ vvT,
        const void* __restrict__ xraw, const int* __restrict__ flag,
        float* __restrict__ accout)
{
    __shared__ unsigned short As[64][32];
    __shared__ unsigned short Bs[64][32];
    int tid = threadIdx.x;
    int wave = tid >> 6, lane = tid & 63;
    int quad = lane >> 4, mr = lane & 15;
    int row0 = blockIdx.y * 64, col0 = blockIdx.x * 64;
    int bz = blockIdx.z;
    int isf = *flag;
    const unsigned short* Au = (const unsigned short*)P + (size_t)bz * NTOK * MDICT;
    const unsigned short* Wu = (const unsigned short*)vvT + (size_t)bz * 192 * MDICT;
    size_t rbase = (size_t)bz * NTOK * CDIM;
    const float* resf = (const float*)xraw + rbase;
    const bf16*  resb = (const bf16*)xraw + rbase;
    float* outF = accout + rbase;
    f32x4 z = {0.f, 0.f, 0.f, 0.f};
    f32x4 acc[4] = {z, z, z, z};
    for (int k0 = 0; k0 < MDICT; k0 += 32) {
        #pragma unroll
        for (int e = 0; e < 8; e++) {
            int idx = tid * 8 + e;
            int r = idx >> 5, c = idx & 31;
            As[r][c] = Au[(size_t)(row0 + r) * MDICT + k0 + c];
            Bs[r][c] = Wu[(size_t)(col0 + r) * MDICT + k0 + c];
        }
        __syncthreads();
        v8s a;
        #pragma unroll
        for (int j = 0; j < 8; j++) a[j] = (short)As[wave * 16 + mr][quad * 8 + j];
        #pragma unroll
        for (int ni = 0; ni < 4; ni++) {
            v8s b;
            #pragma unroll
            for (int j = 0; j < 8; j++) b[j] = (short)Bs[ni * 16 + mr][quad * 8 + j];
            acc[ni] = __builtin_amdgcn_mfma_f32_16x16x32_bf16(a, b, acc[ni], 0, 0, 0);
        }
        __syncthreads();
    }
    #pragma unroll
    for (int ni = 0; ni < 4; ni++) {
        int gc = col0 + ni * 16 + mr;
        if (gc >= CDIM) continue;
        #pragma unroll
        for (int r = 0; r < 4; r++) {
            int gr = row0 + wave * 16 + quad * 4 + r;
            size_t off = (size_t)gr * CDIM + gc;
            float rv = isf ? resf[off] : __bfloat162float(resb[off]);
            outF[off] = acc[ni][r] + rv;
        }
    }
}

// ---------------- Window attention, MFMA flash (bf16 KP1 out) --------------
// R12 structure + R19 bf16-qkv input: Q/K/V loaded as aligned v8s from the
// padded [ROWS][576] layout (Q pre-scaled, pads zero) — no f2b at load.
__global__ __launch_bounds__(256, 4) void win_mfma_kernel(const bf16* __restrict__ qkvb,
        const float* __restrict__ bias_t, bf16* __restrict__ outb)
{
    int b = blockIdx.y;
    int widx = blockIdx.x / NHEADS;
    int hh = blockIdx.x % NHEADS;
    int wy = widx >> 2, wx = widx & 3;
    int tid = threadIdx.x;
    int wave = tid >> 6, lane = tid & 63, quad = lane >> 4, mr = lane & 15;
    __shared__ __align__(16) unsigned short Ks[64][40];
    __shared__ __align__(16) unsigned short Vt[32][80];

    size_t brow = (size_t)b * NTOK;
    const unsigned short* qu = (const unsigned short*)qkvb;

    v8s aq[4];
    #pragma unroll
    for (int tt = 0; tt < 4; tt++) {
        int m = (wave * 4 + tt) * 16 + mr;
        int nt_ = (wy * WS + (m >> 4)) * 64 + wx * WS + (m & 15);
        aq[tt] = *(const v8s*)&qu[(brow + nt_) * QKVP + hh * 32 + quad * 8];
    }
    f32x4 z = {0.f, 0.f, 0.f, 0.f};
    f32x4 oacc[4][2] = {{z, z}, {z, z}, {z, z}, {z, z}};
    float m_r[4], l_r[4];
    #pragma unroll
    for (int tt = 0; tt < 4; tt++) { m_r[tt] = -3.0e38f; l_r[tt] = 0.f; }
    const float* btab = bias_t + (size_t)hh * WIN_N * WIN_N;

    for (int kc = 0; kc < WIN_N; kc += 64) {
        {
            int j = tid >> 2, dg = (tid & 3) * 8;
            int tok = kc + j;
            int nt_ = (wy * WS + (tok >> 4)) * 64 + wx * WS + (tok & 15);
            const unsigned short* base = qu + (brow + nt_) * QKVP + hh * 32;
            v8s kv = *(const v8s*)&base[192 + dg];
            v8s vv = *(const v8s*)&base[384 + dg];
            *(v8s*)&Ks[j][dg] = kv;
            #pragma unroll
            for (int jj = 0; jj < 8; jj++)
                Vt[dg + jj][j] = (unsigned short)vv[jj];
        }
        __syncthreads();
        #pragma unroll
        for (int tt = 0; tt < 4; tt++) {
            // --- QK^T swapped: s[nt][r] = S[key=kc+nt*16+quad*4+r][query] ---
            f32x4 s[4];
            #pragma unroll
            for (int nt = 0; nt < 4; nt++) {
                v8s bk = *(const v8s*)&Ks[nt * 16 + mr][quad * 8];
                s[nt] = __builtin_amdgcn_mfma_f32_16x16x32_bf16(bk, aq[tt], z, 0, 0, 0);
            }
            int qg = (wave * 4 + tt) * 16 + mr;
            const float* bi = btab + (size_t)qg * WIN_N + kc;
            float mc = -3.0e38f;
            #pragma unroll
            for (int nt = 0; nt < 4; nt++) {
                f32x4 b4 = *(const f32x4*)(bi + nt * 16 + quad * 4);
                s[nt][0] += b4[0]; s[nt][1] += b4[1];
                s[nt][2] += b4[2]; s[nt][3] += b4[3];
                mc = fmaxf(mc, fmaxf(fmaxf(s[nt][0], s[nt][1]),
                                     fmaxf(s[nt][2], s[nt][3])));
            }
            mc = fmaxf(mc, __shfl_xor(mc, 16, 64));
            mc = fmaxf(mc, __shfl_xor(mc, 32, 64));
            float mn = fmaxf(m_r[tt], mc);
            float alpha = __expf(m_r[tt] - mn);
            m_r[tt] = mn;
            float ls = 0.f;
            #pragma unroll
            for (int nt = 0; nt < 4; nt++) {
                #pragma unroll
                for (int r = 0; r < 4; r++) {
                    float pp = __expf(s[nt][r] - mn);
                    ls += pp;
                    s[nt][r] = pp;
                }
            }
            ls += __shfl_xor(ls, 16, 64);
            ls += __shfl_xor(ls, 32, 64);
            l_r[tt] = l_r[tt] * alpha + ls;
            // --- pack P (bf16 pairs): dpk[nt][s] = keys nt*16+quad*4+{2s,2s+1}
            unsigned dpk[4][2];
            #pragma unroll
            for (int nt = 0; nt < 4; nt++) {
                dpk[nt][0] = packbf(s[nt][0], s[nt][1]);
                dpk[nt][1] = packbf(s[nt][2], s[nt][3]);
            }
            // --- rescale oacc rows (query = quad*4+r) by alpha ---
            #pragma unroll
            for (int r = 0; r < 4; r++) {
                float av = __shfl(alpha, quad * 4 + r, 64);
                oacc[tt][0][r] *= av;
                oacc[tt][1][r] *= av;
            }
            // --- PV: build A-frags via cross-lane shuffle, 2 chunks of K=32 --
            #pragma unroll
            for (int c = 0; c < 2; c++) {
                union { u32x4 u; v8s s8; } afu;
                #pragma unroll
                for (int t = 0; t < 4; t++) {
                    int srcl = (((quad * 2 + (t >> 1)) & 3) << 4) | mr;
                    unsigned r0 = (unsigned)__shfl((int)dpk[2 * c][t & 1], srcl, 64);
                    unsigned r1 = (unsigned)__shfl((int)dpk[2 * c + 1][t & 1], srcl, 64);
                    afu.u[t] = (quad & 2) ? r1 : r0;
                }
                #pragma unroll
                for (int dt = 0; dt < 2; dt++) {
                    v8s bv = *(const v8s*)&Vt[dt * 16 + mr][c * 32 + quad * 8];
                    oacc[tt][dt] = __builtin_amdgcn_mfma_f32_16x16x32_bf16(
                        afu.s8, bv, oacc[tt][dt], 0, 0, 0);
                }
            }
        }
        __syncthreads();
    }
    #pragma unroll
    for (int tt = 0; tt < 4; tt++) {
        float il = 1.f / l_r[tt];
        #pragma unroll
        for (int r = 0; r < 4; r++) {
            float ilr = __shfl(il, quad * 4 + r, 64);
            int m = (wave * 4 + tt) * 16 + quad * 4 + r;
            int nt_ = (wy * WS + (m >> 4)) * 64 + wx * WS + (m & 15);
            #pragma unroll
            for (int dt = 0; dt < 2; dt++) {
                int d = dt * 16 + mr;
                if (d >= HD) continue;
                outb[(brow + nt_) * KP1 + hh * HD + d] =
                    __float2bfloat16(oacc[tt][dt][r] * ilr);
            }
        }
    }
}

// ---------------- AC_MSA, MFMA flash, swapped QK^T -------------------------
// R17 structure + R19 bf16-qkv input (v8s loads, toks[] indirection).
__global__ __launch_bounds__(256, 4) void acmsa_mfma_kernel(const bf16* __restrict__ qkvb,
        const int* __restrict__ sidx, bf16* __restrict__ outb)
{
    int b = blockIdx.y;
    int g = blockIdx.x / NHEADS;
    int hh = blockIdx.x % NHEADS;
    int tid = threadIdx.x;
    int wave = tid >> 6, lane = tid & 63, quad = lane >> 4, mr = lane & 15;
    __shared__ int toks[GS];
    __shared__ __align__(16) unsigned short Ks[64][40];
    __shared__ __align__(16) unsigned short Vt[32][80];

    size_t brow = (size_t)b * NTOK;
    if (tid < GS) toks[tid] = sidx[brow + (size_t)g * GS + tid];
    __syncthreads();
    const unsigned short* qu = (const unsigned short*)qkvb;

    v8s aq[2];
    #pragma unroll
    for (int tt = 0; tt < 2; tt++) {
        int m = (wave * 2 + tt) * 16 + mr;
        aq[tt] = *(const v8s*)&qu[(brow + toks[m]) * QKVP + hh * 32 + quad * 8];
    }
    f32x4 z = {0.f, 0.f, 0.f, 0.f};
    f32x4 oacc[2][2] = {{z, z}, {z, z}};
    float m_r[2], l_r[2];
    #pragma unroll
    for (int tt = 0; tt < 2; tt++) { m_r[tt] = -3.0e38f; l_r[tt] = 0.f; }

    for (int kc = 0; kc < GS; kc += 64) {
        {
            int j = tid >> 2, dg = (tid & 3) * 8;
            int tok = toks[kc + j];
            const unsigned short* base = qu + (brow + tok) * QKVP + hh * 32;
            v8s kv = *(const v8s*)&base[192 + dg];
            v8s vv = *(const v8s*)&base[384 + dg];
            *(v8s*)&Ks[j][dg] = kv;
            #pragma unroll
            for (int jj = 0; jj < 8; jj++)
                Vt[dg + jj][j] = (unsigned short)vv[jj];
        }
        __syncthreads();
        #pragma unroll
        for (int tt = 0; tt < 2; tt++) {
            // --- QK^T swapped: s[nt][r] = S[key=kc+nt*16+quad*4+r][query=mr]
            f32x4 s[4];
            #pragma unroll
            for (int nt = 0; nt < 4; nt++) {
                v8s bk = *(const v8s*)&Ks[nt * 16 + mr][quad * 8];
                s[nt] = __builtin_amdgcn_mfma_f32_16x16x32_bf16(bk, aq[tt], z, 0, 0, 0);
            }
            float mc = -3.0e38f;
            #pragma unroll
            for (int nt = 0; nt < 4; nt++)
                mc = fmaxf(mc, fmaxf(fmaxf(s[nt][0], s[nt][1]),
                                     fmaxf(s[nt][2], s[nt][3])));
            mc = fmaxf(mc, __shfl_xor(mc, 16, 64));
            mc = fmaxf(mc, __shfl_xor(mc, 32, 64));
            float mn = fmaxf(m_r[tt], mc);
            float alpha = __expf(m_r[tt] - mn);
            m_r[tt] = mn;
            float ls = 0.f;
            #pragma unroll
            for (int nt = 0; nt < 4; nt++) {
                #pragma unroll
                for (int r = 0; r < 4; r++) {
                    float pp = __expf(s[nt][r] - mn);
                    ls += pp;
                    s[nt][r] = pp;
                }
            }
            ls += __shfl_xor(ls, 16, 64);
            ls += __shfl_xor(ls, 32, 64);
            l_r[tt] = l_r[tt] * alpha + ls;
            unsigned dpk[4][2];
            #pragma unroll
            for (int nt = 0; nt < 4; nt++) {
                dpk[nt][0] = packbf(s[nt][0], s[nt][1]);
                dpk[nt][1] = packbf(s[nt][2], s[nt][3]);
            }
            #pragma unroll
            for (int r = 0; r < 4; r++) {
                float av = __shfl(alpha, quad * 4 + r, 64);
                oacc[tt][0][r] *= av;
                oacc[tt][1][r] *= av;
            }
            #pragma unroll
            for (int c = 0; c < 2; c++) {
                union { u32x4 u; v8s s8; } afu;
                #pragma unroll
                for (int t = 0; t < 4; t++) {
                    int srcl = (((quad * 2 + (t >> 1)) & 3) << 4) | mr;
                    unsigned r0 = (unsigned)__shfl((int)dpk[2 * c][t & 1], srcl, 64);
                    unsigned r1 = (unsigned)__shfl((int)dpk[2 * c + 1][t & 1], srcl, 64);
                    afu.u[t] = (quad & 2) ? r1 : r0;
                }
                #pragma unroll
                for (int dt = 0; dt < 2; dt++) {
                    v8s bv = *(const v8s*)&Vt[dt * 16 + mr][c * 32 + quad * 8];
                    oacc[tt][dt] = __builtin_amdgcn_mfma_f32_16x16x32_bf16(
                        afu.s8, bv, oacc[tt][dt], 0, 0, 0);
                }
            }
        }
        __syncthreads();
    }
    #pragma unroll
    for (int tt = 0; tt < 2; tt++) {
        float il = 1.f / l_r[tt];
        #pragma unroll
        for (int r = 0; r < 4; r++) {
            float ilr = __shfl(il, quad * 4 + r, 64);
            int m = (wave * 2 + tt) * 16 + quad * 4 + r;
            int tok = toks[m];
            #pragma unroll
            for (int dt = 0; dt < 2; dt++) {
                int d = dt * 16 + mr;
                if (d >= HD) continue;
                outb[(brow + tok) * KP1 + hh * HD + d] =
                    __float2bfloat16(oacc[tt][dt][r] * ilr);
            }
        }
    }
}

// ---------------- Fused LN1 + ATD softmax/argmax (4 rows/block) ------------
// R23: x read dtype-flex from raw d_in[0] (same conversion as convert_all;
// bit-identical). atd consumes exactly ln1's fp32 registers.
__global__ __launch_bounds__(256) void ln_atd_kernel(const void* __restrict__ xraw,
        const int* __restrict__ flag,
        const float* __restrict__ g, const float* __restrict__ be,
        bf16* __restrict__ outb,
        const float* __restrict__ wq, const float* __restrict__ wqb,
        const float* __restrict__ scale_p, const float* __restrict__ kkn,
        bf16* __restrict__ Pout, int* __restrict__ tk_id)
{
    int row = blockIdx.x * 4 + (threadIdx.x >> 6);
    int b = row >> 12;
    int t = threadIdx.x & 63;
    int isf = *flag;
    size_t rb = (size_t)row * CDIM;
    const float* xf = (const float*)xraw + rb;
    const bf16*  xb = (const bf16*)xraw + rb;
    float v0 = isf ? xf[t]       : __bfloat162float(xb[t]);
    float v1 = isf ? xf[t + 64]  : __bfloat162float(xb[t + 64]);
    float v2 = (t < CDIM - 128)
             ? (isf ? xf[t + 128] : __bfloat162float(xb[t + 128])) : 0.f;
    float s1 = wave_sum(v0 + v1 + v2);
    float s2 = wave_sum(v0*v0 + v1*v1 + v2*v2);
    float mu = s1 / (float)CDIM;
    float var = s2 / (float)CDIM - mu * mu;
    float rs = rsqrtf(var + 1e-5f);
    float o0 = (v0 - mu) * rs * g[t]      + be[t];
    float o1 = (v1 - mu) * rs * g[t + 64] + be[t + 64];
    float o2 = (t < CDIM - 128) ? ((v2 - mu) * rs * g[t + 128] + be[t + 128]) : 0.f;
    bf16* ob = outb + (size_t)row * KP1;
    ob[t]       = __float2bfloat16(o0);
    ob[t + 64]  = __float2bfloat16(o1);
    ob[t + 128] = __float2bfloat16(o2);   // cols 180..191 get 0 (t>=52 -> o2=0)
    // ---- ATD on the same fp32 values (o0..o2 == xn row) ----
    float sq[RD];
    #pragma unroll
    for (int j = 0; j < RD; j++) {
        float part = o0 * wq[t * RD + j] + o1 * wq[(t + 64) * RD + j];
        if (t < CDIM - 128) part += o2 * wq[(t + 128) * RD + j];
        sq[j] = wave_sum(part) + wqb[j];
    }
    float qn = 0.f;
    #pragma unroll
    for (int j = 0; j < RD; j++) qn += sq[j] * sq[j];
    qn = fmaxf(sqrtf(qn), 1e-12f);
    float ls = 1.0f + fminf(fmaxf(scale_p[0], 0.f), 3.f) * 4.158883083359672f;
    const float* kr = kkn + ((size_t)b * MDICT + t) * RD;
    float s = 0.f;
    #pragma unroll
    for (int j = 0; j < RD; j++) s += sq[j] * kr[j];
    s = s / qn * ls;
    float mv = s; int mi = t;
    #pragma unroll
    for (int off = 32; off > 0; off >>= 1) {
        float ov = __shfl_xor(mv, off, 64);
        int   oi = __shfl_xor(mi, off, 64);
        if (ov > mv || (ov == mv && oi < mi)) { mv = ov; mi = oi; }
    }
    float e = __expf(s - mv);
    float denom = wave_sum(e);
    Pout[(size_t)row * MDICT + t] = __float2bfloat16(e / denom);
    if (t == 0) tk_id[row] = mi;
}

// ---------------- LayerNorm (bf16 KP1 out only) ----------------------------
__global__ __launch_bounds__(256) void ln_kernel(const float* __restrict__ x,
        const float* __restrict__ g, const float* __restrict__ be,
        bf16* __restrict__ outb)
{
    int row = blockIdx.x * 4 + (threadIdx.x >> 6);
    int t = threadIdx.x & 63;
    const float* xr = x + (size_t)row * CDIM;
    float v0 = xr[t];
    float v1 = xr[t + 64];
    float v2 = (t < CDIM - 128) ? xr[t + 128] : 0.f;
    float s1 = wave_sum(v0 + v1 + v2);
    float s2 = wave_sum(v0*v0 + v1*v1 + v2*v2);
    float mu = s1 / (float)CDIM;
    float var = s2 / (float)CDIM - mu * mu;
    float rs = rsqrtf(var + 1e-5f);
    float o0 = (v0 - mu) * rs * g[t]      + be[t];
    float o1 = (v1 - mu) * rs * g[t + 64] + be[t + 64];
    float o2 = (t < CDIM - 128) ? ((v2 - mu) * rs * g[t + 128] + be[t + 128]) : 0.f;
    bf16* ob = outb + (size_t)row * KP1;
    ob[t]       = __float2bfloat16(o0);
    ob[t + 64]  = __float2bfloat16(o1);
    ob[t + 128] = __float2bfloat16(o2);   // cols 180..191 get 0 (t>=52 -> o2=0)
}

// ---------------- Dictionary precompute: kkn (l2), vvT bf16, td_proj -------
__global__ __launch_bounds__(64) void td_pre_kernel(const float* __restrict__ td,
        const float* __restrict__ wk, const float* __restrict__ wkb,
        const float* __restrict__ wv, const float* __restrict__ wvb,
        const float* __restrict__ wtd, const float* __restrict__ wtdb,
        float* __restrict__ kkn, bf16* __restrict__ vvT, float* __restrict__ tdp)
{
    int blk = blockIdx.x;   // b*64 + m
    int b = blk >> 6, m = blk & 63;
    int t = threadIdx.x;
    __shared__ float tr[CDIM];
    __shared__ float sk[RD];
    __shared__ float snorm;
    const float* tdr = td + (size_t)blk * CDIM;
    tr[t] = tdr[t]; tr[t + 64] = tdr[t + 64];
    if (t < CDIM - 128) tr[t + 128] = tdr[t + 128];
    __syncthreads();
    if (t < RD) {
        float s = wkb[t];
        for (int k = 0; k < CDIM; k++) s += tr[k] * wk[k * RD + t];
        sk[t] = s;
    }
    __syncthreads();
    if (t == 0) {
        float s = 0.f;
        #pragma unroll
        for (int j = 0; j < RD; j++) s += sk[j] * sk[j];
        snorm = fmaxf(sqrtf(s), 1e-12f);
    }
    __syncthreads();
    if (t < RD) kkn[(size_t)blk * RD + t] = sk[t] / snorm;
    // vvT[b][c][m] bf16, c padded to 192 (tail rows zero)
    for (int c = t; c < 192; c += 64) {
        float s = 0.f;
        if (c < CDIM) {
            s = wvb[c];
            for (int k = 0; k < CDIM; k++) s += tr[k] * wv[k * CDIM + c];
        }
        vvT[((size_t)(b * 192 + c)) * MDICT + m] = __float2bfloat16(s);
    }
    {
        float s = wtdb[t];
        for (int k = 0; k < CDIM; k++) s += tr[k] * wtd[k * DTD + t];
        tdp[(size_t)blk * DTD + t] = s;
    }
}

// ---------------- Stable counting sort of tk_id ----------------------------
__global__ __launch_bounds__(256) void sort_kernel(const int* __restrict__ tk_id,
                                                   int* __restrict__ sidx)
{
    int b = blockIdx.x; int tid = threadIdx.x;
    __shared__ int keys[NTOK];
    __shared__ int cnt[256];
    __shared__ int off[256];
    const int* kb = tk_id + (size_t)b * NTOK;
    for (int i = tid; i < NTOK; i += 256) keys[i] = kb[i];
    __syncthreads();
    int v = tid >> 2, seg = tid & 3;
    int lo = seg * 1024, hi = lo + 1024;
    int c = 0;
    for (int i = lo; i < hi; i++) c += (keys[i] == v);
    cnt[tid] = c;
    __syncthreads();
    if (tid == 0) {
        int run = 0;
        for (int l = 0; l < 256; l++) { off[l] = run; run += cnt[l]; }
    }
    __syncthreads();
    int o = off[tid];
    int* sb = sidx + (size_t)b * NTOK;
    for (int i = lo; i < hi; i++) if (keys[i] == v) sb[o++] = i;
}

// ---------------- Gather dictionary features into hc[:, 360:424] -----------
__global__ __launch_bounds__(256) void gather_td_kernel(const int* __restrict__ tk_id,
        const float* __restrict__ tdp, float* __restrict__ hc)
{
    int idx = blockIdx.x * 256 + threadIdx.x;
    int row = idx >> 6, j = idx & 63;
    int b = row >> 12;
    int tk = tk_id[row];
    hc[(size_t)row * CCAT + MHID + j] = tdp[((size_t)b * MDICT + tk) * DTD + j];
}

// ---------------- Depthwise 5x5 conv: CHK=64, 8x8 tile, bf16 KP2 out -------
// R15 VERBATIM (proven 5x: ~97.7us, VGPR 68, conflicts 0, writes ideal).
#define CHK3 64
#define CTW  8
#define CTH  8
#define CHW  12     // halo width/height = tile + 4
#define CHP  144    // 12*12 halo pixels
#define CSPX 68     // floats per pixel row (64 + 4 pad) = 272B, 16B-aligned
__global__ __launch_bounds__(256) void conv_kernel(const float* __restrict__ hc,
        const float* __restrict__ w, const float* __restrict__ wb,
        bf16* __restrict__ outb)
{
    int ch0 = blockIdx.x * CHK3;        // 0,64,...,384 (7 blocks; 424..447 zeroed)
    int tile = blockIdx.y;              // 64 tiles of 8x8
    int b = blockIdx.z;
    int ty0 = (tile >> 3) * CTH, tx0 = (tile & 7) * CTW;
    __shared__ __align__(16) float sh[CHP][CSPX];   // 39168 B
    __shared__ __align__(16) float wt[25][CHK3];    // 6400 B
    int tid = threadIdx.x;
    // stage input: lanes cover 64 contiguous channels of one pixel (256B)
    for (int idx = tid; idx < CHP * CHK3; idx += 256) {
        int pix = idx >> 6, ch = idx & 63;
        int gy = ty0 + pix / CHW - 2, gx = tx0 + pix % CHW - 2;
        int chg = ch0 + ch;
        float v = 0.f;
        if (gy >= 0 && gy < 64 && gx >= 0 && gx < 64 && chg < CCAT)
            v = hc[((size_t)b * NTOK + gy * 64 + gx) * CCAT + chg];
        sh[pix][ch] = v;
    }
    for (int idx = tid; idx < 25 * CHK3; idx += 256) {
        int kk = idx >> 6, ch = idx & 63;
        int chg = ch0 + ch;
        wt[kk][ch] = (chg < CCAT) ? w[chg * 25 + kk] : 0.f;
    }
    __syncthreads();
    int q = tid & 3, p = tid >> 2;      // p: pixel 0..63; q: 16-ch subgroup
    int px = p & 7, py = p >> 3;
    int cb = q * 16;
    int pc = py * CHW + px;             // top-left of 5x5 window
    v8s pk0, pk1;
    #pragma unroll
    for (int sub = 0; sub < 4; sub++) {
        int cs = cb + sub * 4;
        f32x4 acc = {0.f, 0.f, 0.f, 0.f};
        #pragma unroll
        for (int dy = 0; dy < 5; dy++) {
            #pragma unroll
            for (int dx = 0; dx < 5; dx++) {
                f32x4 sv = *(const f32x4*)&sh[pc + dy * CHW + dx][cs];
                f32x4 wv = *(const f32x4*)&wt[dy * 5 + dx][cs];
                acc += sv * wv;
            }
            __builtin_amdgcn_sched_barrier(0);   // cap hoisting at one row
        }
        f32x4 ctr = *(const f32x4*)&sh[pc + 2 * CHW + 2][cs];
        #pragma unroll
        for (int c = 0; c < 4; c++) {
            int chg = ch0 + cs + c;
            float v = 0.f;
            if (chg < CCAT) {
                float gv = gelu_exact(acc[c] + wb[chg]);
                v = ctr[c] + gv;
            }
            int lc = sub * 4 + c;
            if (lc < 8) pk0[lc] = (short)f2b(v);
            else        pk1[lc - 8] = (short)f2b(v);
        }
        __builtin_amdgcn_sched_barrier(0);
    }
    size_t obase = ((size_t)b * NTOK + (ty0 + py) * 64 + tx0 + px) * KP2 + ch0 + cb;
    unsigned short* ob = (unsigned short*)outb + obase;   // 32B-aligned
    *(v8s*)ob = pk0;
    *(v8s*)(ob + 8) = pk1;
}

// ---------------------------------------------------------------------------
extern "C" void kernel_launch(void* const* d_in, const int* in_sizes, int n_in,
                              void* d_out, int out_size, void* d_ws, size_t ws_size,
                              hipStream_t stream)
{
    (void)n_in; (void)ws_size; (void)out_size;
    const int* rpi = (const int*)d_in[28];

    // ---- workspace carve-up ----
    float* p = (float*)d_ws;
    float* xn    = p; p += (size_t)ROWS * CDIM;    // R23: tmp2b bf16 lives here
    float* acc   = p; p += (size_t)ROWS * CDIM;
    float* tmp1  = p; p += (size_t)ROWS * CDIM;    // alias: P bf16 (head), fc2 out
    float* qkv   = p; p += (size_t)ROWS * C3;      // alias: qkvb bf16; hc fp32 post-win
    float* hcnew = p; p += (size_t)ROWS * CCAT;    // alias: xnb/tmp1b; then conv bf16 out
    float* kkn   = p; p += (size_t)BB * MDICT * RD;
    bf16*  vvT   = (bf16*)p; p += (size_t)BB * 192 * MDICT / 2;   // bf16 [8][192][64]
    float* tdp   = p; p += (size_t)BB * MDICT * DTD;
    int*   tk_id = (int*)p; p += ROWS;
    int*   sidx  = (int*)p; p += ROWS;
    int*   flag  = (int*)p; p += 64;
    int*   diag  = (int*)p; p += 64;
    bf16* wtqkv  = (bf16*)p; p += 576 * KP1 / 2;
    bf16* wtcomb = (bf16*)p; p += 192 * 384 / 2;   // [192][384]: aca | win halves
    bf16* wtfc1  = (bf16*)p; p += 384 * KP1 / 2;
    bf16* wtfc2  = (bf16*)p; p += 192 * KP2 / 2;
    float* cin[28];
    for (int i = 0; i < 28; i++) { cin[i] = p; p += in_sizes[i]; }
    float* bias_t = p; p += (size_t)NHEADS * WIN_N * WIN_N;   // 1.5 MB

    float* hc      = qkv;                // fp32 [ROWS,CCAT]; born after win (qkv dead)
    bf16*  qkvb    = (bf16*)qkv;         // bf16 [ROWS,576] padded; dies at win
    bf16*  xnb     = (bf16*)hcnew;                            // [ROWS,KP1]; dies at fc1
    bf16*  tmp1b   = (bf16*)(hcnew + (size_t)ROWS * KP1 / 2); // [ROWS,KP1]; win out
    bf16*  tmp2b   = (bf16*)xn;          // [ROWS,KP1] bf16; acmsa out (xn region)
    bf16*  hcnewb2 = (bf16*)hcnew;       // [ROWS,KP2] bf16; born at conv
    bf16*  Pbuf    = (bf16*)tmp1;        // [ROWS,64] bf16 = 4MB; dies after av_mgemm

    // ---- dtype detect (+diag=0) + batched input normalize to fp32 ----
    detect_kernel<<<1, 256, 0, stream>>>(d_in[0], flag, diag);
    {
        CvtArgs ca;
        int total = 0, s = 0;
        for (int i = 0; i < 28; i++) {
            if (i == 0 || i == 4 || i == 13 || i == 16 || i == 20 || i == 24) continue;
            ca.src[s] = d_in[i];
            ca.dst[s] = cin[i];
            ca.cum[s] = total;
            total += in_sizes[i];
            s++;
        }
        ca.cum[s] = total;
        convert_all_kernel<<<(total + 255) / 256, 256, 0, stream>>>(ca, total, flag);
    }
    const float *td = cin[1], *n1g = cin[2], *n1b = cin[3],
        *wqkv_b = cin[5], *wq_w = cin[6], *wq_b = cin[7],
        *wk_w = cin[8], *wk_b = cin[9], *wv_w = cin[10], *wv_b = cin[11],
        *atd_scale = cin[12], *aca_b = cin[14], *win_rpb = cin[15],
        *winp_b = cin[17], *fctd_w = cin[18], *fctd_b = cin[19],
        *fc1_b = cin[21], *dw_w = cin[22], *dw_b = cin[23], *fc2_b = cin[25],
        *n2g = cin[26], *n2b = cin[27];

    // ---- adaptive weight repacks (by value) + bias table ----
    packW_kernel<<<576 * KP1 / 256, 256, 0, stream>>>(d_in[4],  wtqkv, CDIM, C3,   KP1, KP1, 0,   576 * KP1, flag);
    packW_kernel<<<192 * KP1 / 256, 256, 0, stream>>>(d_in[13], wtcomb, CDIM, CDIM, KP1, 384, 0,   192 * KP1, flag);
    packW_kernel<<<192 * KP1 / 256, 256, 0, stream>>>(d_in[16], wtcomb, CDIM, CDIM, KP1, 384, 192, 192 * KP1, flag);
    packW_kernel<<<384 * KP1 / 256, 256, 0, stream>>>(d_in[20], wtfc1, CDIM, MHID, KP1, KP1, 0,   384 * KP1, flag);
    packW_kernel<<<192 * KP2 / 256, 256, 0, stream>>>(d_in[24], wtfc2, CCAT, CDIM, KP2, KP2, 0,   192 * KP2, flag);
    bias_pre_kernel<<<NHEADS * WIN_N * WIN_N / 256, 256, 0, stream>>>(rpi, win_rpb, bias_t);

    td_pre_kernel<<<BB * MDICT, 64, 0, stream>>>(td, wk_w, wk_b, wv_w, wv_b,
                                                 fctd_w, fctd_b, kkn, vvT, tdp);
    // Fused LN1 + ATD (x dtype-flex): xnb bf16 + P + tk_id in one pass
    ln_atd_kernel<<<ROWS / 4, 256, 0, stream>>>(d_in[0], flag, n1g, n1b, xnb,
                                                wq_w, wq_b, atd_scale, kkn, Pbuf, tk_id);
    // qkv gemm: bf16 padded output (Q pre-scaled)
    mgemm_kernel<false, false, true, 1><<<dim3(9, ROWS / 128), 256, 0, stream>>>(
        xnb, KP1, wtqkv, KP1, wqkv_b, nullptr, 0, (float*)qkvb, QKVP, C3, KP1,
        nullptr, nullptr, nullptr);
    // merged zeroing: tmp1b/tmp2b K-tails + qkvb pad slots
    zero_aux_kernel<<<ROWS * 60 / 256, 256, 0, stream>>>(tmp1b, tmp2b, qkvb);
    av_mgemm_kernel<<<dim3(3, NTOK / 64, BB), 256, 0, stream>>>(Pbuf, vvT, d_in[0], flag, acc);
    sort_kernel<<<BB, 256, 0, stream>>>(tk_id, sidx);
    // MFMA flash AC_MSA -> tmp2b (bf16 direct)
    acmsa_mfma_kernel<<<dim3(NG * NHEADS, BB), 256, 0, stream>>>(qkvb, sidx, tmp2b);
    // MFMA flash window attention -> tmp1b (bf16 direct)
    win_mfma_kernel<<<dim3(16 * NHEADS, BB), 256, 0, stream>>>(qkvb, bias_t, tmp1b);
    // combined aca+winp gemm: acc += tmp2b@Waca + tmp1b@Wwin + (aca_b+winp_b)
    mgemm_kernel<false, true, true, 3><<<dim3(3, ROWS / 128), 256, 0, stream>>>(
        tmp2b, KP1, wtcomb, 384, aca_b, acc, CDIM, acc, CDIM, CDIM, 384,
        nullptr, tmp1b, winp_b);
    // FFN: LN2 (bf16 out only) -> fc1 -> gather -> conv -> fc2 (+NaN check)
    ln_kernel<<<ROWS / 4, 256, 0, stream>>>(acc, n2g, n2b, xnb);
    mgemm_kernel<true, false, true, 0><<<dim3(6, ROWS / 128), 256, 0, stream>>>(
        xnb, KP1, wtfc1, KP1, fc1_b, nullptr, 0, hc, CCAT, MHID, KP1,
        nullptr, nullptr, nullptr);
    gather_td_kernel<<<ROWS * 64 / 256, 256, 0, stream>>>(tk_id, tdp, hc);
    conv_kernel<<<dim3(7, 64, BB), 256, 0, stream>>>(hc, dw_w, dw_b, hcnewb2);
    mgemm_kernel<false, true, true, 2><<<dim3(3, ROWS / 128), 256, 0, stream>>>(
        hcnewb2, KP2, wtfc2, KP2, fc2_b, acc, CDIM, tmp1, CDIM, CDIM, KP2,
        diag, nullptr, nullptr);
    emit_kernel<<<(ROWS * CDIM + 255) / 256, 256, 0, stream>>>(
        tmp1, d_out, flag, diag, ROWS * CDIM);
}

// Round 14
// 648.366 us; speedup vs baseline: 1.1622x; 1.0287x over previous
//
#include <hip/hip_runtime.h>
#include <hip/hip_bf16.h>
#include <math.h>

// MPv2_3d_arch: B=8, n=64*64=4096, c=180, heads=6 (hd=30), dict M=64, rd=10,
// dtd=64, mlp_hid=360, cat C=424, window 16x16, groups of 128.
// R25: R24 (passing, 667us) + consolidation round 3:
// (a) mega-gemm K=448: av_mgemm absorbed as third A-segment (Pbuf, lda=64)
//     + per-batch vvT B-segment (bz=row0>>12) for k in [384,448); residual x
//     dtype-flex in epilogue. -47MB acc traffic, -1 launch. Reassoc-equal.
// (b) fc2 (OM=2) writes d_out directly in detected dtype + NaN scan; emit
//     deleted; 1-block nan_patch preserves all-or-nothing NaN semantics
//     (early exit when diag==0). -47MB tmp1 traffic.
// Conv = R15 verbatim (proven 6x: ~98us, VGPR 68, conflicts 0).
// SESSION RULE: input dtype VARIES per run (bf16 or fp32) — every d_in
// access must go through *flag (by value). Raw-bit reads = NaN.
#define BB      8
#define NTOK    4096
#define CDIM    180
#define C3      540
#define NHEADS  6
#define HD      30
#define MDICT   64
#define RD      10
#define DTD     64
#define MHID    360
#define CCAT    424
#define WS      16
#define WIN_N   256
#define GS      128
#define NG      32
#define ROWS    (BB*NTOK)   // 32768
#define KP1     192         // Kpad for K=180
#define KP2     448         // Kpad for K=424
#define QKVP    576         // padded qkv row: 3 sec * 6 heads * 32

typedef __hip_bfloat16 bf16;
typedef short v8s __attribute__((ext_vector_type(8)));
typedef float f32x4 __attribute__((ext_vector_type(4)));
typedef unsigned int u32x4 __attribute__((ext_vector_type(4)));

__device__ __forceinline__ float gelu_exact(float x) {
    return 0.5f * x * (1.0f + erff(x * 0.70710678118654752f));
}
__device__ __forceinline__ float wave_sum(float v) {
    #pragma unroll
    for (int off = 32; off > 0; off >>= 1) v += __shfl_xor(v, off, 64);
    return v;
}
// fp32 <-> bf16 bits without type-punning (RNE)
__device__ __forceinline__ unsigned short f2b(float v) {
    unsigned u = __float_as_uint(v);
    return (unsigned short)((u + 0x7FFFu + ((u >> 16) & 1u)) >> 16);
}
__device__ __forceinline__ float b2f(unsigned short h) {
    return __uint_as_float(((unsigned)h) << 16);
}
__device__ __forceinline__ unsigned packbf(float lo, float hi) {
    return (unsigned)f2b(lo) | ((unsigned)f2b(hi) << 16);
}
// async global->LDS 16B (gfx950); size must be literal; lds addr = per-lane
// slot in lane-order-contiguous slab (wave-uniform base + lane*16).
__device__ __forceinline__ void gload16(const void* g, void* l) {
    __builtin_amdgcn_global_load_lds(
        (const __attribute__((address_space(1))) void*)g,
        (__attribute__((address_space(3))) void*)l, 16, 0, 0);
}

// ---------------- dtype detector: flag=1 if inputs are fp32, 0 if bf16 -----
__global__ __launch_bounds__(256) void detect_kernel(const void* __restrict__ x,
                                                     int* __restrict__ flag,
                                                     int* __restrict__ diag)
{
    __shared__ int cnt;
    if (threadIdx.x == 0) { cnt = 0; *diag = 0; }
    __syncthreads();
    const unsigned short* u = (const unsigned short*)x;
    int c = 0;
    for (int i = threadIdx.x; i < 2048; i += 256) {
        unsigned short e = u[2 * i] & 0x7F80;
        if (e >= 0x4300) c++;
    }
    atomicAdd(&cnt, c);
    __syncthreads();
    if (threadIdx.x == 0) *flag = (cnt > 16) ? 1 : 0;
}

// ---------------- batched dtype-flexible input -> fp32 conversion ----------
#define NCVT 23
struct CvtArgs {
    const void* src[NCVT];
    float* dst[NCVT];
    int cum[NCVT + 1];
};
__global__ __launch_bounds__(256) void convert_all_kernel(CvtArgs a, int total,
        const int* __restrict__ flag)
{
    int i = blockIdx.x * 256 + threadIdx.x;
    if (i >= total) return;
    int s = 0;
    while (i >= a.cum[s + 1]) s++;
    int off = i - a.cum[s];
    if (*flag) a.dst[s][off] = ((const float*)a.src[s])[off];
    else       a.dst[s][off] = __bfloat162float(((const bf16*)a.src[s])[off]);
}

// ---------------- NaN patch: if diag set, overwrite d_out with stage code --
// 1 block; early-exits when diag==0 (passing path ~launch cost only).
__global__ __launch_bounds__(256) void nan_patch_kernel(void* __restrict__ out,
        const int* __restrict__ flag, const int* __restrict__ diag)
{
    int d = *diag;
    if (!d) return;
    float v = 100.f + 32.f * (float)d;
    int isf = *flag;
    for (size_t i = threadIdx.x; i < (size_t)ROWS * CDIM; i += 256) {
        if (isf) ((float*)out)[i] = v;
        else     ((bf16*)out)[i]  = __float2bfloat16(v);
    }
}

// ---------------- merged zeroing: tmp1b/tmp2b tails + qkvb pad slots -------
__global__ __launch_bounds__(256) void zero_aux_kernel(bf16* __restrict__ t1,
        bf16* __restrict__ t2, bf16* __restrict__ qb)
{
    int idx = blockIdx.x * 256 + threadIdx.x;   // ROWS*60
    if (idx < ROWS * 12) {
        int row = idx / 12, c = idx % 12;
        t1[(size_t)row * KP1 + CDIM + c] = __float2bfloat16(0.f);
    } else if (idx < ROWS * 24) {
        int j = idx - ROWS * 12;
        int row = j / 12, c = j % 12;
        t2[(size_t)row * KP1 + CDIM + c] = __float2bfloat16(0.f);
    } else {
        int j = idx - ROWS * 24;
        int row = j / 36, r = j % 36;
        int sec = r / 12, rr = r % 12, hh = rr >> 1, d = 30 + (rr & 1);
        qb[(size_t)row * QKVP + sec * 192 + hh * 32 + d] = __float2bfloat16(0.f);
    }
}

// -------- adaptive weight repack: W[K,N] -> Wt[n*ldw + koff + k] bf16 ------
__global__ __launch_bounds__(256) void packW_kernel(const void* __restrict__ W,
        bf16* __restrict__ Wt, int K, int N, int Kpad, int ldw, int koff,
        int total, const int* __restrict__ flag)
{
    int idx = blockIdx.x * 256 + threadIdx.x;
    if (idx >= total) return;
    int n = idx / Kpad, k = idx % Kpad;
    float v = 0.f;
    if (k < K && n < N) {
        size_t src = (size_t)k * N + n;
        v = (*flag) ? ((const float*)W)[src]
                    : __bfloat162float(((const bf16*)W)[src]);
    }
    Wt[(size_t)n * ldw + koff + k] = __float2bfloat16(v);
}

// ---------------- window-attention bias table: [6][256][256] ---------------
__global__ __launch_bounds__(256) void bias_pre_kernel(const int* __restrict__ rpi,
        const float* __restrict__ rpb, float* __restrict__ bias_t)
{
    int idx = blockIdx.x * 256 + threadIdx.x;   // 6*65536
    int h = idx >> 16, ij = idx & 65535;
    bias_t[idx] = rpb[rpi[ij] * NHEADS + h];
}

// ---------------- MFMA GEMM: out = act(A@W [+bias]) [+ res] ----------------
// R18 structure: 128(M)x64(N) tile, 256 threads, global_load_lds staging,
// 8 MFMA/k-step/wave. OM=1: bf16 out to padded qkv layout (Q pre-scaled).
// OM=2: res=acc + NaN scan + dtype-flex store to d_out (emit fused).
// OM=3: triple-A mega (k<192: A=tmp2b; 192..383: A2=tmp1b; 384..447:
// A3=Pbuf with per-batch W2=vvT[bz]); bias+bias2; + dtype-flex x residual.
template<bool GELU_, bool ADDRES, bool BIAS_, int OM>
__global__ __launch_bounds__(256) void mgemm_kernel(
        const bf16* __restrict__ A, int lda,
        const bf16* __restrict__ Wt, int ldw,
        const float* __restrict__ bias,
        const float* __restrict__ res, int ldr,
        float* __restrict__ outF, int ldo, int N, int K,
        int* __restrict__ diag,
        const bf16* __restrict__ A2, const float* __restrict__ bias2,
        const bf16* __restrict__ A3, const bf16* __restrict__ W2,
        const void* __restrict__ xraw, const int* __restrict__ flagp)
{
    __shared__ __align__(16) unsigned short As[128][32];   // 8 KB
    __shared__ __align__(16) unsigned short Bs[64][32];    // 4 KB
    int tid = threadIdx.x;
    int wave = tid >> 6, lane = tid & 63;
    int quad = lane >> 4, mr = lane & 15;
    int row0 = blockIdx.y * 128, col0 = blockIdx.x * 64;
    int bz = row0 >> 12;                     // batch (rows 4096-aligned)
    int ar = tid >> 2, ac = (tid & 3) * 8;   // LDS slot byte off = tid*16
    int isf = (OM == 2 || OM == 3) ? *flagp : 0;
    f32x4 z = {0.f, 0.f, 0.f, 0.f};
    f32x4 acc[2][4] = {{z, z, z, z}, {z, z, z, z}};
    const unsigned short* Au = (const unsigned short*)A;
    const unsigned short* A2u = (const unsigned short*)A2;
    const unsigned short* A3u = (const unsigned short*)A3;
    const unsigned short* Wu = (const unsigned short*)Wt;
    for (int k0 = 0; k0 < K; k0 += 32) {
        const unsigned short* Asel = Au;
        int kk = k0, ldA = lda;
        if (OM == 3) {
            if (k0 >= 384)      { Asel = A3u; kk = k0 - 384; ldA = MDICT; }
            else if (k0 >= KP1) { Asel = A2u; kk = k0 - KP1; ldA = KP1;   }
        }
        gload16(&Asel[(size_t)(row0 + ar) * ldA + kk + ac],      &As[ar][ac]);
        gload16(&Asel[(size_t)(row0 + 64 + ar) * ldA + kk + ac], &As[64 + ar][ac]);
        if (OM == 3 && k0 >= 384) {
            const unsigned short* Wu2 =
                (const unsigned short*)W2 + (size_t)bz * 192 * MDICT;
            gload16(&Wu2[(size_t)(col0 + ar) * MDICT + (k0 - 384) + ac], &Bs[ar][ac]);
        } else {
            gload16(&Wu[(size_t)(col0 + ar) * ldw + k0 + ac], &Bs[ar][ac]);
        }
        __syncthreads();   // compiler emits vmcnt(0) drain before barrier
        v8s bfr[4];
        #pragma unroll
        for (int ni = 0; ni < 4; ni++)
            bfr[ni] = *(const v8s*)&Bs[ni * 16 + mr][quad * 8];
        #pragma unroll
        for (int s = 0; s < 2; s++) {
            v8s a = *(const v8s*)&As[wave * 32 + s * 16 + mr][quad * 8];
            #pragma unroll
            for (int ni = 0; ni < 4; ni++)
                acc[s][ni] = __builtin_amdgcn_mfma_f32_16x16x32_bf16(
                    a, bfr[ni], acc[s][ni], 0, 0, 0);
        }
        __syncthreads();
    }
    if (OM == 1) {
        bf16* outb = (bf16*)outF;
        #pragma unroll
        for (int ni = 0; ni < 4; ni++) {
            int gc = col0 + ni * 16 + mr;
            if (gc >= N) continue;
            float bv = bias[gc];
            int sec = gc / 180, rem = gc - sec * 180;
            int hh = rem / 30, d = rem - hh * 30;
            int slot = sec * 192 + hh * 32 + d;
            float sc = (sec == 0) ? 0.18257418583505536f : 1.f;
            #pragma unroll
            for (int s = 0; s < 2; s++) {
                #pragma unroll
                for (int r = 0; r < 4; r++) {
                    int gr = row0 + wave * 32 + s * 16 + quad * 4 + r;
                    outb[(size_t)gr * QKVP + slot] =
                        __float2bfloat16((acc[s][ni][r] + bv) * sc);
                }
            }
        }
        return;
    }
    #pragma unroll
    for (int ni = 0; ni < 4; ni++) {
        int gc = col0 + ni * 16 + mr;
        if (gc >= N) continue;
        float bv = BIAS_ ? bias[gc] : 0.f;
        if (OM == 3) bv += bias2[gc];
        #pragma unroll
        for (int s = 0; s < 2; s++) {
            #pragma unroll
            for (int r = 0; r < 4; r++) {
                int gr = row0 + wave * 32 + s * 16 + quad * 4 + r;
                size_t off = (size_t)gr * ldo + gc;
                float v = acc[s][ni][r] + bv;
                if (GELU_) v = gelu_exact(v);
                if (ADDRES) v += res[(size_t)gr * ldr + gc];
                if (OM == 3) {
                    size_t xo = (size_t)gr * CDIM + gc;
                    float xv = isf ? ((const float*)xraw)[xo]
                                   : __bfloat162float(((const bf16*)xraw)[xo]);
                    v += xv;
                }
                if (OM == 2) {
                    unsigned u = __float_as_uint(v);
                    if ((u & 0x7F800000u) == 0x7F800000u) atomicOr(diag, 8);
                    if (isf) ((float*)outF)[off] = v;
                    else     ((bf16*)outF)[off]  = __float2bfloat16(v);
                } else {
                    outF[off] = v;
                }
            }
        }
    }
}

// ---------------- Window attention, MFMA flash (bf16 KP1 out) --------------
// R12 structure + R19 bf16-qkv input: Q/K/V loaded as aligned v8s from the
// padded [ROWS][576] layout (Q pre-scaled, pads zero) — no f2b at load.
__global__ __launch_bounds__(256, 4) void win_mfma_kernel(const bf16* __restrict__ qkvb,
        const float* __restrict__ bias_t, bf16* __restrict__ outb)
{
    int b = blockIdx.y;
    int widx = blockIdx.x / NHEADS;
    int hh = blockIdx.x % NHEADS;
    int wy = widx >> 2, wx = widx & 3;
    int tid = threadIdx.x;
    int wave = tid >> 6, lane = tid & 63, quad = lane >> 4, mr = lane & 15;
    __shared__ __align__(16) unsigned short Ks[64][40];
    __shared__ __align__(16) unsigned short Vt[32][80];

    size_t brow = (size_t)b * NTOK;
    const unsigned short* qu = (const unsigned short*)qkvb;

    v8s aq[4];
    #pragma unroll
    for (int tt = 0; tt < 4; tt++) {
        int m = (wave * 4 + tt) * 16 + mr;
        int nt_ = (wy * WS + (m >> 4)) * 64 + wx * WS + (m & 15);
        aq[tt] = *(const v8s*)&qu[(brow + nt_) * QKVP + hh * 32 + quad * 8];
    }
    f32x4 z = {0.f, 0.f, 0.f, 0.f};
    f32x4 oacc[4][2] = {{z, z}, {z, z}, {z, z}, {z, z}};
    float m_r[4], l_r[4];
    #pragma unroll
    for (int tt = 0; tt < 4; tt++) { m_r[tt] = -3.0e38f; l_r[tt] = 0.f; }
    const float* btab = bias_t + (size_t)hh * WIN_N * WIN_N;

    for (int kc = 0; kc < WIN_N; kc += 64) {
        {
            int j = tid >> 2, dg = (tid & 3) * 8;
            int tok = kc + j;
            int nt_ = (wy * WS + (tok >> 4)) * 64 + wx * WS + (tok & 15);
            const unsigned short* base = qu + (brow + nt_) * QKVP + hh * 32;
            v8s kv = *(const v8s*)&base[192 + dg];
            v8s vv = *(const v8s*)&base[384 + dg];
            *(v8s*)&Ks[j][dg] = kv;
            #pragma unroll
            for (int jj = 0; jj < 8; jj++)
                Vt[dg + jj][j] = (unsigned short)vv[jj];
        }
        __syncthreads();
        #pragma unroll
        for (int tt = 0; tt < 4; tt++) {
            // --- QK^T swapped: s[nt][r] = S[key=kc+nt*16+quad*4+r][query] ---
            f32x4 s[4];
            #pragma unroll
            for (int nt = 0; nt < 4; nt++) {
                v8s bk = *(const v8s*)&Ks[nt * 16 + mr][quad * 8];
                s[nt] = __builtin_amdgcn_mfma_f32_16x16x32_bf16(bk, aq[tt], z, 0, 0, 0);
            }
            int qg = (wave * 4 + tt) * 16 + mr;
            const float* bi = btab + (size_t)qg * WIN_N + kc;
            float mc = -3.0e38f;
            #pragma unroll
            for (int nt = 0; nt < 4; nt++) {
                f32x4 b4 = *(const f32x4*)(bi + nt * 16 + quad * 4);
                s[nt][0] += b4[0]; s[nt][1] += b4[1];
                s[nt][2] += b4[2]; s[nt][3] += b4[3];
                mc = fmaxf(mc, fmaxf(fmaxf(s[nt][0], s[nt][1]),
                                     fmaxf(s[nt][2], s[nt][3])));
            }
            mc = fmaxf(mc, __shfl_xor(mc, 16, 64));
            mc = fmaxf(mc, __shfl_xor(mc, 32, 64));
            float mn = fmaxf(m_r[tt], mc);
            float alpha = __expf(m_r[tt] - mn);
            m_r[tt] = mn;
            float ls = 0.f;
            #pragma unroll
            for (int nt = 0; nt < 4; nt++) {
                #pragma unroll
                for (int r = 0; r < 4; r++) {
                    float pp = __expf(s[nt][r] - mn);
                    ls += pp;
                    s[nt][r] = pp;
                }
            }
            ls += __shfl_xor(ls, 16, 64);
            ls += __shfl_xor(ls, 32, 64);
            l_r[tt] = l_r[tt] * alpha + ls;
            // --- pack P (bf16 pairs): dpk[nt][s] = keys nt*16+quad*4+{2s,2s+1}
            unsigned dpk[4][2];
            #pragma unroll
            for (int nt = 0; nt < 4; nt++) {
                dpk[nt][0] = packbf(s[nt][0], s[nt][1]);
                dpk[nt][1] = packbf(s[nt][2], s[nt][3]);
            }
            // --- rescale oacc rows (query = quad*4+r) by alpha ---
            #pragma unroll
            for (int r = 0; r < 4; r++) {
                float av = __shfl(alpha, quad * 4 + r, 64);
                oacc[tt][0][r] *= av;
                oacc[tt][1][r] *= av;
            }
            // --- PV: build A-frags via cross-lane shuffle, 2 chunks of K=32 --
            #pragma unroll
            for (int c = 0; c < 2; c++) {
                union { u32x4 u; v8s s8; } afu;
                #pragma unroll
                for (int t = 0; t < 4; t++) {
                    int srcl = (((quad * 2 + (t >> 1)) & 3) << 4) | mr;
                    unsigned r0 = (unsigned)__shfl((int)dpk[2 * c][t & 1], srcl, 64);
                    unsigned r1 = (unsigned)__shfl((int)dpk[2 * c + 1][t & 1], srcl, 64);
                    afu.u[t] = (quad & 2) ? r1 : r0;
                }
                #pragma unroll
                for (int dt = 0; dt < 2; dt++) {
                    v8s bv = *(const v8s*)&Vt[dt * 16 + mr][c * 32 + quad * 8];
                    oacc[tt][dt] = __builtin_amdgcn_mfma_f32_16x16x32_bf16(
                        afu.s8, bv, oacc[tt][dt], 0, 0, 0);
                }
            }
        }
        __syncthreads();
    }
    #pragma unroll
    for (int tt = 0; tt < 4; tt++) {
        float il = 1.f / l_r[tt];
        #pragma unroll
        for (int r = 0; r < 4; r++) {
            float ilr = __shfl(il, quad * 4 + r, 64);
            int m = (wave * 4 + tt) * 16 + quad * 4 + r;
            int nt_ = (wy * WS + (m >> 4)) * 64 + wx * WS + (m & 15);
            #pragma unroll
            for (int dt = 0; dt < 2; dt++) {
                int d = dt * 16 + mr;
                if (d >= HD) continue;
                outb[(brow + nt_) * KP1 + hh * HD + d] =
                    __float2bfloat16(oacc[tt][dt][r] * ilr);
            }
        }
    }
}

// ---------------- AC_MSA, MFMA flash, swapped QK^T -------------------------
// R17 structure + R19 bf16-qkv input (v8s loads, toks[] indirection).
__global__ __launch_bounds__(256, 4) void acmsa_mfma_kernel(const bf16* __restrict__ qkvb,
        const int* __restrict__ sidx, bf16* __restrict__ outb)
{
    int b = blockIdx.y;
    int g = blockIdx.x / NHEADS;
    int hh = blockIdx.x % NHEADS;
    int tid = threadIdx.x;
    int wave = tid >> 6, lane = tid & 63, quad = lane >> 4, mr = lane & 15;
    __shared__ int toks[GS];
    __shared__ __align__(16) unsigned short Ks[64][40];
    __shared__ __align__(16) unsigned short Vt[32][80];

    size_t brow = (size_t)b * NTOK;
    if (tid < GS) toks[tid] = sidx[brow + (size_t)g * GS + tid];
    __syncthreads();
    const unsigned short* qu = (const unsigned short*)qkvb;

    v8s aq[2];
    #pragma unroll
    for (int tt = 0; tt < 2; tt++) {
        int m = (wave * 2 + tt) * 16 + mr;
        aq[tt] = *(const v8s*)&qu[(brow + toks[m]) * QKVP + hh * 32 + quad * 8];
    }
    f32x4 z = {0.f, 0.f, 0.f, 0.f};
    f32x4 oacc[2][2] = {{z, z}, {z, z}};
    float m_r[2], l_r[2];
    #pragma unroll
    for (int tt = 0; tt < 2; tt++) { m_r[tt] = -3.0e38f; l_r[tt] = 0.f; }

    for (int kc = 0; kc < GS; kc += 64) {
        {
            int j = tid >> 2, dg = (tid & 3) * 8;
            int tok = toks[kc + j];
            const unsigned short* base = qu + (brow + tok) * QKVP + hh * 32;
            v8s kv = *(const v8s*)&base[192 + dg];
            v8s vv = *(const v8s*)&base[384 + dg];
            *(v8s*)&Ks[j][dg] = kv;
            #pragma unroll
            for (int jj = 0; jj < 8; jj++)
                Vt[dg + jj][j] = (unsigned short)vv[jj];
        }
        __syncthreads();
        #pragma unroll
        for (int tt = 0; tt < 2; tt++) {
            // --- QK^T swapped: s[nt][r] = S[key=kc+nt*16+quad*4+r][query=mr]
            f32x4 s[4];
            #pragma unroll
            for (int nt = 0; nt < 4; nt++) {
                v8s bk = *(const v8s*)&Ks[nt * 16 + mr][quad * 8];
                s[nt] = __builtin_amdgcn_mfma_f32_16x16x32_bf16(aq[tt], bk, z, 0, 0, 0);
                s[nt] = __builtin_amdgcn_mfma_f32_16x16x32_bf16(bk, aq[tt], z, 0, 0, 0);
            }
            float mc = -3.0e38f;
            #pragma unroll
            for (int nt = 0; nt < 4; nt++)
                mc = fmaxf(mc, fmaxf(fmaxf(s[nt][0], s[nt][1]),
                                     fmaxf(s[nt][2], s[nt][3])));
            mc = fmaxf(mc, __shfl_xor(mc, 16, 64));
            mc = fmaxf(mc, __shfl_xor(mc, 32, 64));
            float mn = fmaxf(m_r[tt], mc);
            float alpha = __expf(m_r[tt] - mn);
            m_r[tt] = mn;
            float ls = 0.f;
            #pragma unroll
            for (int nt = 0; nt < 4; nt++) {
                #pragma unroll
                for (int r = 0; r < 4; r++) {
                    float pp = __expf(s[nt][r] - mn);
                    ls += pp;
                    s[nt][r] = pp;
                }
            }
            ls += __shfl_xor(ls, 16, 64);
            ls += __shfl_xor(ls, 32, 64);
            l_r[tt] = l_r[tt] * alpha + ls;
            unsigned dpk[4][2];
            #pragma unroll
            for (int nt = 0; nt < 4; nt++) {
                dpk[nt][0] = packbf(s[nt][0], s[nt][1]);
                dpk[nt][1] = packbf(s[nt][2], s[nt][3]);
            }
            #pragma unroll
            for (int r = 0; r < 4; r++) {
                float av = __shfl(alpha, quad * 4 + r, 64);
                oacc[tt][0][r] *= av;
                oacc[tt][1][r] *= av;
            }
            #pragma unroll
            for (int c = 0; c < 2; c++) {
                union { u32x4 u; v8s s8; } afu;
                #pragma unroll
                for (int t = 0; t < 4; t++) {
                    int srcl = (((quad * 2 + (t >> 1)) & 3) << 4) | mr;
                    unsigned r0 = (unsigned)__shfl((int)dpk[2 * c][t & 1], srcl, 64);
                    unsigned r1 = (unsigned)__shfl((int)dpk[2 * c + 1][t & 1], srcl, 64);
                    afu.u[t] = (quad & 2) ? r1 : r0;
                }
                #pragma unroll
                for (int dt = 0; dt < 2; dt++) {
                    v8s bv = *(const v8s*)&Vt[dt * 16 + mr][c * 32 + quad * 8];
                    oacc[tt][dt] = __builtin_amdgcn_mfma_f32_16x16x32_bf16(
                        afu.s8, bv, oacc[tt][dt], 0, 0, 0);
                }
            }
        }
        __syncthreads();
    }
    #pragma unroll
    for (int tt = 0; tt < 2; tt++) {
        float il = 1.f / l_r[tt];
        #pragma unroll
        for (int r = 0; r < 4; r++) {
            float ilr = __shfl(il, quad * 4 + r, 64);
            int m = (wave * 2 + tt) * 16 + quad * 4 + r;
            int tok = toks[m];
            #pragma unroll
            for (int dt = 0; dt < 2; dt++) {
                int d = dt * 16 + mr;
                if (d >= HD) continue;
                outb[(brow + tok) * KP1 + hh * HD + d] =
                    __float2bfloat16(oacc[tt][dt][r] * ilr);
            }
        }
    }
}

// ---------------- Fused LN1 + ATD softmax/argmax (4 rows/block) ------------
// x read dtype-flex from raw d_in[0]; atd consumes ln1's fp32 registers.
__global__ __launch_bounds__(256) void ln_atd_kernel(const void* __restrict__ xraw,
        const int* __restrict__ flag,
        const float* __restrict__ g, const float* __restrict__ be,
        bf16* __restrict__ outb,
        const float* __restrict__ wq, const float* __restrict__ wqb,
        const float* __restrict__ scale_p, const float* __restrict__ kkn,
        bf16* __restrict__ Pout, int* __restrict__ tk_id)
{
    int row = blockIdx.x * 4 + (threadIdx.x >> 6);
    int b = row >> 12;
    int t = threadIdx.x & 63;
    int isf = *flag;
    size_t rb = (size_t)row * CDIM;
    const float* xf = (const float*)xraw + rb;
    const bf16*  xb = (const bf16*)xraw + rb;
    float v0 = isf ? xf[t]       : __bfloat162float(xb[t]);
    float v1 = isf ? xf[t + 64]  : __bfloat162float(xb[t + 64]);
    float v2 = (t < CDIM - 128)
             ? (isf ? xf[t + 128] : __bfloat162float(xb[t + 128])) : 0.f;
    float s1 = wave_sum(v0 + v1 + v2);
    float s2 = wave_sum(v0*v0 + v1*v1 + v2*v2);
    float mu = s1 / (float)CDIM;
    float var = s2 / (float)CDIM - mu * mu;
    float rs = rsqrtf(var + 1e-5f);
    float o0 = (v0 - mu) * rs * g[t]      + be[t];
    float o1 = (v1 - mu) * rs * g[t + 64] + be[t + 64];
    float o2 = (t < CDIM - 128) ? ((v2 - mu) * rs * g[t + 128] + be[t + 128]) : 0.f;
    bf16* ob = outb + (size_t)row * KP1;
    ob[t]       = __float2bfloat16(o0);
    ob[t + 64]  = __float2bfloat16(o1);
    ob[t + 128] = __float2bfloat16(o2);   // cols 180..191 get 0 (t>=52 -> o2=0)
    // ---- ATD on the same fp32 values (o0..o2 == xn row) ----
    float sq[RD];
    #pragma unroll
    for (int j = 0; j < RD; j++) {
        float part = o0 * wq[t * RD + j] + o1 * wq[(t + 64) * RD + j];
        if (t < CDIM - 128) part += o2 * wq[(t + 128) * RD + j];
        sq[j] = wave_sum(part) + wqb[j];
    }
    float qn = 0.f;
    #pragma unroll
    for (int j = 0; j < RD; j++) qn += sq[j] * sq[j];
    qn = fmaxf(sqrtf(qn), 1e-12f);
    float ls = 1.0f + fminf(fmaxf(scale_p[0], 0.f), 3.f) * 4.158883083359672f;
    const float* kr = kkn + ((size_t)b * MDICT + t) * RD;
    float s = 0.f;
    #pragma unroll
    for (int j = 0; j < RD; j++) s += sq[j] * kr[j];
    s = s / qn * ls;
    float mv = s; int mi = t;
    #pragma unroll
    for (int off = 32; off > 0; off >>= 1) {
        float ov = __shfl_xor(mv, off, 64);
        int   oi = __shfl_xor(mi, off, 64);
        if (ov > mv || (ov == mv && oi < mi)) { mv = ov; mi = oi; }
    }
    float e = __expf(s - mv);
    float denom = wave_sum(e);
    Pout[(size_t)row * MDICT + t] = __float2bfloat16(e / denom);
    if (t == 0) tk_id[row] = mi;
}

// ---------------- LayerNorm (bf16 KP1 out only) ----------------------------
__global__ __launch_bounds__(256) void ln_kernel(const float* __restrict__ x,
        const float* __restrict__ g, const float* __restrict__ be,
        bf16* __restrict__ outb)
{
    int row = blockIdx.x * 4 + (threadIdx.x >> 6);
    int t = threadIdx.x & 63;
    const float* xr = x + (size_t)row * CDIM;
    float v0 = xr[t];
    float v1 = xr[t + 64];
    float v2 = (t < CDIM - 128) ? xr[t + 128] : 0.f;
    float s1 = wave_sum(v0 + v1 + v2);
    float s2 = wave_sum(v0*v0 + v1*v1 + v2*v2);
    float mu = s1 / (float)CDIM;
    float var = s2 / (float)CDIM - mu * mu;
    float rs = rsqrtf(var + 1e-5f);
    float o0 = (v0 - mu) * rs * g[t]      + be[t];
    float o1 = (v1 - mu) * rs * g[t + 64] + be[t + 64];
    float o2 = (t < CDIM - 128) ? ((v2 - mu) * rs * g[t + 128] + be[t + 128]) : 0.f;
    bf16* ob = outb + (size_t)row * KP1;
    ob[t]       = __float2bfloat16(o0);
    ob[t + 64]  = __float2bfloat16(o1);
    ob[t + 128] = __float2bfloat16(o2);   // cols 180..191 get 0 (t>=52 -> o2=0)
}

// ---------------- Dictionary precompute: kkn (l2), vvT bf16, td_proj -------
__global__ __launch_bounds__(64) void td_pre_kernel(const float* __restrict__ td,
        const float* __restrict__ wk, const float* __restrict__ wkb,
        const float* __restrict__ wv, const float* __restrict__ wvb,
        const float* __restrict__ wtd, const float* __restrict__ wtdb,
        float* __restrict__ kkn, bf16* __restrict__ vvT, float* __restrict__ tdp)
{
    int blk = blockIdx.x;   // b*64 + m
    int b = blk >> 6, m = blk & 63;
    int t = threadIdx.x;
    __shared__ float tr[CDIM];
    __shared__ float sk[RD];
    __shared__ float snorm;
    const float* tdr = td + (size_t)blk * CDIM;
    tr[t] = tdr[t]; tr[t + 64] = tdr[t + 64];
    if (t < CDIM - 128) tr[t + 128] = tdr[t + 128];
    __syncthreads();
    if (t < RD) {
        float s = wkb[t];
        for (int k = 0; k < CDIM; k++) s += tr[k] * wk[k * RD + t];
        sk[t] = s;
    }
    __syncthreads();
    if (t == 0) {
        float s = 0.f;
        #pragma unroll
        for (int j = 0; j < RD; j++) s += sk[j] * sk[j];
        snorm = fmaxf(sqrtf(s), 1e-12f);
    }
    __syncthreads();
    if (t < RD) kkn[(size_t)blk * RD + t] = sk[t] / snorm;
    // vvT[b][c][m] bf16, c padded to 192 (tail rows zero)
    for (int c = t; c < 192; c += 64) {
        float s = 0.f;
        if (c < CDIM) {
            s = wvb[c];
            for (int k = 0; k < CDIM; k++) s += tr[k] * wv[k * CDIM + c];
        }
        vvT[((size_t)(b * 192 + c)) * MDICT + m] = __float2bfloat16(s);
    }
    {
        float s = wtdb[t];
        for (int k = 0; k < CDIM; k++) s += tr[k] * wtd[k * DTD + t];
        tdp[(size_t)blk * DTD + t] = s;
    }
}

// ---------------- Stable counting sort of tk_id ----------------------------
__global__ __launch_bounds__(256) void sort_kernel(const int* __restrict__ tk_id,
                                                   int* __restrict__ sidx)
{
    int b = blockIdx.x; int tid = threadIdx.x;
    __shared__ int keys[NTOK];
    __shared__ int cnt[256];
    __shared__ int off[256];
    const int* kb = tk_id + (size_t)b * NTOK;
    for (int i = tid; i < NTOK; i += 256) keys[i] = kb[i];
    __syncthreads();
    int v = tid >> 2, seg = tid & 3;
    int lo = seg * 1024, hi = lo + 1024;
    int c = 0;
    for (int i = lo; i < hi; i++) c += (keys[i] == v);
    cnt[tid] = c;
    __syncthreads();
    if (tid == 0) {
        int run = 0;
        for (int l = 0; l < 256; l++) { off[l] = run; run += cnt[l]; }
    }
    __syncthreads();
    int o = off[tid];
    int* sb = sidx + (size_t)b * NTOK;
    for (int i = lo; i < hi; i++) if (keys[i] == v) sb[o++] = i;
}

// ---------------- Gather dictionary features into hc[:, 360:424] -----------
__global__ __launch_bounds__(256) void gather_td_kernel(const int* __restrict__ tk_id,
        const float* __restrict__ tdp, float* __restrict__ hc)
{
    int idx = blockIdx.x * 256 + threadIdx.x;
    int row = idx >> 6, j = idx & 63;
    int b = row >> 12;
    int tk = tk_id[row];
    hc[(size_t)row * CCAT + MHID + j] = tdp[((size_t)b * MDICT + tk) * DTD + j];
}

// ---------------- Depthwise 5x5 conv: CHK=64, 8x8 tile, bf16 KP2 out -------
// R15 VERBATIM (proven 6x: ~98us, VGPR 68, conflicts 0, writes ideal).
#define CHK3 64
#define CTW  8
#define CTH  8
#define CHW  12     // halo width/height = tile + 4
#define CHP  144    // 12*12 halo pixels
#define CSPX 68     // floats per pixel row (64 + 4 pad) = 272B, 16B-aligned
__global__ __launch_bounds__(256) void conv_kernel(const float* __restrict__ hc,
        const float* __restrict__ w, const float* __restrict__ wb,
        bf16* __restrict__ outb)
{
    int ch0 = blockIdx.x * CHK3;        // 0,64,...,384 (7 blocks; 424..447 zeroed)
    int tile = blockIdx.y;              // 64 tiles of 8x8
    int b = blockIdx.z;
    int ty0 = (tile >> 3) * CTH, tx0 = (tile & 7) * CTW;
    __shared__ __align__(16) float sh[CHP][CSPX];   // 39168 B
    __shared__ __align__(16) float wt[25][CHK3];    // 6400 B
    int tid = threadIdx.x;
    // stage input: lanes cover 64 contiguous channels of one pixel (256B)
    for (int idx = tid; idx < CHP * CHK3; idx += 256) {
        int pix = idx >> 6, ch = idx & 63;
        int gy = ty0 + pix / CHW - 2, gx = tx0 + pix % CHW - 2;
        int chg = ch0 + ch;
        float v = 0.f;
        if (gy >= 0 && gy < 64 && gx >= 0 && gx < 64 && chg < CCAT)
            v = hc[((size_t)b * NTOK + gy * 64 + gx) * CCAT + chg];
        sh[pix][ch] = v;
    }
    for (int idx = tid; idx < 25 * CHK3; idx += 256) {
        int kk = idx >> 6, ch = idx & 63;
        int chg = ch0 + ch;
        wt[kk][ch] = (chg < CCAT) ? w[chg * 25 + kk] : 0.f;
    }
    __syncthreads();
    int q = tid & 3, p = tid >> 2;      // p: pixel 0..63; q: 16-ch subgroup
    int px = p & 7, py = p >> 3;
    int cb = q * 16;
    int pc = py * CHW + px;             // top-left of 5x5 window
    v8s pk0, pk1;
    #pragma unroll
    for (int sub = 0; sub < 4; sub++) {
        int cs = cb + sub * 4;
        f32x4 acc = {0.f, 0.f, 0.f, 0.f};
        #pragma unroll
        for (int dy = 0; dy < 5; dy++) {
            #pragma unroll
            for (int dx = 0; dx < 5; dx++) {
                f32x4 sv = *(const f32x4*)&sh[pc + dy * CHW + dx][cs];
                f32x4 wv = *(const f32x4*)&wt[dy * 5 + dx][cs];
                acc += sv * wv;
            }
            __builtin_amdgcn_sched_barrier(0);   // cap hoisting at one row
        }
        f32x4 ctr = *(const f32x4*)&sh[pc + 2 * CHW + 2][cs];
        #pragma unroll
        for (int c = 0; c < 4; c++) {
            int chg = ch0 + cs + c;
            float v = 0.f;
            if (chg < CCAT) {
                float gv = gelu_exact(acc[c] + wb[chg]);
                v = ctr[c] + gv;
            }
            int lc = sub * 4 + c;
            if (lc < 8) pk0[lc] = (short)f2b(v);
            else        pk1[lc - 8] = (short)f2b(v);
        }
        __builtin_amdgcn_sched_barrier(0);
    }
    size_t obase = ((size_t)b * NTOK + (ty0 + py) * 64 + tx0 + px) * KP2 + ch0 + cb;
    unsigned short* ob = (unsigned short*)outb + obase;   // 32B-aligned
    *(v8s*)ob = pk0;
    *(v8s*)(ob + 8) = pk1;
}

// ---------------------------------------------------------------------------
extern "C" void kernel_launch(void* const* d_in, const int* in_sizes, int n_in,
                              void* d_out, int out_size, void* d_ws, size_t ws_size,
                              hipStream_t stream)
{
    (void)n_in; (void)ws_size; (void)out_size;
    const int* rpi = (const int*)d_in[28];

    // ---- workspace carve-up ----
    float* p = (float*)d_ws;
    float* xn    = p; p += (size_t)ROWS * CDIM;    // tmp2b bf16 lives here
    float* acc   = p; p += (size_t)ROWS * CDIM;
    float* tmp1  = p; p += (size_t)ROWS * CDIM;    // alias: P bf16 (head)
    float* qkv   = p; p += (size_t)ROWS * C3;      // alias: qkvb bf16; hc fp32 post-win
    float* hcnew = p; p += (size_t)ROWS * CCAT;    // alias: xnb/tmp1b; then conv bf16 out
    float* kkn   = p; p += (size_t)BB * MDICT * RD;
    bf16*  vvT   = (bf16*)p; p += (size_t)BB * 192 * MDICT / 2;   // bf16 [8][192][64]
    float* tdp   = p; p += (size_t)BB * MDICT * DTD;
    int*   tk_id = (int*)p; p += ROWS;
    int*   sidx  = (int*)p; p += ROWS;
    int*   flag  = (int*)p; p += 64;
    int*   diag  = (int*)p; p += 64;
    bf16* wtqkv  = (bf16*)p; p += 576 * KP1 / 2;
    bf16* wtcomb = (bf16*)p; p += 192 * 384 / 2;   // [192][384]: aca | win halves
    bf16* wtfc1  = (bf16*)p; p += 384 * KP1 / 2;
    bf16* wtfc2  = (bf16*)p; p += 192 * KP2 / 2;
    float* cin[28];
    for (int i = 0; i < 28; i++) { cin[i] = p; p += in_sizes[i]; }
    float* bias_t = p; p += (size_t)NHEADS * WIN_N * WIN_N;   // 1.5 MB

    float* hc      = qkv;                // fp32 [ROWS,CCAT]; born after win (qkv dead)
    bf16*  qkvb    = (bf16*)qkv;         // bf16 [ROWS,576] padded; dies at win
    bf16*  xnb     = (bf16*)hcnew;                            // [ROWS,KP1]; dies at fc1
    bf16*  tmp1b   = (bf16*)(hcnew + (size_t)ROWS * KP1 / 2); // [ROWS,KP1]; win out
    bf16*  tmp2b   = (bf16*)xn;          // [ROWS,KP1] bf16; acmsa out (xn region)
    bf16*  hcnewb2 = (bf16*)hcnew;       // [ROWS,KP2] bf16; born at conv
    bf16*  Pbuf    = (bf16*)tmp1;        // [ROWS,64] bf16; alive until mega-gemm

    // ---- dtype detect (+diag=0) + batched input normalize to fp32 ----
    detect_kernel<<<1, 256, 0, stream>>>(d_in[0], flag, diag);
    {
        CvtArgs ca;
        int total = 0, s = 0;
        for (int i = 0; i < 28; i++) {
            if (i == 0 || i == 4 || i == 13 || i == 16 || i == 20 || i == 24) continue;
            ca.src[s] = d_in[i];
            ca.dst[s] = cin[i];
            ca.cum[s] = total;
            total += in_sizes[i];
            s++;
        }
        ca.cum[s] = total;
        convert_all_kernel<<<(total + 255) / 256, 256, 0, stream>>>(ca, total, flag);
    }
    const float *td = cin[1], *n1g = cin[2], *n1b = cin[3],
        *wqkv_b = cin[5], *wq_w = cin[6], *wq_b = cin[7],
        *wk_w = cin[8], *wk_b = cin[9], *wv_w = cin[10], *wv_b = cin[11],
        *atd_scale = cin[12], *aca_b = cin[14], *win_rpb = cin[15],
        *winp_b = cin[17], *fctd_w = cin[18], *fctd_b = cin[19],
        *fc1_b = cin[21], *dw_w = cin[22], *dw_b = cin[23], *fc2_b = cin[25],
        *n2g = cin[26], *n2b = cin[27];

    // ---- adaptive weight repacks (by value) + bias table ----
    packW_kernel<<<576 * KP1 / 256, 256, 0, stream>>>(d_in[4],  wtqkv, CDIM, C3,   KP1, KP1, 0,   576 * KP1, flag);
    packW_kernel<<<192 * KP1 / 256, 256, 0, stream>>>(d_in[13], wtcomb, CDIM, CDIM, KP1, 384, 0,   192 * KP1, flag);
    packW_kernel<<<192 * KP1 / 256, 256, 0, stream>>>(d_in[16], wtcomb, CDIM, CDIM, KP1, 384, 192, 192 * KP1, flag);
    packW_kernel<<<384 * KP1 / 256, 256, 0, stream>>>(d_in[20], wtfc1, CDIM, MHID, KP1, KP1, 0,   384 * KP1, flag);
    packW_kernel<<<192 * KP2 / 256, 256, 0, stream>>>(d_in[24], wtfc2, CCAT, CDIM, KP2, KP2, 0,   192 * KP2, flag);
    bias_pre_kernel<<<NHEADS * WIN_N * WIN_N / 256, 256, 0, stream>>>(rpi, win_rpb, bias_t);

    td_pre_kernel<<<BB * MDICT, 64, 0, stream>>>(td, wk_w, wk_b, wv_w, wv_b,
                                                 fctd_w, fctd_b, kkn, vvT, tdp);
    // Fused LN1 + ATD (x dtype-flex): xnb bf16 + P + tk_id in one pass
    ln_atd_kernel<<<ROWS / 4, 256, 0, stream>>>(d_in[0], flag, n1g, n1b, xnb,
                                                wq_w, wq_b, atd_scale, kkn, Pbuf, tk_id);
    // qkv gemm: bf16 padded output (Q pre-scaled)
    mgemm_kernel<false, false, true, 1><<<dim3(9, ROWS / 128), 256, 0, stream>>>(
        xnb, KP1, wtqkv, KP1, wqkv_b, nullptr, 0, (float*)qkvb, QKVP, C3, KP1,
        nullptr, nullptr, nullptr, nullptr, nullptr, nullptr, nullptr);
    // merged zeroing: tmp1b/tmp2b K-tails + qkvb pad slots
    zero_aux_kernel<<<ROWS * 60 / 256, 256, 0, stream>>>(tmp1b, tmp2b, qkvb);
    sort_kernel<<<BB, 256, 0, stream>>>(tk_id, sidx);
    // MFMA flash AC_MSA -> tmp2b (bf16 direct)
    acmsa_mfma_kernel<<<dim3(NG * NHEADS, BB), 256, 0, stream>>>(qkvb, sidx, tmp2b);
    // MFMA flash window attention -> tmp1b (bf16 direct)
    win_mfma_kernel<<<dim3(16 * NHEADS, BB), 256, 0, stream>>>(qkvb, bias_t, tmp1b);
    // mega-gemm K=448: acc = tmp2b@Waca + tmp1b@Wwin + P@vvT[bz]
    //                 + (aca_b+winp_b) + x   (av pass absorbed)
    mgemm_kernel<false, false, true, 3><<<dim3(3, ROWS / 128), 256, 0, stream>>>(
        tmp2b, KP1, wtcomb, 384, aca_b, nullptr, 0, acc, CDIM, CDIM, KP2,
        nullptr, tmp1b, winp_b, Pbuf, vvT, d_in[0], flag);
    // FFN: LN2 (bf16 out only) -> fc1 -> gather -> conv -> fc2 (emit fused)
    ln_kernel<<<ROWS / 4, 256, 0, stream>>>(acc, n2g, n2b, xnb);
    mgemm_kernel<true, false, true, 0><<<dim3(6, ROWS / 128), 256, 0, stream>>>(
        xnb, KP1, wtfc1, KP1, fc1_b, nullptr, 0, hc, CCAT, MHID, KP1,
        nullptr, nullptr, nullptr, nullptr, nullptr, nullptr, nullptr);
    gather_td_kernel<<<ROWS * 64 / 256, 256, 0, stream>>>(tk_id, tdp, hc);
    conv_kernel<<<dim3(7, 64, BB), 256, 0, stream>>>(hc, dw_w, dw_b, hcnewb2);
    // fc2: res=acc, NaN scan -> diag, dtype-flex store DIRECT to d_out
    mgemm_kernel<false, true, true, 2><<<dim3(3, ROWS / 128), 256, 0, stream>>>(
        hcnewb2, KP2, wtfc2, KP2, fc2_b, acc, CDIM, (float*)d_out, CDIM, CDIM, KP2,
        diag, nullptr, nullptr, nullptr, nullptr, nullptr, flag);
    // NaN patch (all-or-nothing semantics); early-exits when diag==0
    nan_patch_kernel<<<1, 256, 0, stream>>>(d_out, flag, diag);
}

// Round 15
// 605.104 us; speedup vs baseline: 1.2453x; 1.0715x over previous
//
#include <hip/hip_runtime.h>
#include <hip/hip_bf16.h>
#include <math.h>

// MPv2_3d_arch: B=8, n=64*64=4096, c=180, heads=6 (hd=30), dict M=64, rd=10,
// dtd=64, mlp_hid=360, cat C=424, window 16x16, groups of 128.
// R26: R25 (passing, 648us) + three numerics-identical cleanups:
// (a) zero_aux folded into ln_atd (per-row tail/pad zeroing by lane t;
//     deletes a 7680-block launch; ordering preserved);
// (b) conv staging vectorized f32x4 (9 b128 loads+writes vs 36 scalar;
//     R16/R20-proven pattern; compute loop = R15 verbatim, proven 7x);
// (c) acmsa dead duplicated MFMA removed (R25 artifact).
// SESSION RULE: input dtype VARIES per run (bf16 or fp32) — every d_in
// access must go through *flag (by value). Raw-bit reads = NaN.
#define BB      8
#define NTOK    4096
#define CDIM    180
#define C3      540
#define NHEADS  6
#define HD      30
#define MDICT   64
#define RD      10
#define DTD     64
#define MHID    360
#define CCAT    424
#define WS      16
#define WIN_N   256
#define GS      128
#define NG      32
#define ROWS    (BB*NTOK)   // 32768
#define KP1     192         // Kpad for K=180
#define KP2     448         // Kpad for K=424
#define QKVP    576         // padded qkv row: 3 sec * 6 heads * 32

typedef __hip_bfloat16 bf16;
typedef short v8s __attribute__((ext_vector_type(8)));
typedef float f32x4 __attribute__((ext_vector_type(4)));
typedef unsigned int u32x4 __attribute__((ext_vector_type(4)));

__device__ __forceinline__ float gelu_exact(float x) {
    return 0.5f * x * (1.0f + erff(x * 0.70710678118654752f));
}
__device__ __forceinline__ float wave_sum(float v) {
    #pragma unroll
    for (int off = 32; off > 0; off >>= 1) v += __shfl_xor(v, off, 64);
    return v;
}
// fp32 <-> bf16 bits without type-punning (RNE)
__device__ __forceinline__ unsigned short f2b(float v) {
    unsigned u = __float_as_uint(v);
    return (unsigned short)((u + 0x7FFFu + ((u >> 16) & 1u)) >> 16);
}
__device__ __forceinline__ float b2f(unsigned short h) {
    return __uint_as_float(((unsigned)h) << 16);
}
__device__ __forceinline__ unsigned packbf(float lo, float hi) {
    return (unsigned)f2b(lo) | ((unsigned)f2b(hi) << 16);
}
// async global->LDS 16B (gfx950); size must be literal; lds addr = per-lane
// slot in lane-order-contiguous slab (wave-uniform base + lane*16).
__device__ __forceinline__ void gload16(const void* g, void* l) {
    __builtin_amdgcn_global_load_lds(
        (const __attribute__((address_space(1))) void*)g,
        (__attribute__((address_space(3))) void*)l, 16, 0, 0);
}

// ---------------- dtype detector: flag=1 if inputs are fp32, 0 if bf16 -----
__global__ __launch_bounds__(256) void detect_kernel(const void* __restrict__ x,
                                                     int* __restrict__ flag,
                                                     int* __restrict__ diag)
{
    __shared__ int cnt;
    if (threadIdx.x == 0) { cnt = 0; *diag = 0; }
    __syncthreads();
    const unsigned short* u = (const unsigned short*)x;
    int c = 0;
    for (int i = threadIdx.x; i < 2048; i += 256) {
        unsigned short e = u[2 * i] & 0x7F80;
        if (e >= 0x4300) c++;
    }
    atomicAdd(&cnt, c);
    __syncthreads();
    if (threadIdx.x == 0) *flag = (cnt > 16) ? 1 : 0;
}

// ---------------- batched dtype-flexible input -> fp32 conversion ----------
#define NCVT 23
struct CvtArgs {
    const void* src[NCVT];
    float* dst[NCVT];
    int cum[NCVT + 1];
};
__global__ __launch_bounds__(256) void convert_all_kernel(CvtArgs a, int total,
        const int* __restrict__ flag)
{
    int i = blockIdx.x * 256 + threadIdx.x;
    if (i >= total) return;
    int s = 0;
    while (i >= a.cum[s + 1]) s++;
    int off = i - a.cum[s];
    if (*flag) a.dst[s][off] = ((const float*)a.src[s])[off];
    else       a.dst[s][off] = __bfloat162float(((const bf16*)a.src[s])[off]);
}

// ---------------- NaN patch: if diag set, overwrite d_out with stage code --
// 1 block; early-exits when diag==0 (passing path ~launch cost only).
__global__ __launch_bounds__(256) void nan_patch_kernel(void* __restrict__ out,
        const int* __restrict__ flag, const int* __restrict__ diag)
{
    int d = *diag;
    if (!d) return;
    float v = 100.f + 32.f * (float)d;
    int isf = *flag;
    for (size_t i = threadIdx.x; i < (size_t)ROWS * CDIM; i += 256) {
        if (isf) ((float*)out)[i] = v;
        else     ((bf16*)out)[i]  = __float2bfloat16(v);
    }
}

// -------- adaptive weight repack: W[K,N] -> Wt[n*ldw + koff + k] bf16 ------
__global__ __launch_bounds__(256) void packW_kernel(const void* __restrict__ W,
        bf16* __restrict__ Wt, int K, int N, int Kpad, int ldw, int koff,
        int total, const int* __restrict__ flag)
{
    int idx = blockIdx.x * 256 + threadIdx.x;
    if (idx >= total) return;
    int n = idx / Kpad, k = idx % Kpad;
    float v = 0.f;
    if (k < K && n < N) {
        size_t src = (size_t)k * N + n;
        v = (*flag) ? ((const float*)W)[src]
                    : __bfloat162float(((const bf16*)W)[src]);
    }
    Wt[(size_t)n * ldw + koff + k] = __float2bfloat16(v);
}

// ---------------- window-attention bias table: [6][256][256] ---------------
__global__ __launch_bounds__(256) void bias_pre_kernel(const int* __restrict__ rpi,
        const float* __restrict__ rpb, float* __restrict__ bias_t)
{
    int idx = blockIdx.x * 256 + threadIdx.x;   // 6*65536
    int h = idx >> 16, ij = idx & 65535;
    bias_t[idx] = rpb[rpi[ij] * NHEADS + h];
}

// ---------------- MFMA GEMM: out = act(A@W [+bias]) [+ res] ----------------
// R18 structure: 128(M)x64(N) tile, 256 threads, global_load_lds staging,
// 8 MFMA/k-step/wave. OM=1: bf16 out to padded qkv layout (Q pre-scaled).
// OM=2: res=acc + NaN scan + dtype-flex store to d_out (emit fused).
// OM=3: triple-A mega (k<192: A=tmp2b; 192..383: A2=tmp1b; 384..447:
// A3=Pbuf with per-batch W2=vvT[bz]); bias+bias2; + dtype-flex x residual.
template<bool GELU_, bool ADDRES, bool BIAS_, int OM>
__global__ __launch_bounds__(256) void mgemm_kernel(
        const bf16* __restrict__ A, int lda,
        const bf16* __restrict__ Wt, int ldw,
        const float* __restrict__ bias,
        const float* __restrict__ res, int ldr,
        float* __restrict__ outF, int ldo, int N, int K,
        int* __restrict__ diag,
        const bf16* __restrict__ A2, const float* __restrict__ bias2,
        const bf16* __restrict__ A3, const bf16* __restrict__ W2,
        const void* __restrict__ xraw, const int* __restrict__ flagp)
{
    __shared__ __align__(16) unsigned short As[128][32];   // 8 KB
    __shared__ __align__(16) unsigned short Bs[64][32];    // 4 KB
    int tid = threadIdx.x;
    int wave = tid >> 6, lane = tid & 63;
    int quad = lane >> 4, mr = lane & 15;
    int row0 = blockIdx.y * 128, col0 = blockIdx.x * 64;
    int bz = row0 >> 12;                     // batch (rows 4096-aligned)
    int ar = tid >> 2, ac = (tid & 3) * 8;   // LDS slot byte off = tid*16
    int isf = (OM == 2 || OM == 3) ? *flagp : 0;
    f32x4 z = {0.f, 0.f, 0.f, 0.f};
    f32x4 acc[2][4] = {{z, z, z, z}, {z, z, z, z}};
    const unsigned short* Au = (const unsigned short*)A;
    const unsigned short* A2u = (const unsigned short*)A2;
    const unsigned short* A3u = (const unsigned short*)A3;
    const unsigned short* Wu = (const unsigned short*)Wt;
    for (int k0 = 0; k0 < K; k0 += 32) {
        const unsigned short* Asel = Au;
        int kk = k0, ldA = lda;
        if (OM == 3) {
            if (k0 >= 384)      { Asel = A3u; kk = k0 - 384; ldA = MDICT; }
            else if (k0 >= KP1) { Asel = A2u; kk = k0 - KP1; ldA = KP1;   }
        }
        gload16(&Asel[(size_t)(row0 + ar) * ldA + kk + ac],      &As[ar][ac]);
        gload16(&Asel[(size_t)(row0 + 64 + ar) * ldA + kk + ac], &As[64 + ar][ac]);
        if (OM == 3 && k0 >= 384) {
            const unsigned short* Wu2 =
                (const unsigned short*)W2 + (size_t)bz * 192 * MDICT;
            gload16(&Wu2[(size_t)(col0 + ar) * MDICT + (k0 - 384) + ac], &Bs[ar][ac]);
        } else {
            gload16(&Wu[(size_t)(col0 + ar) * ldw + k0 + ac], &Bs[ar][ac]);
        }
        __syncthreads();   // compiler emits vmcnt(0) drain before barrier
        v8s bfr[4];
        #pragma unroll
        for (int ni = 0; ni < 4; ni++)
            bfr[ni] = *(const v8s*)&Bs[ni * 16 + mr][quad * 8];
        #pragma unroll
        for (int s = 0; s < 2; s++) {
            v8s a = *(const v8s*)&As[wave * 32 + s * 16 + mr][quad * 8];
            #pragma unroll
            for (int ni = 0; ni < 4; ni++)
                acc[s][ni] = __builtin_amdgcn_mfma_f32_16x16x32_bf16(
                    a, bfr[ni], acc[s][ni], 0, 0, 0);
        }
        __syncthreads();
    }
    if (OM == 1) {
        bf16* outb = (bf16*)outF;
        #pragma unroll
        for (int ni = 0; ni < 4; ni++) {
            int gc = col0 + ni * 16 + mr;
            if (gc >= N) continue;
            float bv = bias[gc];
            int sec = gc / 180, rem = gc - sec * 180;
            int hh = rem / 30, d = rem - hh * 30;
            int slot = sec * 192 + hh * 32 + d;
            float sc = (sec == 0) ? 0.18257418583505536f : 1.f;
            #pragma unroll
            for (int s = 0; s < 2; s++) {
                #pragma unroll
                for (int r = 0; r < 4; r++) {
                    int gr = row0 + wave * 32 + s * 16 + quad * 4 + r;
                    outb[(size_t)gr * QKVP + slot] =
                        __float2bfloat16((acc[s][ni][r] + bv) * sc);
                }
            }
        }
        return;
    }
    #pragma unroll
    for (int ni = 0; ni < 4; ni++) {
        int gc = col0 + ni * 16 + mr;
        if (gc >= N) continue;
        float bv = BIAS_ ? bias[gc] : 0.f;
        if (OM == 3) bv += bias2[gc];
        #pragma unroll
        for (int s = 0; s < 2; s++) {
            #pragma unroll
            for (int r = 0; r < 4; r++) {
                int gr = row0 + wave * 32 + s * 16 + quad * 4 + r;
                size_t off = (size_t)gr * ldo + gc;
                float v = acc[s][ni][r] + bv;
                if (GELU_) v = gelu_exact(v);
                if (ADDRES) v += res[(size_t)gr * ldr + gc];
                if (OM == 3) {
                    size_t xo = (size_t)gr * CDIM + gc;
                    float xv = isf ? ((const float*)xraw)[xo]
                                   : __bfloat162float(((const bf16*)xraw)[xo]);
                    v += xv;
                }
                if (OM == 2) {
                    unsigned u = __float_as_uint(v);
                    if ((u & 0x7F800000u) == 0x7F800000u) atomicOr(diag, 8);
                    if (isf) ((float*)outF)[off] = v;
                    else     ((bf16*)outF)[off]  = __float2bfloat16(v);
                } else {
                    outF[off] = v;
                }
            }
        }
    }
}

// ---------------- Window attention, MFMA flash (bf16 KP1 out) --------------
// R12 structure + R19 bf16-qkv input: Q/K/V loaded as aligned v8s from the
// padded [ROWS][576] layout (Q pre-scaled, pads zero) — no f2b at load.
__global__ __launch_bounds__(256, 4) void win_mfma_kernel(const bf16* __restrict__ qkvb,
        const float* __restrict__ bias_t, bf16* __restrict__ outb)
{
    int b = blockIdx.y;
    int widx = blockIdx.x / NHEADS;
    int hh = blockIdx.x % NHEADS;
    int wy = widx >> 2, wx = widx & 3;
    int tid = threadIdx.x;
    int wave = tid >> 6, lane = tid & 63, quad = lane >> 4, mr = lane & 15;
    __shared__ __align__(16) unsigned short Ks[64][40];
    __shared__ __align__(16) unsigned short Vt[32][80];

    size_t brow = (size_t)b * NTOK;
    const unsigned short* qu = (const unsigned short*)qkvb;

    v8s aq[4];
    #pragma unroll
    for (int tt = 0; tt < 4; tt++) {
        int m = (wave * 4 + tt) * 16 + mr;
        int nt_ = (wy * WS + (m >> 4)) * 64 + wx * WS + (m & 15);
        aq[tt] = *(const v8s*)&qu[(brow + nt_) * QKVP + hh * 32 + quad * 8];
    }
    f32x4 z = {0.f, 0.f, 0.f, 0.f};
    f32x4 oacc[4][2] = {{z, z}, {z, z}, {z, z}, {z, z}};
    float m_r[4], l_r[4];
    #pragma unroll
    for (int tt = 0; tt < 4; tt++) { m_r[tt] = -3.0e38f; l_r[tt] = 0.f; }
    const float* btab = bias_t + (size_t)hh * WIN_N * WIN_N;

    for (int kc = 0; kc < WIN_N; kc += 64) {
        {
            int j = tid >> 2, dg = (tid & 3) * 8;
            int tok = kc + j;
            int nt_ = (wy * WS + (tok >> 4)) * 64 + wx * WS + (tok & 15);
            const unsigned short* base = qu + (brow + nt_) * QKVP + hh * 32;
            v8s kv = *(const v8s*)&base[192 + dg];
            v8s vv = *(const v8s*)&base[384 + dg];
            *(v8s*)&Ks[j][dg] = kv;
            #pragma unroll
            for (int jj = 0; jj < 8; jj++)
                Vt[dg + jj][j] = (unsigned short)vv[jj];
        }
        __syncthreads();
        #pragma unroll
        for (int tt = 0; tt < 4; tt++) {
            // --- QK^T swapped: s[nt][r] = S[key=kc+nt*16+quad*4+r][query] ---
            f32x4 s[4];
            #pragma unroll
            for (int nt = 0; nt < 4; nt++) {
                v8s bk = *(const v8s*)&Ks[nt * 16 + mr][quad * 8];
                s[nt] = __builtin_amdgcn_mfma_f32_16x16x32_bf16(bk, aq[tt], z, 0, 0, 0);
            }
            int qg = (wave * 4 + tt) * 16 + mr;
            const float* bi = btab + (size_t)qg * WIN_N + kc;
            float mc = -3.0e38f;
            #pragma unroll
            for (int nt = 0; nt < 4; nt++) {
                f32x4 b4 = *(const f32x4*)(bi + nt * 16 + quad * 4);
                s[nt][0] += b4[0]; s[nt][1] += b4[1];
                s[nt][2] += b4[2]; s[nt][3] += b4[3];
                mc = fmaxf(mc, fmaxf(fmaxf(s[nt][0], s[nt][1]),
                                     fmaxf(s[nt][2], s[nt][3])));
            }
            mc = fmaxf(mc, __shfl_xor(mc, 16, 64));
            mc = fmaxf(mc, __shfl_xor(mc, 32, 64));
            float mn = fmaxf(m_r[tt], mc);
            float alpha = __expf(m_r[tt] - mn);
            m_r[tt] = mn;
            float ls = 0.f;
            #pragma unroll
            for (int nt = 0; nt < 4; nt++) {
                #pragma unroll
                for (int r = 0; r < 4; r++) {
                    float pp = __expf(s[nt][r] - mn);
                    ls += pp;
                    s[nt][r] = pp;
                }
            }
            ls += __shfl_xor(ls, 16, 64);
            ls += __shfl_xor(ls, 32, 64);
            l_r[tt] = l_r[tt] * alpha + ls;
            // --- pack P (bf16 pairs): dpk[nt][s] = keys nt*16+quad*4+{2s,2s+1}
            unsigned dpk[4][2];
            #pragma unroll
            for (int nt = 0; nt < 4; nt++) {
                dpk[nt][0] = packbf(s[nt][0], s[nt][1]);
                dpk[nt][1] = packbf(s[nt][2], s[nt][3]);
            }
            // --- rescale oacc rows (query = quad*4+r) by alpha ---
            #pragma unroll
            for (int r = 0; r < 4; r++) {
                float av = __shfl(alpha, quad * 4 + r, 64);
                oacc[tt][0][r] *= av;
                oacc[tt][1][r] *= av;
            }
            // --- PV: build A-frags via cross-lane shuffle, 2 chunks of K=32 --
            #pragma unroll
            for (int c = 0; c < 2; c++) {
                union { u32x4 u; v8s s8; } afu;
                #pragma unroll
                for (int t = 0; t < 4; t++) {
                    int srcl = (((quad * 2 + (t >> 1)) & 3) << 4) | mr;
                    unsigned r0 = (unsigned)__shfl((int)dpk[2 * c][t & 1], srcl, 64);
                    unsigned r1 = (unsigned)__shfl((int)dpk[2 * c + 1][t & 1], srcl, 64);
                    afu.u[t] = (quad & 2) ? r1 : r0;
                }
                #pragma unroll
                for (int dt = 0; dt < 2; dt++) {
                    v8s bv = *(const v8s*)&Vt[dt * 16 + mr][c * 32 + quad * 8];
                    oacc[tt][dt] = __builtin_amdgcn_mfma_f32_16x16x32_bf16(
                        afu.s8, bv, oacc[tt][dt], 0, 0, 0);
                }
            }
        }
        __syncthreads();
    }
    #pragma unroll
    for (int tt = 0; tt < 4; tt++) {
        float il = 1.f / l_r[tt];
        #pragma unroll
        for (int r = 0; r < 4; r++) {
            float ilr = __shfl(il, quad * 4 + r, 64);
            int m = (wave * 4 + tt) * 16 + quad * 4 + r;
            int nt_ = (wy * WS + (m >> 4)) * 64 + wx * WS + (m & 15);
            #pragma unroll
            for (int dt = 0; dt < 2; dt++) {
                int d = dt * 16 + mr;
                if (d >= HD) continue;
                outb[(brow + nt_) * KP1 + hh * HD + d] =
                    __float2bfloat16(oacc[tt][dt][r] * ilr);
            }
        }
    }
}

// ---------------- AC_MSA, MFMA flash, swapped QK^T -------------------------
// R17 structure + R19 bf16-qkv input (v8s loads, toks[] indirection).
__global__ __launch_bounds__(256, 4) void acmsa_mfma_kernel(const bf16* __restrict__ qkvb,
        const int* __restrict__ sidx, bf16* __restrict__ outb)
{
    int b = blockIdx.y;
    int g = blockIdx.x / NHEADS;
    int hh = blockIdx.x % NHEADS;
    int tid = threadIdx.x;
    int wave = tid >> 6, lane = tid & 63, quad = lane >> 4, mr = lane & 15;
    __shared__ int toks[GS];
    __shared__ __align__(16) unsigned short Ks[64][40];
    __shared__ __align__(16) unsigned short Vt[32][80];

    size_t brow = (size_t)b * NTOK;
    if (tid < GS) toks[tid] = sidx[brow + (size_t)g * GS + tid];
    __syncthreads();
    const unsigned short* qu = (const unsigned short*)qkvb;

    v8s aq[2];
    #pragma unroll
    for (int tt = 0; tt < 2; tt++) {
        int m = (wave * 2 + tt) * 16 + mr;
        aq[tt] = *(const v8s*)&qu[(brow + toks[m]) * QKVP + hh * 32 + quad * 8];
    }
    f32x4 z = {0.f, 0.f, 0.f, 0.f};
    f32x4 oacc[2][2] = {{z, z}, {z, z}};
    float m_r[2], l_r[2];
    #pragma unroll
    for (int tt = 0; tt < 2; tt++) { m_r[tt] = -3.0e38f; l_r[tt] = 0.f; }

    for (int kc = 0; kc < GS; kc += 64) {
        {
            int j = tid >> 2, dg = (tid & 3) * 8;
            int tok = toks[kc + j];
            const unsigned short* base = qu + (brow + tok) * QKVP + hh * 32;
            v8s kv = *(const v8s*)&base[192 + dg];
            v8s vv = *(const v8s*)&base[384 + dg];
            *(v8s*)&Ks[j][dg] = kv;
            #pragma unroll
            for (int jj = 0; jj < 8; jj++)
                Vt[dg + jj][j] = (unsigned short)vv[jj];
        }
        __syncthreads();
        #pragma unroll
        for (int tt = 0; tt < 2; tt++) {
            // --- QK^T swapped: s[nt][r] = S[key=kc+nt*16+quad*4+r][query=mr]
            f32x4 s[4];
            #pragma unroll
            for (int nt = 0; nt < 4; nt++) {
                v8s bk = *(const v8s*)&Ks[nt * 16 + mr][quad * 8];
                s[nt] = __builtin_amdgcn_mfma_f32_16x16x32_bf16(bk, aq[tt], z, 0, 0, 0);
            }
            float mc = -3.0e38f;
            #pragma unroll
            for (int nt = 0; nt < 4; nt++)
                mc = fmaxf(mc, fmaxf(fmaxf(s[nt][0], s[nt][1]),
                                     fmaxf(s[nt][2], s[nt][3])));
            mc = fmaxf(mc, __shfl_xor(mc, 16, 64));
            mc = fmaxf(mc, __shfl_xor(mc, 32, 64));
            float mn = fmaxf(m_r[tt], mc);
            float alpha = __expf(m_r[tt] - mn);
            m_r[tt] = mn;
            float ls = 0.f;
            #pragma unroll
            for (int nt = 0; nt < 4; nt++) {
                #pragma unroll
                for (int r = 0; r < 4; r++) {
                    float pp = __expf(s[nt][r] - mn);
                    ls += pp;
                    s[nt][r] = pp;
                }
            }
            ls += __shfl_xor(ls, 16, 64);
            ls += __shfl_xor(ls, 32, 64);
            l_r[tt] = l_r[tt] * alpha + ls;
            unsigned dpk[4][2];
            #pragma unroll
            for (int nt = 0; nt < 4; nt++) {
                dpk[nt][0] = packbf(s[nt][0], s[nt][1]);
                dpk[nt][1] = packbf(s[nt][2], s[nt][3]);
            }
            #pragma unroll
            for (int r = 0; r < 4; r++) {
                float av = __shfl(alpha, quad * 4 + r, 64);
                oacc[tt][0][r] *= av;
                oacc[tt][1][r] *= av;
            }
            #pragma unroll
            for (int c = 0; c < 2; c++) {
                union { u32x4 u; v8s s8; } afu;
                #pragma unroll
                for (int t = 0; t < 4; t++) {
                    int srcl = (((quad * 2 + (t >> 1)) & 3) << 4) | mr;
                    unsigned r0 = (unsigned)__shfl((int)dpk[2 * c][t & 1], srcl, 64);
                    unsigned r1 = (unsigned)__shfl((int)dpk[2 * c + 1][t & 1], srcl, 64);
                    afu.u[t] = (quad & 2) ? r1 : r0;
                }
                #pragma unroll
                for (int dt = 0; dt < 2; dt++) {
                    v8s bv = *(const v8s*)&Vt[dt * 16 + mr][c * 32 + quad * 8];
                    oacc[tt][dt] = __builtin_amdgcn_mfma_f32_16x16x32_bf16(
                        afu.s8, bv, oacc[tt][dt], 0, 0, 0);
                }
            }
        }
        __syncthreads();
    }
    #pragma unroll
    for (int tt = 0; tt < 2; tt++) {
        float il = 1.f / l_r[tt];
        #pragma unroll
        for (int r = 0; r < 4; r++) {
            float ilr = __shfl(il, quad * 4 + r, 64);
            int m = (wave * 2 + tt) * 16 + quad * 4 + r;
            int tok = toks[m];
            #pragma unroll
            for (int dt = 0; dt < 2; dt++) {
                int d = dt * 16 + mr;
                if (d >= HD) continue;
                outb[(brow + tok) * KP1 + hh * HD + d] =
                    __float2bfloat16(oacc[tt][dt][r] * ilr);
            }
        }
    }
}

// ---------------- Fused LN1 + ATD softmax/argmax (4 rows/block) ------------
// x read dtype-flex from raw d_in[0]; atd consumes ln1's fp32 registers.
// R26: absorbs zero_aux — per-row K-tail zeroing of tmp1b/tmp2b + qkvb pads.
__global__ __launch_bounds__(256) void ln_atd_kernel(const void* __restrict__ xraw,
        const int* __restrict__ flag,
        const float* __restrict__ g, const float* __restrict__ be,
        bf16* __restrict__ outb,
        const float* __restrict__ wq, const float* __restrict__ wqb,
        const float* __restrict__ scale_p, const float* __restrict__ kkn,
        bf16* __restrict__ Pout, int* __restrict__ tk_id,
        bf16* __restrict__ t1, bf16* __restrict__ t2, bf16* __restrict__ qb)
{
    int row = blockIdx.x * 4 + (threadIdx.x >> 6);
    int b = row >> 12;
    int t = threadIdx.x & 63;
    int isf = *flag;
    size_t rb = (size_t)row * CDIM;
    const float* xf = (const float*)xraw + rb;
    const bf16*  xb = (const bf16*)xraw + rb;
    float v0 = isf ? xf[t]       : __bfloat162float(xb[t]);
    float v1 = isf ? xf[t + 64]  : __bfloat162float(xb[t + 64]);
    float v2 = (t < CDIM - 128)
             ? (isf ? xf[t + 128] : __bfloat162float(xb[t + 128])) : 0.f;
    // ---- folded zero_aux: per-row tails/pads (independent writes) ----
    if (t < 12) {
        t1[(size_t)row * KP1 + CDIM + t] = __float2bfloat16(0.f);
        t2[(size_t)row * KP1 + CDIM + t] = __float2bfloat16(0.f);
    }
    if (t < 36) {
        int sec = t / 12, rr = t % 12, hh2 = rr >> 1, d2 = 30 + (rr & 1);
        qb[(size_t)row * QKVP + sec * 192 + hh2 * 32 + d2] = __float2bfloat16(0.f);
    }
    float s1 = wave_sum(v0 + v1 + v2);
    float s2 = wave_sum(v0*v0 + v1*v1 + v2*v2);
    float mu = s1 / (float)CDIM;
    float var = s2 / (float)CDIM - mu * mu;
    float rs = rsqrtf(var + 1e-5f);
    float o0 = (v0 - mu) * rs * g[t]      + be[t];
    float o1 = (v1 - mu) * rs * g[t + 64] + be[t + 64];
    float o2 = (t < CDIM - 128) ? ((v2 - mu) * rs * g[t + 128] + be[t + 128]) : 0.f;
    bf16* ob = outb + (size_t)row * KP1;
    ob[t]       = __float2bfloat16(o0);
    ob[t + 64]  = __float2bfloat16(o1);
    ob[t + 128] = __float2bfloat16(o2);   // cols 180..191 get 0 (t>=52 -> o2=0)
    // ---- ATD on the same fp32 values (o0..o2 == xn row) ----
    float sq[RD];
    #pragma unroll
    for (int j = 0; j < RD; j++) {
        float part = o0 * wq[t * RD + j] + o1 * wq[(t + 64) * RD + j];
        if (t < CDIM - 128) part += o2 * wq[(t + 128) * RD + j];
        sq[j] = wave_sum(part) + wqb[j];
    }
    float qn = 0.f;
    #pragma unroll
    for (int j = 0; j < RD; j++) qn += sq[j] * sq[j];
    qn = fmaxf(sqrtf(qn), 1e-12f);
    float ls = 1.0f + fminf(fmaxf(scale_p[0], 0.f), 3.f) * 4.158883083359672f;
    const float* kr = kkn + ((size_t)b * MDICT + t) * RD;
    float s = 0.f;
    #pragma unroll
    for (int j = 0; j < RD; j++) s += sq[j] * kr[j];
    s = s / qn * ls;
    float mv = s; int mi = t;
    #pragma unroll
    for (int off = 32; off > 0; off >>= 1) {
        float ov = __shfl_xor(mv, off, 64);
        int   oi = __shfl_xor(mi, off, 64);
        if (ov > mv || (ov == mv && oi < mi)) { mv = ov; mi = oi; }
    }
    float e = __expf(s - mv);
    float denom = wave_sum(e);
    Pout[(size_t)row * MDICT + t] = __float2bfloat16(e / denom);
    if (t == 0) tk_id[row] = mi;
}

// ---------------- LayerNorm (bf16 KP1 out only) ----------------------------
__global__ __launch_bounds__(256) void ln_kernel(const float* __restrict__ x,
        const float* __restrict__ g, const float* __restrict__ be,
        bf16* __restrict__ outb)
{
    int row = blockIdx.x * 4 + (threadIdx.x >> 6);
    int t = threadIdx.x & 63;
    const float* xr = x + (size_t)row * CDIM;
    float v0 = xr[t];
    float v1 = xr[t + 64];
    float v2 = (t < CDIM - 128) ? xr[t + 128] : 0.f;
    float s1 = wave_sum(v0 + v1 + v2);
    float s2 = wave_sum(v0*v0 + v1*v1 + v2*v2);
    float mu = s1 / (float)CDIM;
    float var = s2 / (float)CDIM - mu * mu;
    float rs = rsqrtf(var + 1e-5f);
    float o0 = (v0 - mu) * rs * g[t]      + be[t];
    float o1 = (v1 - mu) * rs * g[t + 64] + be[t + 64];
    float o2 = (t < CDIM - 128) ? ((v2 - mu) * rs * g[t + 128] + be[t + 128]) : 0.f;
    bf16* ob = outb + (size_t)row * KP1;
    ob[t]       = __float2bfloat16(o0);
    ob[t + 64]  = __float2bfloat16(o1);
    ob[t + 128] = __float2bfloat16(o2);   // cols 180..191 get 0 (t>=52 -> o2=0)
}

// ---------------- Dictionary precompute: kkn (l2), vvT bf16, td_proj -------
__global__ __launch_bounds__(64) void td_pre_kernel(const float* __restrict__ td,
        const float* __restrict__ wk, const float* __restrict__ wkb,
        const float* __restrict__ wv, const float* __restrict__ wvb,
        const float* __restrict__ wtd, const float* __restrict__ wtdb,
        float* __restrict__ kkn, bf16* __restrict__ vvT, float* __restrict__ tdp)
{
    int blk = blockIdx.x;   // b*64 + m
    int b = blk >> 6, m = blk & 63;
    int t = threadIdx.x;
    __shared__ float tr[CDIM];
    __shared__ float sk[RD];
    __shared__ float snorm;
    const float* tdr = td + (size_t)blk * CDIM;
    tr[t] = tdr[t]; tr[t + 64] = tdr[t + 64];
    if (t < CDIM - 128) tr[t + 128] = tdr[t + 128];
    __syncthreads();
    if (t < RD) {
        float s = wkb[t];
        for (int k = 0; k < CDIM; k++) s += tr[k] * wk[k * RD + t];
        sk[t] = s;
    }
    __syncthreads();
    if (t == 0) {
        float s = 0.f;
        #pragma unroll
        for (int j = 0; j < RD; j++) s += sk[j] * sk[j];
        snorm = fmaxf(sqrtf(s), 1e-12f);
    }
    __syncthreads();
    if (t < RD) kkn[(size_t)blk * RD + t] = sk[t] / snorm;
    // vvT[b][c][m] bf16, c padded to 192 (tail rows zero)
    for (int c = t; c < 192; c += 64) {
        float s = 0.f;
        if (c < CDIM) {
            s = wvb[c];
            for (int k = 0; k < CDIM; k++) s += tr[k] * wv[k * CDIM + c];
        }
        vvT[((size_t)(b * 192 + c)) * MDICT + m] = __float2bfloat16(s);
    }
    {
        float s = wtdb[t];
        for (int k = 0; k < CDIM; k++) s += tr[k] * wtd[k * DTD + t];
        tdp[(size_t)blk * DTD + t] = s;
    }
}

// ---------------- Stable counting sort of tk_id ----------------------------
__global__ __launch_bounds__(256) void sort_kernel(const int* __restrict__ tk_id,
                                                   int* __restrict__ sidx)
{
    int b = blockIdx.x; int tid = threadIdx.x;
    __shared__ int keys[NTOK];
    __shared__ int cnt[256];
    __shared__ int off[256];
    const int* kb = tk_id + (size_t)b * NTOK;
    for (int i = tid; i < NTOK; i += 256) keys[i] = kb[i];
    __syncthreads();
    int v = tid >> 2, seg = tid & 3;
    int lo = seg * 1024, hi = lo + 1024;
    int c = 0;
    for (int i = lo; i < hi; i++) c += (keys[i] == v);
    cnt[tid] = c;
    __syncthreads();
    if (tid == 0) {
        int run = 0;
        for (int l = 0; l < 256; l++) { off[l] = run; run += cnt[l]; }
    }
    __syncthreads();
    int o = off[tid];
    int* sb = sidx + (size_t)b * NTOK;
    for (int i = lo; i < hi; i++) if (keys[i] == v) sb[o++] = i;
}

// ---------------- Gather dictionary features into hc[:, 360:424] -----------
__global__ __launch_bounds__(256) void gather_td_kernel(const int* __restrict__ tk_id,
        const float* __restrict__ tdp, float* __restrict__ hc)
{
    int idx = blockIdx.x * 256 + threadIdx.x;
    int row = idx >> 6, j = idx & 63;
    int b = row >> 12;
    int tk = tk_id[row];
    hc[(size_t)row * CCAT + MHID + j] = tdp[((size_t)b * MDICT + tk) * DTD + j];
}

// ---------------- Depthwise 5x5 conv: CHK=64, 8x8 tile, bf16 KP2 out -------
// R15 compute VERBATIM (proven 7x: ~98us, VGPR 68, conflicts 0, writes
// ideal). R26: staging vectorized to f32x4 (9 b128 loads+writes per thread
// vs 36 scalar; same values; CCAT%4==0, rows 16B-aligned; R16/R20-proven).
#define CHK3 64
#define CTW  8
#define CTH  8
#define CHW  12     // halo width/height = tile + 4
#define CHP  144    // 12*12 halo pixels
#define CSPX 68     // floats per pixel row (64 + 4 pad) = 272B, 16B-aligned
__global__ __launch_bounds__(256) void conv_kernel(const float* __restrict__ hc,
        const float* __restrict__ w, const float* __restrict__ wb,
        bf16* __restrict__ outb)
{
    int ch0 = blockIdx.x * CHK3;        // 0,64,...,384 (7 blocks; 424..447 zeroed)
    int tile = blockIdx.y;              // 64 tiles of 8x8
    int b = blockIdx.z;
    int ty0 = (tile >> 3) * CTH, tx0 = (tile & 7) * CTW;
    __shared__ __align__(16) float sh[CHP][CSPX];   // 39168 B
    __shared__ __align__(16) float wt[25][CHK3];    // 6400 B
    int tid = threadIdx.x;
    // stage input: f32x4 per (pixel, ch-quad); 16 lanes = 256B coalesced
    for (int idx = tid; idx < CHP * 16; idx += 256) {
        int pix = idx >> 4, cq = idx & 15;
        int gy = ty0 + pix / CHW - 2, gx = tx0 + pix % CHW - 2;
        int chg = ch0 + cq * 4;
        f32x4 v = {0.f, 0.f, 0.f, 0.f};
        if (gy >= 0 && gy < 64 && gx >= 0 && gx < 64 && chg < CCAT)
            v = *(const f32x4*)&hc[((size_t)b * NTOK + gy * 64 + gx) * CCAT + chg];
        *(f32x4*)&sh[pix][cq * 4] = v;
    }
    for (int idx = tid; idx < 25 * CHK3; idx += 256) {
        int kk = idx >> 6, ch = idx & 63;
        int chg = ch0 + ch;
        wt[kk][ch] = (chg < CCAT) ? w[chg * 25 + kk] : 0.f;
    }
    __syncthreads();
    int q = tid & 3, p = tid >> 2;      // p: pixel 0..63; q: 16-ch subgroup
    int px = p & 7, py = p >> 3;
    int cb = q * 16;
    int pc = py * CHW + px;             // top-left of 5x5 window
    v8s pk0, pk1;
    #pragma unroll
    for (int sub = 0; sub < 4; sub++) {
        int cs = cb + sub * 4;
        f32x4 acc = {0.f, 0.f, 0.f, 0.f};
        #pragma unroll
        for (int dy = 0; dy < 5; dy++) {
            #pragma unroll
            for (int dx = 0; dx < 5; dx++) {
                f32x4 sv = *(const f32x4*)&sh[pc + dy * CHW + dx][cs];
                f32x4 wv = *(const f32x4*)&wt[dy * 5 + dx][cs];
                acc += sv * wv;
            }
            __builtin_amdgcn_sched_barrier(0);   // cap hoisting at one row
        }
        f32x4 ctr = *(const f32x4*)&sh[pc + 2 * CHW + 2][cs];
        #pragma unroll
        for (int c = 0; c < 4; c++) {
            int chg = ch0 + cs + c;
            float v = 0.f;
            if (chg < CCAT) {
                float gv = gelu_exact(acc[c] + wb[chg]);
                v = ctr[c] + gv;
            }
            int lc = sub * 4 + c;
            if (lc < 8) pk0[lc] = (short)f2b(v);
            else        pk1[lc - 8] = (short)f2b(v);
        }
        __builtin_amdgcn_sched_barrier(0);
    }
    size_t obase = ((size_t)b * NTOK + (ty0 + py) * 64 + tx0 + px) * KP2 + ch0 + cb;
    unsigned short* ob = (unsigned short*)outb + obase;   // 32B-aligned
    *(v8s*)ob = pk0;
    *(v8s*)(ob + 8) = pk1;
}

// ---------------------------------------------------------------------------
extern "C" void kernel_launch(void* const* d_in, const int* in_sizes, int n_in,
                              void* d_out, int out_size, void* d_ws, size_t ws_size,
                              hipStream_t stream)
{
    (void)n_in; (void)ws_size; (void)out_size;
    const int* rpi = (const int*)d_in[28];

    // ---- workspace carve-up ----
    float* p = (float*)d_ws;
    float* xn    = p; p += (size_t)ROWS * CDIM;    // tmp2b bf16 lives here
    float* acc   = p; p += (size_t)ROWS * CDIM;
    float* tmp1  = p; p += (size_t)ROWS * CDIM;    // alias: P bf16 (head)
    float* qkv   = p; p += (size_t)ROWS * C3;      // alias: qkvb bf16; hc fp32 post-win
    float* hcnew = p; p += (size_t)ROWS * CCAT;    // alias: xnb/tmp1b; then conv bf16 out
    float* kkn   = p; p += (size_t)BB * MDICT * RD;
    bf16*  vvT   = (bf16*)p; p += (size_t)BB * 192 * MDICT / 2;   // bf16 [8][192][64]
    float* tdp   = p; p += (size_t)BB * MDICT * DTD;
    int*   tk_id = (int*)p; p += ROWS;
    int*   sidx  = (int*)p; p += ROWS;
    int*   flag  = (int*)p; p += 64;
    int*   diag  = (int*)p; p += 64;
    bf16* wtqkv  = (bf16*)p; p += 576 * KP1 / 2;
    bf16* wtcomb = (bf16*)p; p += 192 * 384 / 2;   // [192][384]: aca | win halves
    bf16* wtfc1  = (bf16*)p; p += 384 * KP1 / 2;
    bf16* wtfc2  = (bf16*)p; p += 192 * KP2 / 2;
    float* cin[28];
    for (int i = 0; i < 28; i++) { cin[i] = p; p += in_sizes[i]; }
    float* bias_t = p; p += (size_t)NHEADS * WIN_N * WIN_N;   // 1.5 MB

    float* hc      = qkv;                // fp32 [ROWS,CCAT]; born after win (qkv dead)
    bf16*  qkvb    = (bf16*)qkv;         // bf16 [ROWS,576] padded; dies at win
    bf16*  xnb     = (bf16*)hcnew;                            // [ROWS,KP1]; dies at fc1
    bf16*  tmp1b   = (bf16*)(hcnew + (size_t)ROWS * KP1 / 2); // [ROWS,KP1]; win out
    bf16*  tmp2b   = (bf16*)xn;          // [ROWS,KP1] bf16; acmsa out (xn region)
    bf16*  hcnewb2 = (bf16*)hcnew;       // [ROWS,KP2] bf16; born at conv
    bf16*  Pbuf    = (bf16*)tmp1;        // [ROWS,64] bf16; alive until mega-gemm

    // ---- dtype detect (+diag=0) + batched input normalize to fp32 ----
    detect_kernel<<<1, 256, 0, stream>>>(d_in[0], flag, diag);
    {
        CvtArgs ca;
        int total = 0, s = 0;
        for (int i = 0; i < 28; i++) {
            if (i == 0 || i == 4 || i == 13 || i == 16 || i == 20 || i == 24) continue;
            ca.src[s] = d_in[i];
            ca.dst[s] = cin[i];
            ca.cum[s] = total;
            total += in_sizes[i];
            s++;
        }
        ca.cum[s] = total;
        convert_all_kernel<<<(total + 255) / 256, 256, 0, stream>>>(ca, total, flag);
    }
    const float *td = cin[1], *n1g = cin[2], *n1b = cin[3],
        *wqkv_b = cin[5], *wq_w = cin[6], *wq_b = cin[7],
        *wk_w = cin[8], *wk_b = cin[9], *wv_w = cin[10], *wv_b = cin[11],
        *atd_scale = cin[12], *aca_b = cin[14], *win_rpb = cin[15],
        *winp_b = cin[17], *fctd_w = cin[18], *fctd_b = cin[19],
        *fc1_b = cin[21], *dw_w = cin[22], *dw_b = cin[23], *fc2_b = cin[25],
        *n2g = cin[26], *n2b = cin[27];

    // ---- adaptive weight repacks (by value) + bias table ----
    packW_kernel<<<576 * KP1 / 256, 256, 0, stream>>>(d_in[4],  wtqkv, CDIM, C3,   KP1, KP1, 0,   576 * KP1, flag);
    packW_kernel<<<192 * KP1 / 256, 256, 0, stream>>>(d_in[13], wtcomb, CDIM, CDIM, KP1, 384, 0,   192 * KP1, flag);
    packW_kernel<<<192 * KP1 / 256, 256, 0, stream>>>(d_in[16], wtcomb, CDIM, CDIM, KP1, 384, 192, 192 * KP1, flag);
    packW_kernel<<<384 * KP1 / 256, 256, 0, stream>>>(d_in[20], wtfc1, CDIM, MHID, KP1, KP1, 0,   384 * KP1, flag);
    packW_kernel<<<192 * KP2 / 256, 256, 0, stream>>>(d_in[24], wtfc2, CCAT, CDIM, KP2, KP2, 0,   192 * KP2, flag);
    bias_pre_kernel<<<NHEADS * WIN_N * WIN_N / 256, 256, 0, stream>>>(rpi, win_rpb, bias_t);

    td_pre_kernel<<<BB * MDICT, 64, 0, stream>>>(td, wk_w, wk_b, wv_w, wv_b,
                                                 fctd_w, fctd_b, kkn, vvT, tdp);
    // Fused LN1 + ATD (x dtype-flex) + folded tail/pad zeroing
    ln_atd_kernel<<<ROWS / 4, 256, 0, stream>>>(d_in[0], flag, n1g, n1b, xnb,
                                                wq_w, wq_b, atd_scale, kkn, Pbuf, tk_id,
                                                tmp1b, tmp2b, qkvb);
    // qkv gemm: bf16 padded output (Q pre-scaled)
    mgemm_kernel<false, false, true, 1><<<dim3(9, ROWS / 128), 256, 0, stream>>>(
        xnb, KP1, wtqkv, KP1, wqkv_b, nullptr, 0, (float*)qkvb, QKVP, C3, KP1,
        nullptr, nullptr, nullptr, nullptr, nullptr, nullptr, nullptr);
    sort_kernel<<<BB, 256, 0, stream>>>(tk_id, sidx);
    // MFMA flash AC_MSA -> tmp2b (bf16 direct)
    acmsa_mfma_kernel<<<dim3(NG * NHEADS, BB), 256, 0, stream>>>(qkvb, sidx, tmp2b);
    // MFMA flash window attention -> tmp1b (bf16 direct)
    win_mfma_kernel<<<dim3(16 * NHEADS, BB), 256, 0, stream>>>(qkvb, bias_t, tmp1b);
    // mega-gemm K=448: acc = tmp2b@Waca + tmp1b@Wwin + P@vvT[bz]
    //                 + (aca_b+winp_b) + x   (av pass absorbed)
    mgemm_kernel<false, false, true, 3><<<dim3(3, ROWS / 128), 256, 0, stream>>>(
        tmp2b, KP1, wtcomb, 384, aca_b, nullptr, 0, acc, CDIM, CDIM, KP2,
        nullptr, tmp1b, winp_b, Pbuf, vvT, d_in[0], flag);
    // FFN: LN2 (bf16 out only) -> fc1 -> gather -> conv -> fc2 (emit fused)
    ln_kernel<<<ROWS / 4, 256, 0, stream>>>(acc, n2g, n2b, xnb);
    mgemm_kernel<true, false, true, 0><<<dim3(6, ROWS / 128), 256, 0, stream>>>(
        xnb, KP1, wtfc1, KP1, fc1_b, nullptr, 0, hc, CCAT, MHID, KP1,
        nullptr, nullptr, nullptr, nullptr, nullptr, nullptr, nullptr);
    gather_td_kernel<<<ROWS * 64 / 256, 256, 0, stream>>>(tk_id, tdp, hc);
    conv_kernel<<<dim3(7, 64, BB), 256, 0, stream>>>(hc, dw_w, dw_b, hcnewb2);
    // fc2: res=acc, NaN scan -> diag, dtype-flex store DIRECT to d_out
    mgemm_kernel<false, true, true, 2><<<dim3(3, ROWS / 128), 256, 0, stream>>>(
        hcnewb2, KP2, wtfc2, KP2, fc2_b, acc, CDIM, (float*)d_out, CDIM, CDIM, KP2,
        diag, nullptr, nullptr, nullptr, nullptr, nullptr, flag);
    // NaN patch (all-or-nothing semantics); early-exits when diag==0
    nan_patch_kernel<<<1, 256, 0, stream>>>(d_out, flag, diag);
}